// Round 1
// baseline (1342.986 us; speedup 1.0000x reference)
//
#include <hip/hip_runtime.h>
#include <math.h>

#define BB   4
#define LSEQ 2048
#define DV   256
#define HH   4
#define RR   128
#define EE   32768
#define ETOT (EE + LSEQ)
#define HD2  64
#define FFD  1024

// ---------------------------------------------------------------------------
// Generic strided batched GEMM: C[m,n] = act(alpha * sum_k A[m,k]*B[k,n] + bias[n])
// A[m,k] at A[m*sam + k*sak], B[k,n] at B[k*sbk + n*sbn], C[m,n] at C[m*scm + n]
// batch z -> (zb = z/subH, zh = z%subH); offsets zb*bs?1 + zh*bs?2.
// Requires M%64==0, N%64==0, K%16==0 (true for all calls here).
// ---------------------------------------------------------------------------
__global__ __launch_bounds__(256) void gemm_k(
    const float* __restrict__ A, const float* __restrict__ B,
    const float* __restrict__ bias, float* __restrict__ C,
    int M, int N, int K,
    int sam, int sak, int sbk, int sbn, int scm,
    long bsA1, long bsA2, long bsB1, long bsB2, long bsC1, long bsC2,
    int subH, float alpha, int act)
{
    int z  = blockIdx.z;
    int zb = z / subH, zh = z % subH;
    A += zb * bsA1 + zh * bsA2;
    B += zb * bsB1 + zh * bsB2;
    C += zb * bsC1 + zh * bsC2;

    int n0 = blockIdx.x * 64;
    int m0 = blockIdx.y * 64;

    __shared__ float As[16][65];
    __shared__ float Bs[16][65];

    int tid = threadIdx.x;
    int tm = tid >> 4, tn = tid & 15;

    float acc[4][4] = {};

    for (int k0 = 0; k0 < K; k0 += 16) {
#pragma unroll
        for (int i = 0; i < 4; ++i) {
            int lin = tid + i * 256;
            int kk = lin & 15, mm = lin >> 4;
            As[kk][mm] = A[(long)(m0 + mm) * sam + (long)(k0 + kk) * sak];
        }
#pragma unroll
        for (int i = 0; i < 4; ++i) {
            int lin = tid + i * 256;
            int nn = lin & 63, kk = lin >> 6;
            Bs[kk][nn] = B[(long)(k0 + kk) * sbk + (long)(n0 + nn) * sbn];
        }
        __syncthreads();
#pragma unroll
        for (int kk = 0; kk < 16; ++kk) {
            float a[4], b[4];
#pragma unroll
            for (int i = 0; i < 4; ++i) a[i] = As[kk][tm * 4 + i];
#pragma unroll
            for (int j = 0; j < 4; ++j) b[j] = Bs[kk][tn * 4 + j];
#pragma unroll
            for (int i = 0; i < 4; ++i)
#pragma unroll
                for (int j = 0; j < 4; ++j)
                    acc[i][j] += a[i] * b[j];
        }
        __syncthreads();
    }

#pragma unroll
    for (int i = 0; i < 4; ++i) {
        int m = m0 + tm * 4 + i;
#pragma unroll
        for (int j = 0; j < 4; ++j) {
            int n = n0 + tn * 4 + j;
            float v = acc[i][j] * alpha;
            if (bias) v += bias[n];
            if (act == 1) v = fmaxf(v, 0.f);
            C[(long)m * scm + n] = v;
        }
    }
}

// ---------------------------------------------------------------------------
// GAT attention logits: a_src[row,h] = sum_c h[row,h,c]*att_src[h,c]; same for dst
// one block per row (= b*L + l), 256 threads = channels
// ---------------------------------------------------------------------------
__global__ __launch_bounds__(256) void gat_att_k(
    const float* __restrict__ h, const float* __restrict__ att_src,
    const float* __restrict__ att_dst, float* __restrict__ a_src,
    float* __restrict__ a_dst)
{
    long row = blockIdx.x;
    int tid = threadIdx.x;
    __shared__ float red[256];
    const float* hrow = h + row * (HH * DV);
    for (int hh = 0; hh < HH; ++hh) {
        float hv = hrow[hh * DV + tid];
        red[tid] = hv * att_src[hh * DV + tid];
        __syncthreads();
        for (int s = 128; s > 0; s >>= 1) { if (tid < s) red[tid] += red[tid + s]; __syncthreads(); }
        if (tid == 0) a_src[row * HH + hh] = red[0];
        __syncthreads();
        red[tid] = hv * att_dst[hh * DV + tid];
        __syncthreads();
        for (int s = 128; s > 0; s >>= 1) { if (tid < s) red[tid] += red[tid + s]; __syncthreads(); }
        if (tid == 0) a_dst[row * HH + hh] = red[0];
        __syncthreads();
    }
}

// ---------------------------------------------------------------------------
// CSR build over dst (edges shared across batch). Self loops appended: i>=EE.
// ---------------------------------------------------------------------------
__global__ void csr_count_k(const int* __restrict__ ei, int* __restrict__ cnt)
{
    int i = blockIdx.x * blockDim.x + threadIdx.x;
    if (i >= ETOT) return;
    int dst = (i < EE) ? ei[EE + i] : (i - EE);
    atomicAdd(&cnt[dst], 1);
}

__global__ __launch_bounds__(256) void csr_scan_k(const int* __restrict__ cnt, int* __restrict__ off)
{
    __shared__ int chunk[256];
    int tid = threadIdx.x;
    int base = tid * 8;
    int loc[8];
    int s = 0;
#pragma unroll
    for (int i = 0; i < 8; ++i) { loc[i] = s; s += cnt[base + i]; }
    chunk[tid] = s;
    __syncthreads();
    for (int st = 1; st < 256; st <<= 1) {
        int v = (tid >= st) ? chunk[tid - st] : 0;
        __syncthreads();
        chunk[tid] += v;
        __syncthreads();
    }
    int pre = (tid == 0) ? 0 : chunk[tid - 1];
#pragma unroll
    for (int i = 0; i < 8; ++i) off[base + i] = pre + loc[i];
    if (tid == 255) off[LSEQ] = chunk[255];
}

__global__ void csr_fill_k(const int* __restrict__ ei, const int* __restrict__ off,
                           int* __restrict__ cursor, int* __restrict__ bucket)
{
    int i = blockIdx.x * blockDim.x + threadIdx.x;
    if (i >= ETOT) return;
    int dst = (i < EE) ? ei[EE + i] : (i - EE);
    int p = atomicAdd(&cursor[dst], 1);
    bucket[off[dst] + p] = i;
}

// ---------------------------------------------------------------------------
// GAT scatter-softmax + aggregate. One block per (node n, batch b).
// 3 passes over incoming-edge bucket: max, sum(exp), weighted gather.
// out[b,n,hh*DV+c] = sum_e alpha[e,hh]*h[b,src(e),hh,c] + gat_b
// ---------------------------------------------------------------------------
__global__ __launch_bounds__(256) void gat_gather_k(
    const float* __restrict__ h, const int* __restrict__ ei,
    const int* __restrict__ off, const int* __restrict__ bucket,
    const float* __restrict__ a_src, const float* __restrict__ a_dst,
    const float* __restrict__ gat_b, float* __restrict__ out)
{
    int n = blockIdx.x;
    int b = blockIdx.y;
    int tid = threadIdx.x;
    int beg = off[n], end = off[n + 1];
    int deg = end - beg;

    const float* asrc_b = a_src + (long)b * LSEQ * HH;
    float adst[HH];
#pragma unroll
    for (int hh = 0; hh < HH; ++hh) adst[hh] = a_dst[((long)b * LSEQ + n) * HH + hh];

    __shared__ float red[256];
    __shared__ float m_sh[HH], den_sh[HH];
    __shared__ float alpha_sh[256][HH];
    __shared__ int   src_sh[256];

    // pass 1: per-head max
    float mx[HH] = { -INFINITY, -INFINITY, -INFINITY, -INFINITY };
    for (int c0 = 0; c0 < deg; c0 += 256) {
        int idx = c0 + tid;
        if (idx < deg) {
            int eid = bucket[beg + idx];
            int src = (eid < EE) ? ei[eid] : (eid - EE);
#pragma unroll
            for (int hh = 0; hh < HH; ++hh) {
                float e = asrc_b[(long)src * HH + hh] + adst[hh];
                e = (e >= 0.f) ? e : 0.2f * e;
                mx[hh] = fmaxf(mx[hh], e);
            }
        }
    }
#pragma unroll
    for (int hh = 0; hh < HH; ++hh) {
        red[tid] = mx[hh]; __syncthreads();
        for (int st = 128; st > 0; st >>= 1) { if (tid < st) red[tid] = fmaxf(red[tid], red[tid + st]); __syncthreads(); }
        if (tid == 0) m_sh[hh] = red[0];
        __syncthreads();
    }

    // pass 2: per-head denom
    float sm[HH] = { 0.f, 0.f, 0.f, 0.f };
    for (int c0 = 0; c0 < deg; c0 += 256) {
        int idx = c0 + tid;
        if (idx < deg) {
            int eid = bucket[beg + idx];
            int src = (eid < EE) ? ei[eid] : (eid - EE);
#pragma unroll
            for (int hh = 0; hh < HH; ++hh) {
                float e = asrc_b[(long)src * HH + hh] + adst[hh];
                e = (e >= 0.f) ? e : 0.2f * e;
                sm[hh] += __expf(e - m_sh[hh]);
            }
        }
    }
#pragma unroll
    for (int hh = 0; hh < HH; ++hh) {
        red[tid] = sm[hh]; __syncthreads();
        for (int st = 128; st > 0; st >>= 1) { if (tid < st) red[tid] += red[tid + st]; __syncthreads(); }
        if (tid == 0) den_sh[hh] = red[0];
        __syncthreads();
    }

    // pass 3: weighted gather. thread = channel c.
    float acc[HH] = { 0.f, 0.f, 0.f, 0.f };
    for (int c0 = 0; c0 < deg; c0 += 256) {
        int cn = min(256, deg - c0);
        if (tid < cn) {
            int eid = bucket[beg + c0 + tid];
            int src = (eid < EE) ? ei[eid] : (eid - EE);
            src_sh[tid] = src;
#pragma unroll
            for (int hh = 0; hh < HH; ++hh) {
                float e = asrc_b[(long)src * HH + hh] + adst[hh];
                e = (e >= 0.f) ? e : 0.2f * e;
                alpha_sh[tid][hh] = __expf(e - m_sh[hh]) / den_sh[hh];
            }
        }
        __syncthreads();
        for (int j = 0; j < cn; ++j) {
            int src = src_sh[j];
            const float* hsrc = h + ((long)b * LSEQ + src) * (HH * DV);
#pragma unroll
            for (int hh = 0; hh < HH; ++hh)
                acc[hh] += alpha_sh[j][hh] * hsrc[hh * DV + tid];
        }
        __syncthreads();
    }
#pragma unroll
    for (int hh = 0; hh < HH; ++hh)
        out[((long)b * LSEQ + n) * (HH * DV) + hh * DV + tid] = acc[hh] + gat_b[hh * DV + tid];
}

// ---------------------------------------------------------------------------
// LayerNorm over D=256: out = (x - mu)*rsqrt(var+eps)*g + b, x = x0 (+x1) (+x2)
// one block per row, 256 threads
// ---------------------------------------------------------------------------
__global__ __launch_bounds__(256) void ln_k(
    const float* __restrict__ x0, const float* __restrict__ x1,
    const float* __restrict__ x2, const float* __restrict__ g,
    const float* __restrict__ bta, float* __restrict__ out)
{
    long row = blockIdx.x;
    int tid = threadIdx.x;
    long base = row * DV + tid;
    float v = x0[base];
    if (x1) v += x1[base];
    if (x2) v += x2[base];
    __shared__ float red[256];
    red[tid] = v; __syncthreads();
    for (int s = 128; s > 0; s >>= 1) { if (tid < s) red[tid] += red[tid + s]; __syncthreads(); }
    float mu = red[0] * (1.0f / DV);
    __syncthreads();
    float d = v - mu;
    red[tid] = d * d; __syncthreads();
    for (int s = 128; s > 0; s >>= 1) { if (tid < s) red[tid] += red[tid + s]; __syncthreads(); }
    float var = red[0] * (1.0f / DV);
    float r = rsqrtf(var + 1e-5f);
    out[base] = d * r * g[tid] + bta[tid];
}

// ---------------------------------------------------------------------------
// Column softmax over L (axis=1) for pm [B, L, R], in place. block=(r, b)
// ---------------------------------------------------------------------------
__global__ __launch_bounds__(256) void colsoftmax_k(float* __restrict__ pm)
{
    int r = blockIdx.x;
    int b = blockIdx.y;
    int tid = threadIdx.x;
    float* base = pm + (long)b * LSEQ * RR + r;
    __shared__ float red[256];
    float mx = -INFINITY;
    for (int l = tid; l < LSEQ; l += 256) mx = fmaxf(mx, base[(long)l * RR]);
    red[tid] = mx; __syncthreads();
    for (int s = 128; s > 0; s >>= 1) { if (tid < s) red[tid] = fmaxf(red[tid], red[tid + s]); __syncthreads(); }
    float m = red[0]; __syncthreads();
    float sm = 0.f;
    for (int l = tid; l < LSEQ; l += 256) sm += __expf(base[(long)l * RR] - m);
    red[tid] = sm; __syncthreads();
    for (int s = 128; s > 0; s >>= 1) { if (tid < s) red[tid] += red[tid + s]; __syncthreads(); }
    float inv = 1.0f / red[0];
    for (int l = tid; l < LSEQ; l += 256) base[(long)l * RR] = __expf(base[(long)l * RR] - m) * inv;
}

// ---------------------------------------------------------------------------
// Row softmax over last dim R=128 for scores [B,H,L,R], in place. 1 block/row.
// ---------------------------------------------------------------------------
__global__ __launch_bounds__(128) void rowsoftmax_k(float* __restrict__ sc)
{
    long row = blockIdx.x;
    int tid = threadIdx.x;
    float* base = sc + row * RR;
    float v = base[tid];
    __shared__ float red[128];
    red[tid] = v; __syncthreads();
    for (int s = 64; s > 0; s >>= 1) { if (tid < s) red[tid] = fmaxf(red[tid], red[tid + s]); __syncthreads(); }
    float m = red[0]; __syncthreads();
    float e = __expf(v - m);
    red[tid] = e; __syncthreads();
    for (int s = 64; s > 0; s >>= 1) { if (tid < s) red[tid] += red[tid + s]; __syncthreads(); }
    base[tid] = e / red[0];
}

// ---------------------------------------------------------------------------
static void launch_gemm(hipStream_t st, const float* A, const float* B,
                        const float* bias, float* C,
                        int M, int N, int K,
                        int sam, int sak, int sbk, int sbn, int scm,
                        long bsA1, long bsA2, long bsB1, long bsB2,
                        long bsC1, long bsC2, int subH, int nb,
                        float alpha, int act)
{
    dim3 g(N / 64, M / 64, nb);
    gemm_k<<<g, 256, 0, st>>>(A, B, bias, C, M, N, K, sam, sak, sbk, sbn, scm,
                              bsA1, bsA2, bsB1, bsB2, bsC1, bsC2, subH, alpha, act);
}

extern "C" void kernel_launch(void* const* d_in, const int* in_sizes, int n_in,
                              void* d_out, int out_size, void* d_ws, size_t ws_size,
                              hipStream_t stream)
{
    const float* s        = (const float*)d_in[0];
    const float* gat_W    = (const float*)d_in[1];
    const float* att_src  = (const float*)d_in[2];
    const float* att_dst  = (const float*)d_in[3];
    const float* gat_b    = (const float*)d_in[4];
    const float* short_W  = (const float*)d_in[5];
    const float* short_b  = (const float*)d_in[6];
    const float* q_W      = (const float*)d_in[7];
    const float* q_b      = (const float*)d_in[8];
    const float* k_W      = (const float*)d_in[9];
    const float* k_b      = (const float*)d_in[10];
    const float* v_W      = (const float*)d_in[11];
    const float* v_b      = (const float*)d_in[12];
    const float* o_W      = (const float*)d_in[13];
    const float* o_b      = (const float*)d_in[14];
    const float* p_W      = (const float*)d_in[15];
    const float* p_b      = (const float*)d_in[16];
    const float* lnq_g    = (const float*)d_in[17];
    const float* lnq_b    = (const float*)d_in[18];
    const float* lnk_g    = (const float*)d_in[19];
    const float* lnk_b    = (const float*)d_in[20];
    const float* lnv_g    = (const float*)d_in[21];
    const float* lnv_b    = (const float*)d_in[22];
    const float* ln1_g    = (const float*)d_in[23];
    const float* ln1_b    = (const float*)d_in[24];
    const float* ln2_g    = (const float*)d_in[25];
    const float* ln2_b    = (const float*)d_in[26];
    const float* f1_W     = (const float*)d_in[27];
    const float* f1_b     = (const float*)d_in[28];
    const float* f2_W     = (const float*)d_in[29];
    const float* f2_b     = (const float*)d_in[30];
    const int*   ei       = (const int*)d_in[31];
    float* out = (float*)d_out;

    // ---- workspace layout (floats) ----
    float* ws = (float*)d_ws;
    float* hbuf    = ws;                       // B*L*H*D = 8388608  (later: ffh)
    float* gat_out = ws + 8388608;             // 8388608 (later: scores 4194304 + ff2)
    float* scores  = gat_out;                  // alias (after short GEMM)
    float* ff2     = gat_out + 4194304;        // alias
    float* a_src   = ws + 16777216;            // 32768
    float* a_dst   = a_src + 32768;            // 32768
    float* shortb  = a_dst + 32768;            // 2097152
    float* qb      = shortb + 2097152;         // 2097152 (later: lng)
    float* kb      = qb + 2097152;             // 2097152 (later: lng2)
    float* vb      = kb + 2097152;             // 2097152 (later: h1)
    float* pmb     = vb + 2097152;             // 1048576
    float* kc      = pmb + 1048576;            // 131072
    float* vc      = kc + 131072;              // 131072
    float* lng     = qb;                       // alias (q dead after scores)
    float* lng2    = kb;                       // alias (k dead after k_c)
    float* h1      = vb;                       // alias (v dead after v_c)
    float* ffh     = hbuf;                     // alias (h dead after gather)
    int*   ioff    = (int*)(vc + 131072);      // L+1 = 2049
    int*   icnt    = ioff + 2049;              // 2048 (count, then cursor)
    int*   ibucket = icnt + 2048;              // ETOT = 34816

    const int ML = BB * LSEQ;  // 8192 rows

    // ---- CSR over dst (batch-shared) ----
    hipMemsetAsync(icnt, 0, LSEQ * sizeof(int), stream);
    csr_count_k<<<(ETOT + 255) / 256, 256, 0, stream>>>(ei, icnt);
    csr_scan_k<<<1, 256, 0, stream>>>(icnt, ioff);
    hipMemsetAsync(icnt, 0, LSEQ * sizeof(int), stream);
    csr_fill_k<<<(ETOT + 255) / 256, 256, 0, stream>>>(ei, ioff, icnt, ibucket);

    // ---- GAT: h = s @ gat_W ----
    launch_gemm(stream, s, gat_W, nullptr, hbuf, ML, HH * DV, DV,
                DV, 1, HH * DV, 1, HH * DV, 0, 0, 0, 0, 0, 0, 1, 1, 1.f, 0);
    gat_att_k<<<ML, 256, 0, stream>>>(hbuf, att_src, att_dst, a_src, a_dst);
    gat_gather_k<<<dim3(LSEQ, BB), 256, 0, stream>>>(hbuf, ei, ioff, ibucket,
                                                     a_src, a_dst, gat_b, gat_out);
    // short = gat_out @ short_W + short_b
    launch_gemm(stream, gat_out, short_W, short_b, shortb, ML, DV, HH * DV,
                HH * DV, 1, DV, 1, DV, 0, 0, 0, 0, 0, 0, 1, 1, 1.f, 0);

    // ---- long-range: q/k/v projections + LN ----
    launch_gemm(stream, s, q_W, q_b, qb, ML, DV, DV, DV, 1, DV, 1, DV,
                0, 0, 0, 0, 0, 0, 1, 1, 1.f, 0);
    ln_k<<<ML, 256, 0, stream>>>(qb, nullptr, nullptr, lnq_g, lnq_b, qb);
    launch_gemm(stream, s, k_W, k_b, kb, ML, DV, DV, DV, 1, DV, 1, DV,
                0, 0, 0, 0, 0, 0, 1, 1, 1.f, 0);
    ln_k<<<ML, 256, 0, stream>>>(kb, nullptr, nullptr, lnk_g, lnk_b, kb);
    launch_gemm(stream, s, v_W, v_b, vb, ML, DV, DV, DV, 1, DV, 1, DV,
                0, 0, 0, 0, 0, 0, 1, 1, 1.f, 0);
    ln_k<<<ML, 256, 0, stream>>>(vb, nullptr, nullptr, lnv_g, lnv_b, vb);

    // pm = softmax_L(k @ p_W + p_b)
    launch_gemm(stream, kb, p_W, p_b, pmb, ML, RR, DV, DV, 1, RR, 1, RR,
                0, 0, 0, 0, 0, 0, 1, 1, 1.f, 0);
    colsoftmax_k<<<dim3(RR, BB), 256, 0, stream>>>(pmb);

    // k_c[b,r,d] = sum_l pm[b,l,r]*k[b,l,d]  (A = pm^T)
    launch_gemm(stream, pmb, kb, nullptr, kc, RR, DV, LSEQ,
                1, RR, DV, 1, DV,
                (long)LSEQ * RR, 0, (long)LSEQ * DV, 0, (long)RR * DV, 0, 1, BB, 1.f, 0);
    launch_gemm(stream, pmb, vb, nullptr, vc, RR, DV, LSEQ,
                1, RR, DV, 1, DV,
                (long)LSEQ * RR, 0, (long)LSEQ * DV, 0, (long)RR * DV, 0, 1, BB, 1.f, 0);

    // scores[b,h,l,r] = (q_h . k_c)/8 ; batched over z = b*H + h
    launch_gemm(stream, qb, kc, nullptr, scores, LSEQ, RR, HD2,
                DV, 1, 1, DV, RR,
                (long)LSEQ * DV, HD2, (long)RR * DV, HD2,
                (long)HH * LSEQ * RR, (long)LSEQ * RR, HH, BB * HH, 0.125f, 0);
    rowsoftmax_k<<<BB * HH * LSEQ, 128, 0, stream>>>(scores);

    // lng[b,l,h*64+d] = sum_r probs * v_c
    launch_gemm(stream, scores, vc, nullptr, lng, LSEQ, HD2, RR,
                RR, 1, DV, 1, DV,
                (long)HH * LSEQ * RR, (long)LSEQ * RR, (long)RR * DV, HD2,
                (long)LSEQ * DV, HD2, HH, BB * HH, 1.f, 0);

    // lng2 = lng @ o_W + o_b
    launch_gemm(stream, lng, o_W, o_b, lng2, ML, DV, DV, DV, 1, DV, 1, DV,
                0, 0, 0, 0, 0, 0, 1, 1, 1.f, 0);

    // h1 = LN(s + short + lng2)
    ln_k<<<ML, 256, 0, stream>>>(s, shortb, lng2, ln1_g, ln1_b, h1);

    // FFN
    launch_gemm(stream, h1, f1_W, f1_b, ffh, ML, FFD, DV, DV, 1, FFD, 1, FFD,
                0, 0, 0, 0, 0, 0, 1, 1, 1.f, 1);
    launch_gemm(stream, ffh, f2_W, f2_b, ff2, ML, DV, FFD, FFD, 1, DV, 1, DV,
                0, 0, 0, 0, 0, 0, 1, 1, 1.f, 0);

    // out = LN(h1 + ff2)
    ln_k<<<ML, 256, 0, stream>>>(h1, ff2, nullptr, ln2_g, ln2_b, out);
}

// Round 2
// 358.104 us; speedup vs baseline: 3.7503x; 3.7503x over previous
//
#include <hip/hip_runtime.h>
#include <math.h>

#define BB   4
#define LSEQ 2048
#define DV   256
#define HH   4
#define RR   128
#define EE   32768
#define ETOT (EE + LSEQ)
#define FFD  1024

typedef unsigned short u16;
typedef __attribute__((ext_vector_type(8))) short bf16x8;
typedef __attribute__((ext_vector_type(4))) float f32x4;

__device__ __forceinline__ u16 f2bf(float f) {
    union { float f; unsigned u; } x; x.f = f;
    unsigned r = x.u + 0x7fff + ((x.u >> 16) & 1);
    return (u16)(r >> 16);
}
__device__ __forceinline__ float bf2f(u16 u) {
    union { unsigned u; float f; } x; x.u = ((unsigned)u) << 16;
    return x.f;
}

__device__ __forceinline__ void gload16(const void* g, void* l) {
    __builtin_amdgcn_global_load_lds(
        (const __attribute__((address_space(1))) unsigned int*)g,
        (__attribute__((address_space(3))) unsigned int*)l, 16, 0, 0);
}

// ---------------------------------------------------------------------------
// bf16 MFMA GEMM, BM=128, BK=64, BN template (128 or 64).
// C[m,n] = act(alpha * sum_k A[m,k]*BT[n,k] + bias[n])
// A bf16 [.,lda] row-major; BT bf16 [.,ldb] row-major (= B transposed).
// z -> zb=z/subH, zh=z%subH. pair = blockIdx.y / (M/128).
// split: k-range = [zh*ksl, zh*ksl+ksl)
// ---------------------------------------------------------------------------
template<int BN, int OUTBF16, int ACT>
__global__ __launch_bounds__(256) void mfma_gemm_k(
    const u16* __restrict__ A, const u16* __restrict__ BT,
    const float* __restrict__ bias, void* __restrict__ Cv,
    int M, int N, int K, int lda, int ldb, int ldc,
    long bsA1, long bsA2, long bsB1, long bsB2, long bsC1, long bsC2,
    int subH, long pairB, long pairC, int ksl, int split, float alpha)
{
    constexpr int BM = 128;
    constexpr int BK = 64;
    __shared__ u16 As[BM * BK];
    __shared__ u16 Bs[BN * BK];

    int z = blockIdx.z;
    int zb = z / subH, zh = z - zb * subH;
    int mtiles = M / BM;
    int pair = blockIdx.y / mtiles;
    int mt   = blockIdx.y - pair * mtiles;

    const u16* Ab = A  + zb * bsA1 + zh * bsA2;
    const u16* Bb = BT + zb * bsB1 + zh * bsB2 + (long)pair * pairB;
    int kstart = split ? zh * ksl : 0;
    int kcount = split ? ksl : K;
    int m0 = mt * BM, n0 = blockIdx.x * BN;

    int tid  = threadIdx.x;
    int wave = tid >> 6, lane = tid & 63;
    constexpr int WGN = (BN == 128) ? 2 : 1;
    constexpr int MI  = (BN == 128) ? 4 : 2;
    constexpr int NI  = 4;
    int wm = wave / WGN, wn = wave - wm * WGN;
    int wmo = wm * (MI * 16);
    int wno = wn * (NI * 16);

    f32x4 acc[MI][NI];
#pragma unroll
    for (int mi = 0; mi < MI; ++mi)
#pragma unroll
        for (int ni = 0; ni < NI; ++ni)
            acc[mi][ni] = (f32x4){0.f, 0.f, 0.f, 0.f};

    constexpr int AIT = (BM * BK / 8) / 256;   // 4
    constexpr int BIT = (BN * BK / 8) / 256;   // 4 or 2

    for (int k0 = 0; k0 < kcount; k0 += BK) {
        int kb = kstart + k0;
#pragma unroll
        for (int i = 0; i < AIT; ++i) {
            int p   = i * 256 + tid;
            int row = p >> 3;
            int kc  = (p & 7) ^ (row & 7);   // pre-swizzled source
            const u16* gp = Ab + (long)(m0 + row) * lda + kb + kc * 8;
            gload16(gp, (char*)As + (size_t)(i * 256 + wave * 64) * 16);
        }
#pragma unroll
        for (int i = 0; i < BIT; ++i) {
            int p   = i * 256 + tid;
            int row = p >> 3;
            int kc  = (p & 7) ^ (row & 7);
            const u16* gp = Bb + (long)(n0 + row) * ldb + kb + kc * 8;
            gload16(gp, (char*)Bs + (size_t)(i * 256 + wave * 64) * 16);
        }
        asm volatile("s_waitcnt vmcnt(0)");
        __syncthreads();

        const char* Ac = (const char*)As;
        const char* Bc = (const char*)Bs;
#pragma unroll
        for (int kh = 0; kh < 2; ++kh) {
            bf16x8 af[MI], bfr[NI];
            int kby = kh * 64 + ((lane >> 4) << 4);
#pragma unroll
            for (int mi = 0; mi < MI; ++mi) {
                int r = wmo + mi * 16 + (lane & 15);
                af[mi] = *(const bf16x8*)(Ac + r * 128 + (kby ^ ((r & 7) << 4)));
            }
#pragma unroll
            for (int ni = 0; ni < NI; ++ni) {
                int r = wno + ni * 16 + (lane & 15);
                bfr[ni] = *(const bf16x8*)(Bc + r * 128 + (kby ^ ((r & 7) << 4)));
            }
#pragma unroll
            for (int mi = 0; mi < MI; ++mi)
#pragma unroll
                for (int ni = 0; ni < NI; ++ni)
                    acc[mi][ni] = __builtin_amdgcn_mfma_f32_16x16x32_bf16(
                        af[mi], bfr[ni], acc[mi][ni], 0, 0, 0);
        }
        __syncthreads();
    }

    long cb = zb * bsC1 + zh * bsC2 + (long)pair * pairC;
#pragma unroll
    for (int mi = 0; mi < MI; ++mi) {
#pragma unroll
        for (int ni = 0; ni < NI; ++ni) {
            int col = n0 + wno + ni * 16 + (lane & 15);
            float bv = bias ? bias[col] : 0.f;
#pragma unroll
            for (int j = 0; j < 4; ++j) {
                int row = m0 + wmo + mi * 16 + ((lane >> 4) << 2) + j;
                float v = acc[mi][ni][j] * alpha + bv;
                if (ACT) v = fmaxf(v, 0.f);
                long idx = (long)row * ldc + col + cb;
                if (OUTBF16) ((u16*)Cv)[idx] = f2bf(v);
                else         ((float*)Cv)[idx] = v;
            }
        }
    }
}

// ---------------------------------------------------------------------------
// fp32 [K][N] -> bf16 [N][K] transpose-cast (weights)
// ---------------------------------------------------------------------------
__global__ __launch_bounds__(256) void wtrans_k(const float* __restrict__ src,
                                                u16* __restrict__ dst, int K, int N)
{
    __shared__ float t[32][33];
    int n0 = blockIdx.x * 32, k0 = blockIdx.y * 32;
    int tx = threadIdx.x & 31, ty = threadIdx.x >> 5;
#pragma unroll
    for (int i = 0; i < 32; i += 8)
        t[ty + i][tx] = src[(long)(k0 + ty + i) * N + n0 + tx];
    __syncthreads();
#pragma unroll
    for (int i = 0; i < 32; i += 8)
        dst[(long)(n0 + ty + i) * K + k0 + tx] = f2bf(t[tx][ty + i]);
}

// bf16 [R][C] -> bf16 [C][R] transpose, batched over z
__global__ __launch_bounds__(256) void ttrans_k(const u16* __restrict__ in,
                                                u16* __restrict__ out,
                                                int R, int C, long isb, long osb)
{
    in  += blockIdx.z * isb;
    out += blockIdx.z * osb;
    __shared__ u16 t[32][33];
    int c0 = blockIdx.x * 32, r0 = blockIdx.y * 32;
    int tx = threadIdx.x & 31, ty = threadIdx.x >> 5;
#pragma unroll
    for (int i = 0; i < 32; i += 8)
        t[ty + i][tx] = in[(long)(r0 + ty + i) * C + c0 + tx];
    __syncthreads();
#pragma unroll
    for (int i = 0; i < 32; i += 8)
        out[(long)(c0 + ty + i) * R + r0 + tx] = t[tx][ty + i];
}

__global__ void cast_bf16_k(const float* __restrict__ in, u16* __restrict__ out, int n)
{
    int i = (blockIdx.x * 256 + threadIdx.x) * 4;
    if (i < n) {
        float4 v = *(const float4*)(in + i);
        out[i]     = f2bf(v.x);
        out[i + 1] = f2bf(v.y);
        out[i + 2] = f2bf(v.z);
        out[i + 3] = f2bf(v.w);
    }
}

__global__ void concat3_k(const float* a, const float* b, const float* c, float* o)
{
    int i = blockIdx.x * 256 + threadIdx.x;
    if (i >= 768) return;
    o[i] = (i < 256) ? a[i] : ((i < 512) ? b[i - 256] : c[i - 512]);
}

// ---------------------------------------------------------------------------
// GAT attention logits from bf16 h
// ---------------------------------------------------------------------------
__global__ __launch_bounds__(256) void gat_att_k(
    const u16* __restrict__ h, const float* __restrict__ att_src,
    const float* __restrict__ att_dst, float* __restrict__ a_src,
    float* __restrict__ a_dst)
{
    long row = blockIdx.x;
    int tid = threadIdx.x;
    __shared__ float red[256];
    const u16* hrow = h + row * (HH * DV);
    for (int hh = 0; hh < HH; ++hh) {
        float hv = bf2f(hrow[hh * DV + tid]);
        red[tid] = hv * att_src[hh * DV + tid];
        __syncthreads();
        for (int s = 128; s > 0; s >>= 1) { if (tid < s) red[tid] += red[tid + s]; __syncthreads(); }
        if (tid == 0) a_src[row * HH + hh] = red[0];
        __syncthreads();
        red[tid] = hv * att_dst[hh * DV + tid];
        __syncthreads();
        for (int s = 128; s > 0; s >>= 1) { if (tid < s) red[tid] += red[tid + s]; __syncthreads(); }
        if (tid == 0) a_dst[row * HH + hh] = red[0];
        __syncthreads();
    }
}

// ---------------------------------------------------------------------------
// CSR build over dst (batch-shared)
// ---------------------------------------------------------------------------
__global__ void csr_count_k(const int* __restrict__ ei, int* __restrict__ cnt)
{
    int i = blockIdx.x * blockDim.x + threadIdx.x;
    if (i >= ETOT) return;
    int dst = (i < EE) ? ei[EE + i] : (i - EE);
    atomicAdd(&cnt[dst], 1);
}

__global__ __launch_bounds__(256) void csr_scan_k(const int* __restrict__ cnt, int* __restrict__ off)
{
    __shared__ int chunk[256];
    int tid = threadIdx.x;
    int base = tid * 8;
    int loc[8];
    int s = 0;
#pragma unroll
    for (int i = 0; i < 8; ++i) { loc[i] = s; s += cnt[base + i]; }
    chunk[tid] = s;
    __syncthreads();
    for (int st = 1; st < 256; st <<= 1) {
        int v = (tid >= st) ? chunk[tid - st] : 0;
        __syncthreads();
        chunk[tid] += v;
        __syncthreads();
    }
    int pre = (tid == 0) ? 0 : chunk[tid - 1];
#pragma unroll
    for (int i = 0; i < 8; ++i) off[base + i] = pre + loc[i];
    if (tid == 255) off[LSEQ] = chunk[255];
}

__global__ void csr_fill_k(const int* __restrict__ ei, const int* __restrict__ off,
                           int* __restrict__ cursor, int* __restrict__ bucket)
{
    int i = blockIdx.x * blockDim.x + threadIdx.x;
    if (i >= ETOT) return;
    int dst = (i < EE) ? ei[EE + i] : (i - EE);
    int p = atomicAdd(&cursor[dst], 1);
    bucket[off[dst] + p] = i;
}

// ---------------------------------------------------------------------------
// GAT scatter-softmax + aggregate (h bf16 in, gat_out bf16 out)
// ---------------------------------------------------------------------------
__global__ __launch_bounds__(256) void gat_gather_k(
    const u16* __restrict__ h, const int* __restrict__ ei,
    const int* __restrict__ off, const int* __restrict__ bucket,
    const float* __restrict__ a_src, const float* __restrict__ a_dst,
    const float* __restrict__ gat_b, u16* __restrict__ out)
{
    int n = blockIdx.x;
    int b = blockIdx.y;
    int tid = threadIdx.x;
    int beg = off[n], end = off[n + 1];
    int deg = end - beg;

    const float* asrc_b = a_src + (long)b * LSEQ * HH;
    float adst[HH];
#pragma unroll
    for (int hh = 0; hh < HH; ++hh) adst[hh] = a_dst[((long)b * LSEQ + n) * HH + hh];

    __shared__ float red[256];
    __shared__ float m_sh[HH], den_sh[HH];
    __shared__ float alpha_sh[256][HH];
    __shared__ int   src_sh[256];

    float mx[HH] = { -INFINITY, -INFINITY, -INFINITY, -INFINITY };
    for (int c0 = 0; c0 < deg; c0 += 256) {
        int idx = c0 + tid;
        if (idx < deg) {
            int eid = bucket[beg + idx];
            int src = (eid < EE) ? ei[eid] : (eid - EE);
#pragma unroll
            for (int hh = 0; hh < HH; ++hh) {
                float e = asrc_b[(long)src * HH + hh] + adst[hh];
                e = (e >= 0.f) ? e : 0.2f * e;
                mx[hh] = fmaxf(mx[hh], e);
            }
        }
    }
#pragma unroll
    for (int hh = 0; hh < HH; ++hh) {
        red[tid] = mx[hh]; __syncthreads();
        for (int st = 128; st > 0; st >>= 1) { if (tid < st) red[tid] = fmaxf(red[tid], red[tid + st]); __syncthreads(); }
        if (tid == 0) m_sh[hh] = red[0];
        __syncthreads();
    }

    float sm[HH] = { 0.f, 0.f, 0.f, 0.f };
    for (int c0 = 0; c0 < deg; c0 += 256) {
        int idx = c0 + tid;
        if (idx < deg) {
            int eid = bucket[beg + idx];
            int src = (eid < EE) ? ei[eid] : (eid - EE);
#pragma unroll
            for (int hh = 0; hh < HH; ++hh) {
                float e = asrc_b[(long)src * HH + hh] + adst[hh];
                e = (e >= 0.f) ? e : 0.2f * e;
                sm[hh] += __expf(e - m_sh[hh]);
            }
        }
    }
#pragma unroll
    for (int hh = 0; hh < HH; ++hh) {
        red[tid] = sm[hh]; __syncthreads();
        for (int st = 128; st > 0; st >>= 1) { if (tid < st) red[tid] += red[tid + st]; __syncthreads(); }
        if (tid == 0) den_sh[hh] = red[0];
        __syncthreads();
    }

    float acc[HH] = { 0.f, 0.f, 0.f, 0.f };
    for (int c0 = 0; c0 < deg; c0 += 256) {
        int cn = min(256, deg - c0);
        if (tid < cn) {
            int eid = bucket[beg + c0 + tid];
            int src = (eid < EE) ? ei[eid] : (eid - EE);
            src_sh[tid] = src;
#pragma unroll
            for (int hh = 0; hh < HH; ++hh) {
                float e = asrc_b[(long)src * HH + hh] + adst[hh];
                e = (e >= 0.f) ? e : 0.2f * e;
                alpha_sh[tid][hh] = __expf(e - m_sh[hh]) / den_sh[hh];
            }
        }
        __syncthreads();
        for (int j = 0; j < cn; ++j) {
            int src = src_sh[j];
            const u16* hsrc = h + ((long)b * LSEQ + src) * (HH * DV);
#pragma unroll
            for (int hh = 0; hh < HH; ++hh)
                acc[hh] += alpha_sh[j][hh] * bf2f(hsrc[hh * DV + tid]);
        }
        __syncthreads();
    }
#pragma unroll
    for (int hh = 0; hh < HH; ++hh)
        out[((long)b * LSEQ + n) * (HH * DV) + hh * DV + tid] = f2bf(acc[hh] + gat_b[hh * DV + tid]);
}

// ---------------------------------------------------------------------------
// LN over D=256 of strided fp32 row -> bf16 row (q/k/v)
// ---------------------------------------------------------------------------
__global__ __launch_bounds__(256) void ln_cast_k(
    const float* __restrict__ x, int ldx, int off,
    const float* __restrict__ g, const float* __restrict__ bta,
    u16* __restrict__ o)
{
    long row = blockIdx.x;
    int tid = threadIdx.x;
    float v = x[row * ldx + off + tid];
    __shared__ float red[256];
    red[tid] = v; __syncthreads();
    for (int s = 128; s > 0; s >>= 1) { if (tid < s) red[tid] += red[tid + s]; __syncthreads(); }
    float mu = red[0] * (1.0f / DV);
    __syncthreads();
    float d = v - mu;
    red[tid] = d * d; __syncthreads();
    for (int s = 128; s > 0; s >>= 1) { if (tid < s) red[tid] += red[tid + s]; __syncthreads(); }
    float r = rsqrtf(red[0] * (1.0f / DV) + 1e-5f);
    o[row * DV + tid] = f2bf(d * r * g[tid] + bta[tid]);
}

// LN of (x0 [+x1] [+x2]) -> fp32 out (+ optional bf16 outb)
__global__ __launch_bounds__(256) void ln3_k(
    const float* __restrict__ x0, const float* __restrict__ x1,
    const float* __restrict__ x2, const float* __restrict__ g,
    const float* __restrict__ bta, float* __restrict__ out,
    u16* __restrict__ outb)
{
    long row = blockIdx.x;
    int tid = threadIdx.x;
    long base = row * DV + tid;
    float v = x0[base];
    if (x1) v += x1[base];
    if (x2) v += x2[base];
    __shared__ float red[256];
    red[tid] = v; __syncthreads();
    for (int s = 128; s > 0; s >>= 1) { if (tid < s) red[tid] += red[tid + s]; __syncthreads(); }
    float mu = red[0] * (1.0f / DV);
    __syncthreads();
    float d = v - mu;
    red[tid] = d * d; __syncthreads();
    for (int s = 128; s > 0; s >>= 1) { if (tid < s) red[tid] += red[tid + s]; __syncthreads(); }
    float r = rsqrtf(red[0] * (1.0f / DV) + 1e-5f);
    float o = d * r * g[tid] + bta[tid];
    out[base] = o;
    if (outb) outb[base] = f2bf(o);
}

// pm softmax over L (axis=1): fp32 [b,l,r] -> bf16 pmT [b,r,l]
__global__ __launch_bounds__(256) void colsoftmax_k(const float* __restrict__ pm,
                                                    u16* __restrict__ pmT)
{
    int r = blockIdx.x;
    int b = blockIdx.y;
    int tid = threadIdx.x;
    const float* base = pm + (long)b * LSEQ * RR + r;
    u16* obase = pmT + ((long)b * RR + r) * LSEQ;
    __shared__ float red[256];
    float mx = -INFINITY;
    for (int l = tid; l < LSEQ; l += 256) mx = fmaxf(mx, base[(long)l * RR]);
    red[tid] = mx; __syncthreads();
    for (int s = 128; s > 0; s >>= 1) { if (tid < s) red[tid] = fmaxf(red[tid], red[tid + s]); __syncthreads(); }
    float m = red[0]; __syncthreads();
    float sm = 0.f;
    for (int l = tid; l < LSEQ; l += 256) sm += __expf(base[(long)l * RR] - m);
    red[tid] = sm; __syncthreads();
    for (int s = 128; s > 0; s >>= 1) { if (tid < s) red[tid] += red[tid + s]; __syncthreads(); }
    float inv = 1.0f / red[0];
    for (int l = tid; l < LSEQ; l += 256) obase[l] = f2bf(__expf(base[(long)l * RR] - m) * inv);
}

// row softmax over R=128: scores fp32 -> P bf16
__global__ __launch_bounds__(128) void rowsoftmax_k(const float* __restrict__ sc,
                                                    u16* __restrict__ P)
{
    long row = blockIdx.x;
    int tid = threadIdx.x;
    const float* base = sc + row * RR;
    float v = base[tid];
    __shared__ float red[128];
    red[tid] = v; __syncthreads();
    for (int s = 64; s > 0; s >>= 1) { if (tid < s) red[tid] = fmaxf(red[tid], red[tid + s]); __syncthreads(); }
    float m = red[0]; __syncthreads();
    float e = __expf(v - m);
    red[tid] = e; __syncthreads();
    for (int s = 64; s > 0; s >>= 1) { if (tid < s) red[tid] += red[tid + s]; __syncthreads(); }
    P[row * RR + tid] = f2bf(e / red[0]);
}

// sum 8 split-K partials -> bf16 kvc
__global__ void reduce_kvc_k(const float* __restrict__ part, u16* __restrict__ kvcb)
{
    int i = blockIdx.x * 256 + threadIdx.x;   // over 2*4*32768
    int bb = i >> 15, e = i & 32767;
    float s = 0.f;
#pragma unroll
    for (int s8 = 0; s8 < 8; ++s8) s += part[(long)(bb * 8 + s8) * 32768 + e];
    kvcb[i] = f2bf(s);
}

// ---------------------------------------------------------------------------
extern "C" void kernel_launch(void* const* d_in, const int* in_sizes, int n_in,
                              void* d_out, int out_size, void* d_ws, size_t ws_size,
                              hipStream_t stream)
{
    const float* s        = (const float*)d_in[0];
    const float* gat_W    = (const float*)d_in[1];
    const float* att_src  = (const float*)d_in[2];
    const float* att_dst  = (const float*)d_in[3];
    const float* gat_b    = (const float*)d_in[4];
    const float* short_W  = (const float*)d_in[5];
    const float* short_b  = (const float*)d_in[6];
    const float* q_W      = (const float*)d_in[7];
    const float* q_b      = (const float*)d_in[8];
    const float* k_W      = (const float*)d_in[9];
    const float* k_b      = (const float*)d_in[10];
    const float* v_W      = (const float*)d_in[11];
    const float* v_b      = (const float*)d_in[12];
    const float* o_W      = (const float*)d_in[13];
    const float* o_b      = (const float*)d_in[14];
    const float* p_W      = (const float*)d_in[15];
    const float* p_b      = (const float*)d_in[16];
    const float* lnq_g    = (const float*)d_in[17];
    const float* lnq_b    = (const float*)d_in[18];
    const float* lnk_g    = (const float*)d_in[19];
    const float* lnk_b    = (const float*)d_in[20];
    const float* lnv_g    = (const float*)d_in[21];
    const float* lnv_b    = (const float*)d_in[22];
    const float* ln1_g    = (const float*)d_in[23];
    const float* ln1_b    = (const float*)d_in[24];
    const float* ln2_g    = (const float*)d_in[25];
    const float* ln2_b    = (const float*)d_in[26];
    const float* f1_W     = (const float*)d_in[27];
    const float* f1_b     = (const float*)d_in[28];
    const float* f2_W     = (const float*)d_in[29];
    const float* f2_b     = (const float*)d_in[30];
    const int*   ei       = (const int*)d_in[31];
    float* out = (float*)d_out;

    const size_t MB = 1024 * 1024;
    char* W = (char*)d_ws;
    u16*   sb      = (u16*)(W);                         // 4MB
    u16*   gatT    = (u16*)(W + 4*MB);                  // 512KB  [1024][256]
    u16*   shortT  = (u16*)(W + 4*MB + 524288);         // 512KB  [256][1024]
    u16*   qkvT    = (u16*)(W + 4*MB + 1048576);        // 384KB  [768][256]
    u16*   oT      = (u16*)(W + 4*MB + 1441792);        // 128KB  [256][256]
    u16*   pT      = (u16*)(W + 4*MB + 1572864);        // 64KB   [128][256]
    u16*   f1T     = (u16*)(W + 4*MB + 1638400);        // 512KB  [1024][256]
    u16*   f2T     = (u16*)(W + 4*MB + 2162688);        // 512KB  [256][1024]
    float* qkvb    = (float*)(W + 4*MB + 2686976);      // 3KB
    int*   ioff    = (int*)(W + 4*MB + 2690048);        // 2049
    int*   icnt    = (int*)(W + 4*MB + 2699264);        // 2048
    int*   ibucket = (int*)(W + 4*MB + 2707456);        // 34816
    u16*   h       = (u16*)(W + 8*MB);                  // 16MB [b,l,1024]
    float* part    = (float*)(W + 16*MB);               // 8MB  [2][4][8][32768]
    u16*   Pb      = (u16*)(W + 16*MB);                 // alias (after part dead)
    u16*   ffh     = (u16*)(W + 8*MB);                  // alias h
    u16*   gat_out = (u16*)(W + 24*MB);                 // 16MB
    float* h1      = (float*)(W + 24*MB);               // alias (8MB)
    u16*   h1b     = (u16*)(W + 32*MB);                 // alias (4MB)
    float* shortb  = (float*)(W + 40*MB);               // 8MB
    float* qkv     = (float*)(W + 48*MB);               // 24MB [8192][768]
    float* pmraw   = (float*)(W + 48*MB);               // alias 4MB
    float* scores  = (float*)(W + 48*MB);               // alias 16MB
    float* lng2    = (float*)(W + 64*MB);               // 8MB
    u16*   qb      = (u16*)(W + 72*MB);                 // 4MB
    u16*   lngb    = (u16*)(W + 72*MB);                 // alias
    u16*   kvb     = (u16*)(W + 76*MB);                 // 8MB [2][4][2048][256]
    float* ff2     = (float*)(W + 76*MB);               // alias
    u16*   kvT     = (u16*)(W + 84*MB);                 // 8MB [2][4][256][2048]
    u16*   pmT     = (u16*)(W + 92*MB);                 // 2MB [4][128][2048]
    u16*   kvcb    = (u16*)(W + 94*MB);                 // 512KB [2][4][128][256]
    u16*   vcT     = (u16*)(W + 94*MB + 524288);        // 256KB [4][256][128]
    float* a_src   = (float*)(W + 95*MB);               // 128KB
    float* a_dst   = (float*)(W + 95*MB + 131072);      // 128KB

    const int ML = BB * LSEQ;  // 8192

    // ---- weights -> bf16 transposed ----
    wtrans_k<<<dim3(32, 8), 256, 0, stream>>>(gat_W, gatT, 256, 1024);
    wtrans_k<<<dim3(8, 32), 256, 0, stream>>>(short_W, shortT, 1024, 256);
    wtrans_k<<<dim3(8, 8), 256, 0, stream>>>(q_W, qkvT, 256, 256);
    wtrans_k<<<dim3(8, 8), 256, 0, stream>>>(k_W, qkvT + 65536, 256, 256);
    wtrans_k<<<dim3(8, 8), 256, 0, stream>>>(v_W, qkvT + 131072, 256, 256);
    wtrans_k<<<dim3(8, 8), 256, 0, stream>>>(o_W, oT, 256, 256);
    wtrans_k<<<dim3(4, 8), 256, 0, stream>>>(p_W, pT, 256, 128);
    wtrans_k<<<dim3(32, 8), 256, 0, stream>>>(f1_W, f1T, 256, 1024);
    wtrans_k<<<dim3(8, 32), 256, 0, stream>>>(f2_W, f2T, 1024, 256);
    concat3_k<<<3, 256, 0, stream>>>(q_b, k_b, v_b, qkvb);
    cast_bf16_k<<<2048, 256, 0, stream>>>(s, sb, ML * DV);

    // ---- CSR ----
    hipMemsetAsync(icnt, 0, LSEQ * sizeof(int), stream);
    csr_count_k<<<(ETOT + 255) / 256, 256, 0, stream>>>(ei, icnt);
    csr_scan_k<<<1, 256, 0, stream>>>(icnt, ioff);
    hipMemsetAsync(icnt, 0, LSEQ * sizeof(int), stream);
    csr_fill_k<<<(ETOT + 255) / 256, 256, 0, stream>>>(ei, ioff, icnt, ibucket);

    // ---- GAT: h = s @ gat_W (bf16 out) ----
    mfma_gemm_k<128, 1, 0><<<dim3(8, 64, 1), 256, 0, stream>>>(
        sb, gatT, nullptr, h, ML, 1024, 256, 256, 256, 1024,
        0, 0, 0, 0, 0, 0, 1, 0, 0, 0, 0, 1.f);
    gat_att_k<<<ML, 256, 0, stream>>>(h, att_src, att_dst, a_src, a_dst);
    gat_gather_k<<<dim3(LSEQ, BB), 256, 0, stream>>>(h, ei, ioff, ibucket,
                                                     a_src, a_dst, gat_b, gat_out);
    // short = gat_out @ short_W + short_b (fp32)
    mfma_gemm_k<128, 0, 0><<<dim3(2, 64, 1), 256, 0, stream>>>(
        gat_out, shortT, short_b, shortb, ML, 256, 1024, 1024, 1024, 256,
        0, 0, 0, 0, 0, 0, 1, 0, 0, 0, 0, 1.f);

    // ---- qkv = s @ [qW|kW|vW] + bias (fp32) ----
    mfma_gemm_k<128, 0, 0><<<dim3(6, 64, 1), 256, 0, stream>>>(
        sb, qkvT, qkvb, qkv, ML, 768, 256, 256, 256, 768,
        0, 0, 0, 0, 0, 0, 1, 0, 0, 0, 0, 1.f);
    ln_cast_k<<<ML, 256, 0, stream>>>(qkv, 768, 0,   lnq_g, lnq_b, qb);
    ln_cast_k<<<ML, 256, 0, stream>>>(qkv, 768, 256, lnk_g, lnk_b, kvb);
    ln_cast_k<<<ML, 256, 0, stream>>>(qkv, 768, 512, lnv_g, lnv_b, kvb + 2097152);

    // pm = softmax_L(k @ p_W + p_b) -> pmT bf16 [b][r][l]
    mfma_gemm_k<128, 0, 0><<<dim3(1, 64, 1), 256, 0, stream>>>(
        kvb, pT, p_b, pmraw, ML, 128, 256, 256, 256, 128,
        0, 0, 0, 0, 0, 0, 1, 0, 0, 0, 0, 1.f);
    colsoftmax_k<<<dim3(RR, BB), 256, 0, stream>>>(pmraw, pmT);

    // k,v -> L-major  kvT [2][4][256][2048]
    ttrans_k<<<dim3(8, 64, 8), 256, 0, stream>>>(kvb, kvT, 2048, 256, 524288, 524288);

    // k_c/v_c: part[pair][b][split][128][256] = pmT @ kvT  (split-K, pair via gridy)
    mfma_gemm_k<128, 0, 0><<<dim3(2, 2, 32), 256, 0, stream>>>(
        pmT, kvT, nullptr, part, 128, 256, 2048, 2048, 2048, 256,
        262144, 0, 524288, 0, 262144, 32768, 8, 2097152, 1048576, 256, 1, 1.f);
    reduce_kvc_k<<<1024, 256, 0, stream>>>(part, kvcb);
    // vcT [4][256][128] from kvcb pair1
    ttrans_k<<<dim3(8, 4, 4), 256, 0, stream>>>(kvcb + 131072, vcT, 128, 256, 32768, 32768);

    // scores = q_h @ k_c^T / 8  (z = b*4+h)
    mfma_gemm_k<128, 0, 0><<<dim3(1, 16, 16), 256, 0, stream>>>(
        qb, kvcb, nullptr, scores, LSEQ, 128, 64, 256, 256, 128,
        524288, 64, 32768, 64, 1048576, 262144, 4, 0, 0, 0, 0, 0.125f);
    rowsoftmax_k<<<BB * HH * LSEQ, 128, 0, stream>>>(scores, Pb);

    // lng = P @ v_c  (bf16 out, z = b*4+h)
    mfma_gemm_k<64, 1, 0><<<dim3(1, 16, 16), 256, 0, stream>>>(
        Pb, vcT, nullptr, lngb, LSEQ, 64, 128, 128, 128, 256,
        1048576, 262144, 32768, 8192, 524288, 64, 4, 0, 0, 0, 0, 1.f);

    // lng2 = lng @ o_W + o_b (fp32)
    mfma_gemm_k<128, 0, 0><<<dim3(2, 64, 1), 256, 0, stream>>>(
        lngb, oT, o_b, lng2, ML, 256, 256, 256, 256, 256,
        0, 0, 0, 0, 0, 0, 1, 0, 0, 0, 0, 1.f);

    // h1 = LN(s + short + lng2), fp32 + bf16
    ln3_k<<<ML, 256, 0, stream>>>(s, shortb, lng2, ln1_g, ln1_b, h1, h1b);

    // FFN
    mfma_gemm_k<128, 1, 1><<<dim3(8, 64, 1), 256, 0, stream>>>(
        h1b, f1T, f1_b, ffh, ML, 1024, 256, 256, 256, 1024,
        0, 0, 0, 0, 0, 0, 1, 0, 0, 0, 0, 1.f);
    mfma_gemm_k<128, 0, 0><<<dim3(2, 64, 1), 256, 0, stream>>>(
        ffh, f2T, f2_b, ff2, ML, 256, 1024, 1024, 1024, 256,
        0, 0, 0, 0, 0, 0, 1, 0, 0, 0, 0, 1.f);

    // out = LN(h1 + ff2)
    ln3_k<<<ML, 256, 0, stream>>>(h1, ff2, nullptr, ln2_g, ln2_b, out, nullptr);
}

// Round 3
// 273.909 us; speedup vs baseline: 4.9030x; 1.3074x over previous
//
#include <hip/hip_runtime.h>
#include <math.h>

#define BB   4
#define LSEQ 2048
#define DV   256
#define HH   4
#define RR   128
#define EE   32768
#define ETOT (EE + LSEQ)
#define FFD  1024

typedef unsigned short u16;
typedef __attribute__((ext_vector_type(8))) short bf16x8;
typedef __attribute__((ext_vector_type(4))) float f32x4;

__device__ __forceinline__ u16 f2bf(float f) {
    union { float f; unsigned u; } x; x.f = f;
    unsigned r = x.u + 0x7fff + ((x.u >> 16) & 1);
    return (u16)(r >> 16);
}
__device__ __forceinline__ float bf2f(u16 u) {
    union { unsigned u; float f; } x; x.u = ((unsigned)u) << 16;
    return x.f;
}

__device__ __forceinline__ void gload16(const void* g, void* l) {
    __builtin_amdgcn_global_load_lds(
        (const __attribute__((address_space(1))) unsigned int*)g,
        (__attribute__((address_space(3))) unsigned int*)l, 16, 0, 0);
}

// ---------------------------------------------------------------------------
// bf16 MFMA GEMM, BM=128, BK=64, BN template (128 or 64). (unchanged, verified)
// ---------------------------------------------------------------------------
template<int BN, int OUTBF16, int ACT>
__global__ __launch_bounds__(256) void mfma_gemm_k(
    const u16* __restrict__ A, const u16* __restrict__ BT,
    const float* __restrict__ bias, void* __restrict__ Cv,
    int M, int N, int K, int lda, int ldb, int ldc,
    long bsA1, long bsA2, long bsB1, long bsB2, long bsC1, long bsC2,
    int subH, long pairB, long pairC, int ksl, int split, float alpha)
{
    constexpr int BM = 128;
    constexpr int BK = 64;
    __shared__ u16 As[BM * BK];
    __shared__ u16 Bs[BN * BK];

    int z = blockIdx.z;
    int zb = z / subH, zh = z - zb * subH;
    int mtiles = M / BM;
    int pair = blockIdx.y / mtiles;
    int mt   = blockIdx.y - pair * mtiles;

    const u16* Ab = A  + zb * bsA1 + zh * bsA2;
    const u16* Bb = BT + zb * bsB1 + zh * bsB2 + (long)pair * pairB;
    int kstart = split ? zh * ksl : 0;
    int kcount = split ? ksl : K;
    int m0 = mt * BM, n0 = blockIdx.x * BN;

    int tid  = threadIdx.x;
    int wave = tid >> 6, lane = tid & 63;
    constexpr int WGN = (BN == 128) ? 2 : 1;
    constexpr int MI  = (BN == 128) ? 4 : 2;
    constexpr int NI  = 4;
    int wm = wave / WGN, wn = wave - wm * WGN;
    int wmo = wm * (MI * 16);
    int wno = wn * (NI * 16);

    f32x4 acc[MI][NI];
#pragma unroll
    for (int mi = 0; mi < MI; ++mi)
#pragma unroll
        for (int ni = 0; ni < NI; ++ni)
            acc[mi][ni] = (f32x4){0.f, 0.f, 0.f, 0.f};

    constexpr int AIT = (BM * BK / 8) / 256;
    constexpr int BIT = (BN * BK / 8) / 256;

    for (int k0 = 0; k0 < kcount; k0 += BK) {
        int kb = kstart + k0;
#pragma unroll
        for (int i = 0; i < AIT; ++i) {
            int p   = i * 256 + tid;
            int row = p >> 3;
            int kc  = (p & 7) ^ (row & 7);
            const u16* gp = Ab + (long)(m0 + row) * lda + kb + kc * 8;
            gload16(gp, (char*)As + (size_t)(i * 256 + wave * 64) * 16);
        }
#pragma unroll
        for (int i = 0; i < BIT; ++i) {
            int p   = i * 256 + tid;
            int row = p >> 3;
            int kc  = (p & 7) ^ (row & 7);
            const u16* gp = Bb + (long)(n0 + row) * ldb + kb + kc * 8;
            gload16(gp, (char*)Bs + (size_t)(i * 256 + wave * 64) * 16);
        }
        asm volatile("s_waitcnt vmcnt(0)");
        __syncthreads();

        const char* Ac = (const char*)As;
        const char* Bc = (const char*)Bs;
#pragma unroll
        for (int kh = 0; kh < 2; ++kh) {
            bf16x8 af[MI], bfr[NI];
            int kby = kh * 64 + ((lane >> 4) << 4);
#pragma unroll
            for (int mi = 0; mi < MI; ++mi) {
                int r = wmo + mi * 16 + (lane & 15);
                af[mi] = *(const bf16x8*)(Ac + r * 128 + (kby ^ ((r & 7) << 4)));
            }
#pragma unroll
            for (int ni = 0; ni < NI; ++ni) {
                int r = wno + ni * 16 + (lane & 15);
                bfr[ni] = *(const bf16x8*)(Bc + r * 128 + (kby ^ ((r & 7) << 4)));
            }
#pragma unroll
            for (int mi = 0; mi < MI; ++mi)
#pragma unroll
                for (int ni = 0; ni < NI; ++ni)
                    acc[mi][ni] = __builtin_amdgcn_mfma_f32_16x16x32_bf16(
                        af[mi], bfr[ni], acc[mi][ni], 0, 0, 0);
        }
        __syncthreads();
    }

    long cb = zb * bsC1 + zh * bsC2 + (long)pair * pairC;
#pragma unroll
    for (int mi = 0; mi < MI; ++mi) {
#pragma unroll
        for (int ni = 0; ni < NI; ++ni) {
            int col = n0 + wno + ni * 16 + (lane & 15);
            float bv = bias ? bias[col] : 0.f;
#pragma unroll
            for (int j = 0; j < 4; ++j) {
                int row = m0 + wmo + mi * 16 + ((lane >> 4) << 2) + j;
                float v = acc[mi][ni][j] * alpha + bv;
                if (ACT) v = fmaxf(v, 0.f);
                long idx = (long)row * ldc + col + cb;
                if (OUTBF16) ((u16*)Cv)[idx] = f2bf(v);
                else         ((float*)Cv)[idx] = v;
            }
        }
    }
}

// ---------------------------------------------------------------------------
// Fused long-range attention: per (b,h), per 64 q-rows:
// S^T = kc @ q^T (scaled), softmax over r (lane-local + 2 shfl), P->LDS,
// out = P @ vcT. Replaces scores GEMM + rowsoftmax + PV GEMM.
// ---------------------------------------------------------------------------
__global__ __launch_bounds__(256) void attn_k(
    const u16* __restrict__ qb, const u16* __restrict__ kcb,
    const u16* __restrict__ vcT, u16* __restrict__ lngb)
{
    __shared__ u16 Ps[64 * 128];   // P [l][r], XOR-swizzled

    int bh = blockIdx.y;
    int b = bh >> 2, h = bh & 3;
    int l0 = blockIdx.x * 64;
    int tid = threadIdx.x, wave = tid >> 6, lane = tid & 63;
    int c = lane & 15, g = lane >> 4;

    const u16* kc = kcb + (long)b * (RR * DV) + h * 64;           // [128 r][256]
    const u16* qg = qb + ((long)(b * LSEQ + l0)) * DV + h * 64;   // [l][256]
    const u16* vg = vcT + ((long)b * DV + h * 64) * RR;           // [64 dh][128 r]

    // ---- QK^T swapped: acc[mi] = S^T rows r=mi*16+c.., col l = wave*16+c
    f32x4 acc[8];
#pragma unroll
    for (int mi = 0; mi < 8; ++mi) acc[mi] = (f32x4){0.f, 0.f, 0.f, 0.f};

#pragma unroll
    for (int kh = 0; kh < 2; ++kh) {
        bf16x8 bq = *(const bf16x8*)(qg + (long)(wave * 16 + c) * DV + kh * 32 + g * 8);
#pragma unroll
        for (int mi = 0; mi < 8; ++mi) {
            bf16x8 af = *(const bf16x8*)(kc + (long)(mi * 16 + c) * DV + kh * 32 + g * 8);
            acc[mi] = __builtin_amdgcn_mfma_f32_16x16x32_bf16(af, bq, acc[mi], 0, 0, 0);
        }
    }

    // ---- softmax over r (32 in-lane values + lanes ^16, ^32)
    float mx = -INFINITY;
#pragma unroll
    for (int mi = 0; mi < 8; ++mi)
#pragma unroll
        for (int j = 0; j < 4; ++j) {
            acc[mi][j] *= 0.125f;
            mx = fmaxf(mx, acc[mi][j]);
        }
    mx = fmaxf(mx, __shfl_xor(mx, 16));
    mx = fmaxf(mx, __shfl_xor(mx, 32));
    float den = 0.f;
#pragma unroll
    for (int mi = 0; mi < 8; ++mi)
#pragma unroll
        for (int j = 0; j < 4; ++j) {
            acc[mi][j] = __expf(acc[mi][j] - mx);
            den += acc[mi][j];
        }
    den += __shfl_xor(den, 16);
    den += __shfl_xor(den, 32);
    float inv = 1.0f / den;

    // ---- P -> LDS [l][r] bf16, swizzled byte ^ ((l&7)<<4)
    int l = wave * 16 + c;
#pragma unroll
    for (int mi = 0; mi < 8; ++mi) {
        short4 sv;
        sv.x = (short)f2bf(acc[mi][0] * inv);
        sv.y = (short)f2bf(acc[mi][1] * inv);
        sv.z = (short)f2bf(acc[mi][2] * inv);
        sv.w = (short)f2bf(acc[mi][3] * inv);
        int byte = l * 256 + ((mi * 32 + g * 8) ^ ((l & 7) << 4));
        *(short4*)((char*)Ps + byte) = sv;
    }
    __syncthreads();

    // ---- PV: out[l][dh] = P @ vcT
    f32x4 a2[4];
#pragma unroll
    for (int ni = 0; ni < 4; ++ni) a2[ni] = (f32x4){0.f, 0.f, 0.f, 0.f};
#pragma unroll
    for (int kb = 0; kb < 4; ++kb) {
        int kby = kb * 64 + (g << 4);
        bf16x8 pa = *(const bf16x8*)((char*)Ps + l * 256 + (kby ^ ((l & 7) << 4)));
#pragma unroll
        for (int ni = 0; ni < 4; ++ni) {
            bf16x8 vf = *(const bf16x8*)(vg + (long)(ni * 16 + c) * RR + kb * 32 + g * 8);
            a2[ni] = __builtin_amdgcn_mfma_f32_16x16x32_bf16(pa, vf, a2[ni], 0, 0, 0);
        }
    }
#pragma unroll
    for (int ni = 0; ni < 4; ++ni)
#pragma unroll
        for (int j = 0; j < 4; ++j) {
            int lr = wave * 16 + g * 4 + j;
            int dh = ni * 16 + c;
            lngb[((long)(b * LSEQ + l0 + lr)) * DV + h * 64 + dh] = f2bf(a2[ni][j]);
        }
}

// ---------------------------------------------------------------------------
// All weight transposes in one kernel (descriptor table)
// ---------------------------------------------------------------------------
struct WTD { const float* src; u16* dst; int K, N, toff; };
struct WTA { WTD d[9]; };

__global__ __launch_bounds__(256) void wtrans_all_k(WTA a)
{
    int bid = blockIdx.x;
    int di = 0;
#pragma unroll
    for (int i = 1; i < 9; ++i) if (bid >= a.d[i].toff) di = i;
    const float* src = a.d[di].src;
    u16* dst = a.d[di].dst;
    int K = a.d[di].K, N = a.d[di].N;
    int tix = bid - a.d[di].toff;
    int nx = N >> 5;
    int tn = tix % nx, tk = tix / nx;
    int n0 = tn * 32, k0 = tk * 32;

    __shared__ float t[32][33];
    int tx = threadIdx.x & 31, ty = threadIdx.x >> 5;
#pragma unroll
    for (int i = 0; i < 32; i += 8)
        t[ty + i][tx] = src[(long)(k0 + ty + i) * N + n0 + tx];
    __syncthreads();
#pragma unroll
    for (int i = 0; i < 32; i += 8)
        dst[(long)(n0 + ty + i) * K + k0 + tx] = f2bf(t[tx][ty + i]);
}

// bf16 [R][C] -> bf16 [C][R] transpose, batched over z
__global__ __launch_bounds__(256) void ttrans_k(const u16* __restrict__ in,
                                                u16* __restrict__ out,
                                                int R, int C, long isb, long osb)
{
    in  += blockIdx.z * isb;
    out += blockIdx.z * osb;
    __shared__ u16 t[32][33];
    int c0 = blockIdx.x * 32, r0 = blockIdx.y * 32;
    int tx = threadIdx.x & 31, ty = threadIdx.x >> 5;
#pragma unroll
    for (int i = 0; i < 32; i += 8)
        t[ty + i][tx] = in[(long)(r0 + ty + i) * C + c0 + tx];
    __syncthreads();
#pragma unroll
    for (int i = 0; i < 32; i += 8)
        out[(long)(c0 + ty + i) * R + r0 + tx] = t[tx][ty + i];
}

__global__ void cast_bf16_k(const float* __restrict__ in, u16* __restrict__ out, int n)
{
    int i = (blockIdx.x * 256 + threadIdx.x) * 4;
    if (i < n) {
        float4 v = *(const float4*)(in + i);
        out[i]     = f2bf(v.x);
        out[i + 1] = f2bf(v.y);
        out[i + 2] = f2bf(v.z);
        out[i + 3] = f2bf(v.w);
    }
}

__global__ void concat3_k(const float* a, const float* b, const float* c, float* o)
{
    int i = blockIdx.x * 256 + threadIdx.x;
    if (i >= 768) return;
    o[i] = (i < 256) ? a[i] : ((i < 512) ? b[i - 256] : c[i - 512]);
}

// ---------------------------------------------------------------------------
// GAT attention logits: wave-per-row, shfl reduce
// ---------------------------------------------------------------------------
__global__ __launch_bounds__(256) void gat_att_k(
    const u16* __restrict__ h, const float* __restrict__ att_src,
    const float* __restrict__ att_dst, float* __restrict__ a_src,
    float* __restrict__ a_dst)
{
    int row  = blockIdx.x * 4 + (threadIdx.x >> 6);
    int lane = threadIdx.x & 63;
    int c0   = lane * 16;
    int head = lane >> 4;

    float as[16], ad[16];
#pragma unroll
    for (int i = 0; i < 16; ++i) { as[i] = att_src[c0 + i]; ad[i] = att_dst[c0 + i]; }

    const u16* hr = h + (long)row * (HH * DV) + c0;
    bf16x8 v0 = *(const bf16x8*)(hr);
    bf16x8 v1 = *(const bf16x8*)(hr + 8);
    float ps = 0.f, pd = 0.f;
#pragma unroll
    for (int i = 0; i < 8; ++i) {
        float f0 = bf2f((u16)v0[i]), f1 = bf2f((u16)v1[i]);
        ps += f0 * as[i] + f1 * as[i + 8];
        pd += f0 * ad[i] + f1 * ad[i + 8];
    }
#pragma unroll
    for (int m = 1; m <= 8; m <<= 1) {
        ps += __shfl_xor(ps, m);
        pd += __shfl_xor(pd, m);
    }
    if ((lane & 15) == 0) {
        a_src[(long)row * HH + head] = ps;
        a_dst[(long)row * HH + head] = pd;
    }
}

// ---------------------------------------------------------------------------
// CSR build over dst (batch-shared)
// ---------------------------------------------------------------------------
__global__ void csr_count_k(const int* __restrict__ ei, int* __restrict__ cnt)
{
    int i = blockIdx.x * blockDim.x + threadIdx.x;
    if (i >= ETOT) return;
    int dst = (i < EE) ? ei[EE + i] : (i - EE);
    atomicAdd(&cnt[dst], 1);
}

__global__ __launch_bounds__(256) void csr_scan_k(const int* __restrict__ cnt, int* __restrict__ off)
{
    __shared__ int chunk[256];
    int tid = threadIdx.x;
    int base = tid * 8;
    int loc[8];
    int s = 0;
#pragma unroll
    for (int i = 0; i < 8; ++i) { loc[i] = s; s += cnt[base + i]; }
    chunk[tid] = s;
    __syncthreads();
    for (int st = 1; st < 256; st <<= 1) {
        int v = (tid >= st) ? chunk[tid - st] : 0;
        __syncthreads();
        chunk[tid] += v;
        __syncthreads();
    }
    int pre = (tid == 0) ? 0 : chunk[tid - 1];
#pragma unroll
    for (int i = 0; i < 8; ++i) off[base + i] = pre + loc[i];
    if (tid == 255) off[LSEQ] = chunk[255];
}

__global__ void csr_fill_k(const int* __restrict__ ei, const int* __restrict__ off,
                           int* __restrict__ cursor, int* __restrict__ bucket)
{
    int i = blockIdx.x * blockDim.x + threadIdx.x;
    if (i >= ETOT) return;
    int dst = (i < EE) ? ei[EE + i] : (i - EE);
    int p = atomicAdd(&cursor[dst], 1);
    bucket[off[dst] + p] = i;
}

// ---------------------------------------------------------------------------
// GAT scatter-softmax + aggregate, vectorized.
// pass 1: max (shfl reduce). pass 2: exp->LDS + local den + 16B gathers,
// den division deferred to the end.
// ---------------------------------------------------------------------------
__global__ __launch_bounds__(256) void gat_gather_k(
    const u16* __restrict__ h, const int* __restrict__ ei,
    const int* __restrict__ off, const int* __restrict__ bucket,
    const float* __restrict__ a_src, const float* __restrict__ a_dst,
    const float* __restrict__ gat_b, u16* __restrict__ out)
{
    int n = blockIdx.x;
    int b = blockIdx.y;
    int tid = threadIdx.x, wave = tid >> 6, lane = tid & 63;
    int beg = off[n], deg = off[n + 1] - beg;

    const float* asrc_b = a_src + (long)b * LSEQ * HH;
    float adst[HH];
#pragma unroll
    for (int hh = 0; hh < HH; ++hh) adst[hh] = a_dst[((long)b * LSEQ + n) * HH + hh];

    __shared__ float ex_sh[256][4];
    __shared__ int   src_sh[256];
    __shared__ float red[4][4];
    __shared__ float comb[128][9];
    __shared__ float m_sh[4], den_sh[4];

    // pass 1: global max per head
    float mx[4] = { -INFINITY, -INFINITY, -INFINITY, -INFINITY };
    for (int c0 = 0; c0 < deg; c0 += 256) {
        int idx = c0 + tid;
        if (idx < deg) {
            int eid = bucket[beg + idx];
            int src = (eid < EE) ? ei[eid] : (eid - EE);
#pragma unroll
            for (int hh = 0; hh < HH; ++hh) {
                float e = asrc_b[(long)src * HH + hh] + adst[hh];
                e = (e >= 0.f) ? e : 0.2f * e;
                mx[hh] = fmaxf(mx[hh], e);
            }
        }
    }
#pragma unroll
    for (int hh = 0; hh < HH; ++hh) {
        float v = mx[hh];
#pragma unroll
        for (int m = 32; m >= 1; m >>= 1) v = fmaxf(v, __shfl_xor(v, m));
        if (lane == 0) red[wave][hh] = v;
    }
    __syncthreads();
    if (tid < 4) m_sh[tid] = fmaxf(fmaxf(red[0][tid], red[1][tid]),
                                   fmaxf(red[2][tid], red[3][tid]));
    __syncthreads();
    float mloc[4];
#pragma unroll
    for (int hh = 0; hh < HH; ++hh) mloc[hh] = m_sh[hh];

    // pass 2: exp + gather (den applied at end)
    int g = tid >> 7, t = tid & 127;
    int c8 = t * 8, hd = t >> 5;
    float sm[4] = { 0.f, 0.f, 0.f, 0.f };
    float acc[8] = { 0.f, 0.f, 0.f, 0.f, 0.f, 0.f, 0.f, 0.f };
    const u16* hb = h + (long)b * LSEQ * (HH * DV);

    for (int c0 = 0; c0 < deg; c0 += 256) {
        int cn = min(256, deg - c0);
        int idx = c0 + tid;
        if (idx < deg) {
            int eid = bucket[beg + idx];
            int src = (eid < EE) ? ei[eid] : (eid - EE);
            src_sh[tid] = src;
#pragma unroll
            for (int hh = 0; hh < HH; ++hh) {
                float e = asrc_b[(long)src * HH + hh] + adst[hh];
                e = (e >= 0.f) ? e : 0.2f * e;
                float ex = __expf(e - mloc[hh]);
                ex_sh[tid][hh] = ex;
                sm[hh] += ex;
            }
        }
        __syncthreads();
        for (int jj = g; jj < cn; jj += 2) {
            int src = src_sh[jj];
            float al = ex_sh[jj][hd];
            bf16x8 v = *(const bf16x8*)(hb + (long)src * (HH * DV) + c8);
#pragma unroll
            for (int i = 0; i < 8; ++i) acc[i] += al * bf2f((u16)v[i]);
        }
        __syncthreads();
    }

    // reduce den
#pragma unroll
    for (int hh = 0; hh < HH; ++hh) {
        float v = sm[hh];
#pragma unroll
        for (int m = 32; m >= 1; m >>= 1) v += __shfl_xor(v, m);
        if (lane == 0) red[wave][hh] = v;
    }
    __syncthreads();
    if (tid < 4) den_sh[tid] = red[0][tid] + red[1][tid] + red[2][tid] + red[3][tid];
    __syncthreads();

    if (g == 1) {
#pragma unroll
        for (int i = 0; i < 8; ++i) comb[t][i] = acc[i];
    }
    __syncthreads();
    if (g == 0) {
        float inv = 1.0f / den_sh[hd];
        u16 o8[8];
#pragma unroll
        for (int i = 0; i < 8; ++i)
            o8[i] = f2bf((acc[i] + comb[t][i]) * inv + gat_b[c8 + i]);
        *(uint4*)(out + ((long)b * LSEQ + n) * (HH * DV) + c8) = *(uint4*)o8;
    }
}

// ---------------------------------------------------------------------------
// Fused LN of q/k/v segments: grid (ML, 3)
// ---------------------------------------------------------------------------
__global__ __launch_bounds__(256) void ln_cast3_k(
    const float* __restrict__ x,
    const float* g0, const float* b0, const float* g1, const float* b1,
    const float* g2, const float* b2,
    u16* o0, u16* o1, u16* o2)
{
    int seg = blockIdx.y;
    long row = blockIdx.x;
    int tid = threadIdx.x;
    const float* g = (seg == 0) ? g0 : (seg == 1) ? g1 : g2;
    const float* bt = (seg == 0) ? b0 : (seg == 1) ? b1 : b2;
    u16* o = (seg == 0) ? o0 : (seg == 1) ? o1 : o2;

    float v = x[row * 768 + seg * 256 + tid];
    __shared__ float red[256];
    red[tid] = v; __syncthreads();
    for (int s = 128; s > 0; s >>= 1) { if (tid < s) red[tid] += red[tid + s]; __syncthreads(); }
    float mu = red[0] * (1.0f / DV);
    __syncthreads();
    float d = v - mu;
    red[tid] = d * d; __syncthreads();
    for (int s = 128; s > 0; s >>= 1) { if (tid < s) red[tid] += red[tid + s]; __syncthreads(); }
    float r = rsqrtf(red[0] * (1.0f / DV) + 1e-5f);
    o[row * DV + tid] = f2bf(d * r * g[tid] + bt[tid]);
}

// LN of (x0 [+x1] [+x2]) -> fp32 out (+ optional bf16 outb)
__global__ __launch_bounds__(256) void ln3_k(
    const float* __restrict__ x0, const float* __restrict__ x1,
    const float* __restrict__ x2, const float* __restrict__ g,
    const float* __restrict__ bta, float* __restrict__ out,
    u16* __restrict__ outb)
{
    long row = blockIdx.x;
    int tid = threadIdx.x;
    long base = row * DV + tid;
    float v = x0[base];
    if (x1) v += x1[base];
    if (x2) v += x2[base];
    __shared__ float red[256];
    red[tid] = v; __syncthreads();
    for (int s = 128; s > 0; s >>= 1) { if (tid < s) red[tid] += red[tid + s]; __syncthreads(); }
    float mu = red[0] * (1.0f / DV);
    __syncthreads();
    float d = v - mu;
    red[tid] = d * d; __syncthreads();
    for (int s = 128; s > 0; s >>= 1) { if (tid < s) red[tid] += red[tid + s]; __syncthreads(); }
    float r = rsqrtf(red[0] * (1.0f / DV) + 1e-5f);
    float o = d * r * g[tid] + bta[tid];
    out[base] = o;
    if (outb) outb[base] = f2bf(o);
}

// pm softmax over L: single global read pass (row cached in 8 regs)
__global__ __launch_bounds__(256) void colsoftmax_k(const float* __restrict__ pm,
                                                    u16* __restrict__ pmT)
{
    int r = blockIdx.x;
    int b = blockIdx.y;
    int tid = threadIdx.x, wave = tid >> 6, lane = tid & 63;
    const float* base = pm + (long)b * LSEQ * RR + r;
    u16* obase = pmT + ((long)b * RR + r) * LSEQ;

    float x[8];
#pragma unroll
    for (int i = 0; i < 8; ++i) x[i] = base[(long)(tid + i * 256) * RR];

    __shared__ float red[4];
    __shared__ float m_sh, d_sh;
    float mx = x[0];
#pragma unroll
    for (int i = 1; i < 8; ++i) mx = fmaxf(mx, x[i]);
#pragma unroll
    for (int m = 32; m >= 1; m >>= 1) mx = fmaxf(mx, __shfl_xor(mx, m));
    if (lane == 0) red[wave] = mx;
    __syncthreads();
    if (tid == 0) m_sh = fmaxf(fmaxf(red[0], red[1]), fmaxf(red[2], red[3]));
    __syncthreads();
    float m = m_sh;
    float sm = 0.f;
#pragma unroll
    for (int i = 0; i < 8; ++i) { x[i] = __expf(x[i] - m); sm += x[i]; }
#pragma unroll
    for (int mm = 32; mm >= 1; mm >>= 1) sm += __shfl_xor(sm, mm);
    if (lane == 0) red[wave] = sm;
    __syncthreads();
    if (tid == 0) d_sh = red[0] + red[1] + red[2] + red[3];
    __syncthreads();
    float inv = 1.0f / d_sh;
#pragma unroll
    for (int i = 0; i < 8; ++i) obase[tid + i * 256] = f2bf(x[i] * inv);
}

// sum 8 split-K partials -> bf16 kvc
__global__ void reduce_kvc_k(const float* __restrict__ part, u16* __restrict__ kvcb)
{
    int i = blockIdx.x * 256 + threadIdx.x;
    int bb = i >> 15, e = i & 32767;
    float s = 0.f;
#pragma unroll
    for (int s8 = 0; s8 < 8; ++s8) s += part[(long)(bb * 8 + s8) * 32768 + e];
    kvcb[i] = f2bf(s);
}

// ---------------------------------------------------------------------------
extern "C" void kernel_launch(void* const* d_in, const int* in_sizes, int n_in,
                              void* d_out, int out_size, void* d_ws, size_t ws_size,
                              hipStream_t stream)
{
    const float* s        = (const float*)d_in[0];
    const float* gat_W    = (const float*)d_in[1];
    const float* att_src  = (const float*)d_in[2];
    const float* att_dst  = (const float*)d_in[3];
    const float* gat_b    = (const float*)d_in[4];
    const float* short_W  = (const float*)d_in[5];
    const float* short_b  = (const float*)d_in[6];
    const float* q_W      = (const float*)d_in[7];
    const float* q_b      = (const float*)d_in[8];
    const float* k_W      = (const float*)d_in[9];
    const float* k_b      = (const float*)d_in[10];
    const float* v_W      = (const float*)d_in[11];
    const float* v_b      = (const float*)d_in[12];
    const float* o_W      = (const float*)d_in[13];
    const float* o_b      = (const float*)d_in[14];
    const float* p_W      = (const float*)d_in[15];
    const float* p_b      = (const float*)d_in[16];
    const float* lnq_g    = (const float*)d_in[17];
    const float* lnq_b    = (const float*)d_in[18];
    const float* lnk_g    = (const float*)d_in[19];
    const float* lnk_b    = (const float*)d_in[20];
    const float* lnv_g    = (const float*)d_in[21];
    const float* lnv_b    = (const float*)d_in[22];
    const float* ln1_g    = (const float*)d_in[23];
    const float* ln1_b    = (const float*)d_in[24];
    const float* ln2_g    = (const float*)d_in[25];
    const float* ln2_b    = (const float*)d_in[26];
    const float* f1_W     = (const float*)d_in[27];
    const float* f1_b     = (const float*)d_in[28];
    const float* f2_W     = (const float*)d_in[29];
    const float* f2_b     = (const float*)d_in[30];
    const int*   ei       = (const int*)d_in[31];
    float* out = (float*)d_out;

    const size_t MB = 1024 * 1024;
    char* W = (char*)d_ws;
    u16*   sb      = (u16*)(W);                         // 4MB
    u16*   gatT    = (u16*)(W + 4*MB);                  // 512KB
    u16*   shortT  = (u16*)(W + 4*MB + 524288);         // 512KB
    u16*   qkvT    = (u16*)(W + 4*MB + 1048576);        // 384KB
    u16*   oT      = (u16*)(W + 4*MB + 1441792);        // 128KB
    u16*   pT      = (u16*)(W + 4*MB + 1572864);        // 64KB
    u16*   f1T     = (u16*)(W + 4*MB + 1638400);        // 512KB
    u16*   f2T     = (u16*)(W + 4*MB + 2162688);        // 512KB
    float* qkvb    = (float*)(W + 4*MB + 2686976);      // 3KB
    int*   ioff    = (int*)(W + 4*MB + 2690048);        // 2049
    int*   icnt    = (int*)(W + 4*MB + 2699264);        // 2048
    int*   ibucket = (int*)(W + 4*MB + 2707456);        // 34816
    u16*   h       = (u16*)(W + 8*MB);                  // 16MB
    float* part    = (float*)(W + 16*MB);               // 8MB
    u16*   ffh     = (u16*)(W + 8*MB);                  // alias h
    u16*   gat_out = (u16*)(W + 24*MB);                 // 16MB
    float* h1      = (float*)(W + 24*MB);               // alias (8MB)
    u16*   h1b     = (u16*)(W + 32*MB);                 // alias (4MB)
    float* shortb  = (float*)(W + 40*MB);               // 8MB
    float* qkv     = (float*)(W + 48*MB);               // 24MB (dead after ln_cast3)
    float* pmraw   = (float*)(W + 48*MB);               // alias 4MB
    u16*   lngb    = (u16*)(W + 48*MB);                 // alias (4MB, after qkv dead)
    float* lng2    = (float*)(W + 64*MB);               // 8MB
    u16*   qb      = (u16*)(W + 72*MB);                 // 4MB
    u16*   kvb     = (u16*)(W + 76*MB);                 // 8MB
    float* ff2     = (float*)(W + 76*MB);               // alias (after kvb dead)
    u16*   kvT     = (u16*)(W + 84*MB);                 // 8MB
    u16*   pmT     = (u16*)(W + 92*MB);                 // 2MB
    u16*   kvcb    = (u16*)(W + 94*MB);                 // 512KB [2][4][128][256]
    u16*   vcT     = (u16*)(W + 94*MB + 524288);        // 256KB [4][256][128]
    float* a_src   = (float*)(W + 95*MB);               // 128KB
    float* a_dst   = (float*)(W + 95*MB + 131072);      // 128KB

    const int ML = BB * LSEQ;  // 8192

    // ---- weights -> bf16 transposed (single kernel) ----
    WTA wa;
    wa.d[0] = { gat_W,   gatT,            256, 1024, 0    };
    wa.d[1] = { short_W, shortT,         1024,  256, 256  };
    wa.d[2] = { q_W,     qkvT,            256,  256, 512  };
    wa.d[3] = { k_W,     qkvT + 65536,    256,  256, 576  };
    wa.d[4] = { v_W,     qkvT + 131072,   256,  256, 640  };
    wa.d[5] = { o_W,     oT,              256,  256, 704  };
    wa.d[6] = { p_W,     pT,              256,  128, 768  };
    wa.d[7] = { f1_W,    f1T,             256, 1024, 800  };
    wa.d[8] = { f2_W,    f2T,            1024,  256, 1056 };
    wtrans_all_k<<<1312, 256, 0, stream>>>(wa);
    concat3_k<<<3, 256, 0, stream>>>(q_b, k_b, v_b, qkvb);
    cast_bf16_k<<<2048, 256, 0, stream>>>(s, sb, ML * DV);

    // ---- CSR ----
    hipMemsetAsync(icnt, 0, LSEQ * sizeof(int), stream);
    csr_count_k<<<(ETOT + 255) / 256, 256, 0, stream>>>(ei, icnt);
    csr_scan_k<<<1, 256, 0, stream>>>(icnt, ioff);
    hipMemsetAsync(icnt, 0, LSEQ * sizeof(int), stream);
    csr_fill_k<<<(ETOT + 255) / 256, 256, 0, stream>>>(ei, ioff, icnt, ibucket);

    // ---- GAT ----
    mfma_gemm_k<128, 1, 0><<<dim3(8, 64, 1), 256, 0, stream>>>(
        sb, gatT, nullptr, h, ML, 1024, 256, 256, 256, 1024,
        0, 0, 0, 0, 0, 0, 1, 0, 0, 0, 0, 1.f);
    gat_att_k<<<ML / 4, 256, 0, stream>>>(h, att_src, att_dst, a_src, a_dst);
    gat_gather_k<<<dim3(LSEQ, BB), 256, 0, stream>>>(h, ei, ioff, ibucket,
                                                     a_src, a_dst, gat_b, gat_out);
    mfma_gemm_k<128, 0, 0><<<dim3(2, 64, 1), 256, 0, stream>>>(
        gat_out, shortT, short_b, shortb, ML, 256, 1024, 1024, 1024, 256,
        0, 0, 0, 0, 0, 0, 1, 0, 0, 0, 0, 1.f);

    // ---- qkv projections + LN ----
    mfma_gemm_k<128, 0, 0><<<dim3(6, 64, 1), 256, 0, stream>>>(
        sb, qkvT, qkvb, qkv, ML, 768, 256, 256, 256, 768,
        0, 0, 0, 0, 0, 0, 1, 0, 0, 0, 0, 1.f);
    ln_cast3_k<<<dim3(ML, 3), 256, 0, stream>>>(qkv, lnq_g, lnq_b, lnk_g, lnk_b,
                                                lnv_g, lnv_b, qb, kvb, kvb + 2097152);

    // pm = softmax_L(k @ p_W + p_b) -> pmT bf16 [b][r][l]
    mfma_gemm_k<128, 0, 0><<<dim3(1, 64, 1), 256, 0, stream>>>(
        kvb, pT, p_b, pmraw, ML, 128, 256, 256, 256, 128,
        0, 0, 0, 0, 0, 0, 1, 0, 0, 0, 0, 1.f);
    colsoftmax_k<<<dim3(RR, BB), 256, 0, stream>>>(pmraw, pmT);

    // k,v -> L-major kvT [2][4][256][2048]
    ttrans_k<<<dim3(8, 64, 8), 256, 0, stream>>>(kvb, kvT, 2048, 256, 524288, 524288);

    // k_c/v_c via split-K
    mfma_gemm_k<128, 0, 0><<<dim3(2, 2, 32), 256, 0, stream>>>(
        pmT, kvT, nullptr, part, 128, 256, 2048, 2048, 2048, 256,
        262144, 0, 524288, 0, 262144, 32768, 8, 2097152, 1048576, 256, 1, 1.f);
    reduce_kvc_k<<<1024, 256, 0, stream>>>(part, kvcb);
    ttrans_k<<<dim3(8, 4, 4), 256, 0, stream>>>(kvcb + 131072, vcT, 128, 256, 32768, 32768);

    // ---- fused attention: scores + softmax + PV ----
    attn_k<<<dim3(LSEQ / 64, BB * HH), 256, 0, stream>>>(qb, kvcb, vcT, lngb);

    // lng2 = lng @ o_W + o_b
    mfma_gemm_k<128, 0, 0><<<dim3(2, 64, 1), 256, 0, stream>>>(
        lngb, oT, o_b, lng2, ML, 256, 256, 256, 256, 256,
        0, 0, 0, 0, 0, 0, 1, 0, 0, 0, 0, 1.f);

    // h1 = LN(s + short + lng2)
    ln3_k<<<ML, 256, 0, stream>>>(s, shortb, lng2, ln1_g, ln1_b, h1, h1b);

    // FFN
    mfma_gemm_k<128, 1, 1><<<dim3(8, 64, 1), 256, 0, stream>>>(
        h1b, f1T, f1_b, ffh, ML, 1024, 256, 256, 256, 1024,
        0, 0, 0, 0, 0, 0, 1, 0, 0, 0, 0, 1.f);
    mfma_gemm_k<128, 0, 0><<<dim3(2, 64, 1), 256, 0, stream>>>(
        ffh, f2T, f2_b, ff2, ML, 256, 1024, 1024, 1024, 256,
        0, 0, 0, 0, 0, 0, 1, 0, 0, 0, 0, 1.f);

    // out = LN(h1 + ff2)
    ln3_k<<<ML, 256, 0, stream>>>(h1, ff2, nullptr, ln2_g, ln2_b, out, nullptr);
}

// Round 4
// 247.303 us; speedup vs baseline: 5.4305x; 1.1076x over previous
//
#include <hip/hip_runtime.h>
#include <math.h>

#define BB   4
#define LSEQ 2048
#define DV   256
#define HH   4
#define RR   128
#define EE   32768
#define ETOT (EE + LSEQ)
#define FFD  1024

typedef unsigned short u16;
typedef __attribute__((ext_vector_type(8))) short bf16x8;
typedef __attribute__((ext_vector_type(4))) float f32x4;

__device__ __forceinline__ u16 f2bf(float f) {
    union { float f; unsigned u; } x; x.f = f;
    unsigned r = x.u + 0x7fff + ((x.u >> 16) & 1);
    return (u16)(r >> 16);
}
__device__ __forceinline__ float bf2f(u16 u) {
    union { unsigned u; float f; } x; x.u = ((unsigned)u) << 16;
    return x.f;
}

__device__ __forceinline__ void gload16(const void* g, void* l) {
    __builtin_amdgcn_global_load_lds(
        (const __attribute__((address_space(1))) unsigned int*)g,
        (__attribute__((address_space(3))) unsigned int*)l, 16, 0, 0);
}

// ---------------------------------------------------------------------------
// bf16 MFMA GEMM. BM in {128,64}, BN in {128,64}, BK=64.
// C[m,n] = act(alpha * sum_k A[m,k]*BT[n,k] + bias[n])
// ---------------------------------------------------------------------------
template<int BM, int BN, int OUTBF16, int ACT>
__global__ __launch_bounds__(256) void mfma_gemm_k(
    const u16* __restrict__ A, const u16* __restrict__ BT,
    const float* __restrict__ bias, void* __restrict__ Cv,
    int M, int N, int K, int lda, int ldb, int ldc,
    long bsA1, long bsA2, long bsB1, long bsB2, long bsC1, long bsC2,
    int subH, long pairB, long pairC, int ksl, int split, float alpha)
{
    constexpr int BK = 64;
    __shared__ u16 As[BM * BK];
    __shared__ u16 Bs[BN * BK];

    int z = blockIdx.z;
    int zb = z / subH, zh = z - zb * subH;
    int mtiles = M / BM;
    int pair = blockIdx.y / mtiles;
    int mt   = blockIdx.y - pair * mtiles;

    const u16* Ab = A  + zb * bsA1 + zh * bsA2;
    const u16* Bb = BT + zb * bsB1 + zh * bsB2 + (long)pair * pairB;
    int kstart = split ? zh * ksl : 0;
    int kcount = split ? ksl : K;
    int m0 = mt * BM, n0 = blockIdx.x * BN;

    int tid  = threadIdx.x;
    int wave = tid >> 6, lane = tid & 63;
    constexpr int WGN = (BN == 128) ? 2 : 1;
    constexpr int WGM = 4 / WGN;
    constexpr int MI  = BM / (WGM * 16);
    constexpr int NI  = BN / (WGN * 16);   // 4
    int wm = wave / WGN, wn = wave - wm * WGN;
    int wmo = wm * (MI * 16);
    int wno = wn * (NI * 16);

    f32x4 acc[MI][NI];
#pragma unroll
    for (int mi = 0; mi < MI; ++mi)
#pragma unroll
        for (int ni = 0; ni < NI; ++ni)
            acc[mi][ni] = (f32x4){0.f, 0.f, 0.f, 0.f};

    constexpr int AIT = (BM * BK / 8) / 256;
    constexpr int BIT = (BN * BK / 8) / 256;

    for (int k0 = 0; k0 < kcount; k0 += BK) {
        int kb = kstart + k0;
#pragma unroll
        for (int i = 0; i < AIT; ++i) {
            int p   = i * 256 + tid;
            int row = p >> 3;
            int kc  = (p & 7) ^ (row & 7);
            const u16* gp = Ab + (long)(m0 + row) * lda + kb + kc * 8;
            gload16(gp, (char*)As + (size_t)(i * 256 + wave * 64) * 16);
        }
#pragma unroll
        for (int i = 0; i < BIT; ++i) {
            int p   = i * 256 + tid;
            int row = p >> 3;
            int kc  = (p & 7) ^ (row & 7);
            const u16* gp = Bb + (long)(n0 + row) * ldb + kb + kc * 8;
            gload16(gp, (char*)Bs + (size_t)(i * 256 + wave * 64) * 16);
        }
        asm volatile("s_waitcnt vmcnt(0)");
        __syncthreads();

        const char* Ac = (const char*)As;
        const char* Bc = (const char*)Bs;
#pragma unroll
        for (int kh = 0; kh < 2; ++kh) {
            bf16x8 af[MI], bfr[NI];
            int kby = kh * 64 + ((lane >> 4) << 4);
#pragma unroll
            for (int mi = 0; mi < MI; ++mi) {
                int r = wmo + mi * 16 + (lane & 15);
                af[mi] = *(const bf16x8*)(Ac + r * 128 + (kby ^ ((r & 7) << 4)));
            }
#pragma unroll
            for (int ni = 0; ni < NI; ++ni) {
                int r = wno + ni * 16 + (lane & 15);
                bfr[ni] = *(const bf16x8*)(Bc + r * 128 + (kby ^ ((r & 7) << 4)));
            }
#pragma unroll
            for (int mi = 0; mi < MI; ++mi)
#pragma unroll
                for (int ni = 0; ni < NI; ++ni)
                    acc[mi][ni] = __builtin_amdgcn_mfma_f32_16x16x32_bf16(
                        af[mi], bfr[ni], acc[mi][ni], 0, 0, 0);
        }
        __syncthreads();
    }

    long cb = zb * bsC1 + zh * bsC2 + (long)pair * pairC;
#pragma unroll
    for (int mi = 0; mi < MI; ++mi) {
#pragma unroll
        for (int ni = 0; ni < NI; ++ni) {
            int col = n0 + wno + ni * 16 + (lane & 15);
            float bv = bias ? bias[col] : 0.f;
#pragma unroll
            for (int j = 0; j < 4; ++j) {
                int row = m0 + wmo + mi * 16 + ((lane >> 4) << 2) + j;
                float v = acc[mi][ni][j] * alpha + bv;
                if (ACT) v = fmaxf(v, 0.f);
                long idx = (long)row * ldc + col + cb;
                if (OUTBF16) ((u16*)Cv)[idx] = f2bf(v);
                else         ((float*)Cv)[idx] = v;
            }
        }
    }
}

// ---------------------------------------------------------------------------
// Fused long-range attention (unchanged, verified round 2)
// ---------------------------------------------------------------------------
__global__ __launch_bounds__(256) void attn_k(
    const u16* __restrict__ qb, const u16* __restrict__ kcb,
    const u16* __restrict__ vcT, u16* __restrict__ lngb)
{
    __shared__ u16 Ps[64 * 128];

    int bh = blockIdx.y;
    int b = bh >> 2, h = bh & 3;
    int l0 = blockIdx.x * 64;
    int tid = threadIdx.x, wave = tid >> 6, lane = tid & 63;
    int c = lane & 15, g = lane >> 4;

    const u16* kc = kcb + (long)b * (RR * DV) + h * 64;
    const u16* qg = qb + ((long)(b * LSEQ + l0)) * DV + h * 64;
    const u16* vg = vcT + ((long)b * DV + h * 64) * RR;

    f32x4 acc[8];
#pragma unroll
    for (int mi = 0; mi < 8; ++mi) acc[mi] = (f32x4){0.f, 0.f, 0.f, 0.f};

#pragma unroll
    for (int kh = 0; kh < 2; ++kh) {
        bf16x8 bq = *(const bf16x8*)(qg + (long)(wave * 16 + c) * DV + kh * 32 + g * 8);
#pragma unroll
        for (int mi = 0; mi < 8; ++mi) {
            bf16x8 af = *(const bf16x8*)(kc + (long)(mi * 16 + c) * DV + kh * 32 + g * 8);
            acc[mi] = __builtin_amdgcn_mfma_f32_16x16x32_bf16(af, bq, acc[mi], 0, 0, 0);
        }
    }

    float mx = -INFINITY;
#pragma unroll
    for (int mi = 0; mi < 8; ++mi)
#pragma unroll
        for (int j = 0; j < 4; ++j) {
            acc[mi][j] *= 0.125f;
            mx = fmaxf(mx, acc[mi][j]);
        }
    mx = fmaxf(mx, __shfl_xor(mx, 16));
    mx = fmaxf(mx, __shfl_xor(mx, 32));
    float den = 0.f;
#pragma unroll
    for (int mi = 0; mi < 8; ++mi)
#pragma unroll
        for (int j = 0; j < 4; ++j) {
            acc[mi][j] = __expf(acc[mi][j] - mx);
            den += acc[mi][j];
        }
    den += __shfl_xor(den, 16);
    den += __shfl_xor(den, 32);
    float inv = 1.0f / den;

    int l = wave * 16 + c;
#pragma unroll
    for (int mi = 0; mi < 8; ++mi) {
        short4 sv;
        sv.x = (short)f2bf(acc[mi][0] * inv);
        sv.y = (short)f2bf(acc[mi][1] * inv);
        sv.z = (short)f2bf(acc[mi][2] * inv);
        sv.w = (short)f2bf(acc[mi][3] * inv);
        int byte = l * 256 + ((mi * 32 + g * 8) ^ ((l & 7) << 4));
        *(short4*)((char*)Ps + byte) = sv;
    }
    __syncthreads();

    f32x4 a2[4];
#pragma unroll
    for (int ni = 0; ni < 4; ++ni) a2[ni] = (f32x4){0.f, 0.f, 0.f, 0.f};
#pragma unroll
    for (int kb = 0; kb < 4; ++kb) {
        int kby = kb * 64 + (g << 4);
        bf16x8 pa = *(const bf16x8*)((char*)Ps + l * 256 + (kby ^ ((l & 7) << 4)));
#pragma unroll
        for (int ni = 0; ni < 4; ++ni) {
            bf16x8 vf = *(const bf16x8*)(vg + (long)(ni * 16 + c) * RR + kb * 32 + g * 8);
            a2[ni] = __builtin_amdgcn_mfma_f32_16x16x32_bf16(pa, vf, a2[ni], 0, 0, 0);
        }
    }
#pragma unroll
    for (int ni = 0; ni < 4; ++ni)
#pragma unroll
        for (int j = 0; j < 4; ++j) {
            int lr = wave * 16 + g * 4 + j;
            int dh = ni * 16 + c;
            lngb[((long)(b * LSEQ + l0 + lr)) * DV + h * 64 + dh] = f2bf(a2[ni][j]);
        }
}

// ---------------------------------------------------------------------------
// All weight transposes in one kernel
// ---------------------------------------------------------------------------
struct WTD { const float* src; u16* dst; int K, N, toff; };
struct WTA { WTD d[9]; };

__global__ __launch_bounds__(256) void wtrans_all_k(WTA a)
{
    int bid = blockIdx.x;
    int di = 0;
#pragma unroll
    for (int i = 1; i < 9; ++i) if (bid >= a.d[i].toff) di = i;
    const float* src = a.d[di].src;
    u16* dst = a.d[di].dst;
    int K = a.d[di].K, N = a.d[di].N;
    int tix = bid - a.d[di].toff;
    int nx = N >> 5;
    int tn = tix % nx, tk = tix / nx;
    int n0 = tn * 32, k0 = tk * 32;

    __shared__ float t[32][33];
    int tx = threadIdx.x & 31, ty = threadIdx.x >> 5;
#pragma unroll
    for (int i = 0; i < 32; i += 8)
        t[ty + i][tx] = src[(long)(k0 + ty + i) * N + n0 + tx];
    __syncthreads();
#pragma unroll
    for (int i = 0; i < 32; i += 8)
        dst[(long)(n0 + ty + i) * K + k0 + tx] = f2bf(t[tx][ty + i]);
}

// bf16 [R][C] -> bf16 [C][R] transpose, batched over z
__global__ __launch_bounds__(256) void ttrans_k(const u16* __restrict__ in,
                                                u16* __restrict__ out,
                                                int R, int C, long isb, long osb)
{
    in  += blockIdx.z * isb;
    out += blockIdx.z * osb;
    __shared__ u16 t[32][33];
    int c0 = blockIdx.x * 32, r0 = blockIdx.y * 32;
    int tx = threadIdx.x & 31, ty = threadIdx.x >> 5;
#pragma unroll
    for (int i = 0; i < 32; i += 8)
        t[ty + i][tx] = in[(long)(r0 + ty + i) * C + c0 + tx];
    __syncthreads();
#pragma unroll
    for (int i = 0; i < 32; i += 8)
        out[(long)(c0 + ty + i) * R + r0 + tx] = t[tx][ty + i];
}

// s -> bf16 cast + qkv bias concat, one kernel
__global__ void castcat_k(const float* __restrict__ in, u16* __restrict__ out,
                          const float* qb_, const float* kb_, const float* vb_,
                          float* qkvb)
{
    int bid = blockIdx.x;
    if (bid < 2048) {
        int i = (bid * 256 + threadIdx.x) * 4;
        float4 v = *(const float4*)(in + i);
        out[i]     = f2bf(v.x);
        out[i + 1] = f2bf(v.y);
        out[i + 2] = f2bf(v.z);
        out[i + 3] = f2bf(v.w);
    } else {
        int i = (bid - 2048) * 256 + threadIdx.x;
        if (i < 768)
            qkvb[i] = (i < 256) ? qb_[i] : ((i < 512) ? kb_[i - 256] : vb_[i - 512]);
    }
}

// ---------------------------------------------------------------------------
// GAT attention logits: wave-per-row, shfl reduce
// ---------------------------------------------------------------------------
__global__ __launch_bounds__(256) void gat_att_k(
    const u16* __restrict__ h, const float* __restrict__ att_src,
    const float* __restrict__ att_dst, float* __restrict__ a_src,
    float* __restrict__ a_dst)
{
    int row  = blockIdx.x * 4 + (threadIdx.x >> 6);
    int lane = threadIdx.x & 63;
    int c0   = lane * 16;
    int head = lane >> 4;

    float as[16], ad[16];
#pragma unroll
    for (int i = 0; i < 16; ++i) { as[i] = att_src[c0 + i]; ad[i] = att_dst[c0 + i]; }

    const u16* hr = h + (long)row * (HH * DV) + c0;
    bf16x8 v0 = *(const bf16x8*)(hr);
    bf16x8 v1 = *(const bf16x8*)(hr + 8);
    float ps = 0.f, pd = 0.f;
#pragma unroll
    for (int i = 0; i < 8; ++i) {
        float f0 = bf2f((u16)v0[i]), f1 = bf2f((u16)v1[i]);
        ps += f0 * as[i] + f1 * as[i + 8];
        pd += f0 * ad[i] + f1 * ad[i + 8];
    }
#pragma unroll
    for (int m = 1; m <= 8; m <<= 1) {
        ps += __shfl_xor(ps, m);
        pd += __shfl_xor(pd, m);
    }
    if ((lane & 15) == 0) {
        a_src[(long)row * HH + head] = ps;
        a_dst[(long)row * HH + head] = pd;
    }
}

// ---------------------------------------------------------------------------
// CSR build over dst (batch-shared)
// ---------------------------------------------------------------------------
__global__ void csr_count_k(const int* __restrict__ ei, int* __restrict__ cnt)
{
    int i = blockIdx.x * blockDim.x + threadIdx.x;
    if (i >= ETOT) return;
    int dst = (i < EE) ? ei[EE + i] : (i - EE);
    atomicAdd(&cnt[dst], 1);
}

__global__ __launch_bounds__(256) void csr_scan_k(const int* __restrict__ cnt, int* __restrict__ off)
{
    __shared__ int chunk[256];
    int tid = threadIdx.x;
    int base = tid * 8;
    int loc[8];
    int s = 0;
#pragma unroll
    for (int i = 0; i < 8; ++i) { loc[i] = s; s += cnt[base + i]; }
    chunk[tid] = s;
    __syncthreads();
    for (int st = 1; st < 256; st <<= 1) {
        int v = (tid >= st) ? chunk[tid - st] : 0;
        __syncthreads();
        chunk[tid] += v;
        __syncthreads();
    }
    int pre = (tid == 0) ? 0 : chunk[tid - 1];
#pragma unroll
    for (int i = 0; i < 8; ++i) off[base + i] = pre + loc[i];
    if (tid == 255) off[LSEQ] = chunk[255];
}

// fill uses atomicSub on counts (no second memset needed)
__global__ void csr_fill_k(const int* __restrict__ ei, const int* __restrict__ off,
                           int* __restrict__ cnt, int* __restrict__ bucket)
{
    int i = blockIdx.x * blockDim.x + threadIdx.x;
    if (i >= ETOT) return;
    int dst = (i < EE) ? ei[EE + i] : (i - EE);
    int p = atomicSub(&cnt[dst], 1) - 1;
    bucket[off[dst] + p] = i;
}

// ---------------------------------------------------------------------------
// GAT scatter-softmax + aggregate: ONE WAVE PER (b,n).
// ---------------------------------------------------------------------------
__global__ __launch_bounds__(256) void gat_gather_k(
    const u16* __restrict__ h, const int* __restrict__ ei,
    const int* __restrict__ off, const int* __restrict__ bucket,
    const float* __restrict__ a_src, const float* __restrict__ a_dst,
    const float* __restrict__ gat_b, u16* __restrict__ out)
{
    int wv = threadIdx.x >> 6, lane = threadIdx.x & 63;
    int n = blockIdx.x * 4 + wv;
    int b = blockIdx.y;
    int beg = off[n], deg = off[n + 1] - beg;

    __shared__ int   src_sh[4][64];
    __shared__ float ex_sh[4][64][4];
    __shared__ int   cmax_sh;

    if (threadIdx.x == 0) cmax_sh = 0;
    __syncthreads();
    if (lane == 0) atomicMax(&cmax_sh, (deg + 63) >> 6);
    __syncthreads();
    int cmax = cmax_sh;

    const float* asrc_b = a_src + (long)b * LSEQ * HH;
    const float4 ad4 = *(const float4*)(a_dst + ((long)b * LSEQ + n) * HH);
    float adst[4] = { ad4.x, ad4.y, ad4.z, ad4.w };

    // pass 1: global max per head (wave shfl reduce)
    float mx[4] = { -INFINITY, -INFINITY, -INFINITY, -INFINITY };
    for (int c0 = 0; c0 < deg; c0 += 64) {
        int idx = c0 + lane;
        if (idx < deg) {
            int eid = bucket[beg + idx];
            int src = (eid < EE) ? ei[eid] : (eid - EE);
            float4 as4 = *(const float4*)(asrc_b + (long)src * HH);
            float as[4] = { as4.x, as4.y, as4.z, as4.w };
#pragma unroll
            for (int hh = 0; hh < 4; ++hh) {
                float e = as[hh] + adst[hh];
                e = (e >= 0.f) ? e : 0.2f * e;
                mx[hh] = fmaxf(mx[hh], e);
            }
        }
    }
#pragma unroll
    for (int hh = 0; hh < 4; ++hh)
#pragma unroll
        for (int m = 32; m >= 1; m >>= 1)
            mx[hh] = fmaxf(mx[hh], __shfl_xor(mx[hh], m));

    // pass 2: exp -> LDS, gather with all 64 lanes (32B per lane per edge)
    int hd = lane >> 4;
    const u16* hb = h + (long)b * LSEQ * (HH * DV) + lane * 16;
    float acc[16];
#pragma unroll
    for (int i = 0; i < 16; ++i) acc[i] = 0.f;
    float sm[4] = { 0.f, 0.f, 0.f, 0.f };

    for (int ci = 0; ci < cmax; ++ci) {
        int c0 = ci * 64;
        int idx = c0 + lane;
        if (idx < deg) {
            int eid = bucket[beg + idx];
            int src = (eid < EE) ? ei[eid] : (eid - EE);
            src_sh[wv][lane] = src;
            float4 as4 = *(const float4*)(asrc_b + (long)src * HH);
            float as[4] = { as4.x, as4.y, as4.z, as4.w };
#pragma unroll
            for (int hh = 0; hh < 4; ++hh) {
                float e = as[hh] + adst[hh];
                e = (e >= 0.f) ? e : 0.2f * e;
                float ex = __expf(e - mx[hh]);
                ex_sh[wv][lane][hh] = ex;
                sm[hh] += ex;
            }
        }
        __syncthreads();
        int cn = deg - c0; if (cn > 64) cn = 64;
#pragma unroll 2
        for (int j = 0; j < cn; ++j) {
            int src = src_sh[wv][j];
            float al = ex_sh[wv][j][hd];
            const u16* p = hb + (long)src * (HH * DV);
            bf16x8 v0 = *(const bf16x8*)p;
            bf16x8 v1 = *(const bf16x8*)(p + 8);
#pragma unroll
            for (int i = 0; i < 8; ++i) {
                acc[i]     += al * bf2f((u16)v0[i]);
                acc[i + 8] += al * bf2f((u16)v1[i]);
            }
        }
        __syncthreads();
    }

#pragma unroll
    for (int hh = 0; hh < 4; ++hh)
#pragma unroll
        for (int m = 32; m >= 1; m >>= 1)
            sm[hh] += __shfl_xor(sm[hh], m);
    float inv = 1.0f / sm[hd];

    u16 o16[16];
    const float* gb = gat_b + lane * 16;
#pragma unroll
    for (int i = 0; i < 16; ++i) o16[i] = f2bf(acc[i] * inv + gb[i]);
    uint4* op = (uint4*)(out + ((long)b * LSEQ + n) * (HH * DV) + lane * 16);
    op[0] = ((uint4*)o16)[0];
    op[1] = ((uint4*)o16)[1];
}

// ---------------------------------------------------------------------------
// Fused LN of q/k/v segments: grid (ML, 3)
// ---------------------------------------------------------------------------
__global__ __launch_bounds__(256) void ln_cast3_k(
    const float* __restrict__ x,
    const float* g0, const float* b0, const float* g1, const float* b1,
    const float* g2, const float* b2,
    u16* o0, u16* o1, u16* o2)
{
    int seg = blockIdx.y;
    long row = blockIdx.x;
    int tid = threadIdx.x;
    const float* g = (seg == 0) ? g0 : (seg == 1) ? g1 : g2;
    const float* bt = (seg == 0) ? b0 : (seg == 1) ? b1 : b2;
    u16* o = (seg == 0) ? o0 : (seg == 1) ? o1 : o2;

    float v = x[row * 768 + seg * 256 + tid];
    __shared__ float red[256];
    red[tid] = v; __syncthreads();
    for (int s = 128; s > 0; s >>= 1) { if (tid < s) red[tid] += red[tid + s]; __syncthreads(); }
    float mu = red[0] * (1.0f / DV);
    __syncthreads();
    float d = v - mu;
    red[tid] = d * d; __syncthreads();
    for (int s = 128; s > 0; s >>= 1) { if (tid < s) red[tid] += red[tid + s]; __syncthreads(); }
    float r = rsqrtf(red[0] * (1.0f / DV) + 1e-5f);
    o[row * DV + tid] = f2bf(d * r * g[tid] + bt[tid]);
}

// LN of (x0 [+x1] [+x2]) -> fp32 out (+ optional bf16 outb)
__global__ __launch_bounds__(256) void ln3_k(
    const float* __restrict__ x0, const float* __restrict__ x1,
    const float* __restrict__ x2, const float* __restrict__ g,
    const float* __restrict__ bta, float* __restrict__ out,
    u16* __restrict__ outb)
{
    long row = blockIdx.x;
    int tid = threadIdx.x;
    long base = row * DV + tid;
    float v = x0[base];
    if (x1) v += x1[base];
    if (x2) v += x2[base];
    __shared__ float red[256];
    red[tid] = v; __syncthreads();
    for (int s = 128; s > 0; s >>= 1) { if (tid < s) red[tid] += red[tid + s]; __syncthreads(); }
    float mu = red[0] * (1.0f / DV);
    __syncthreads();
    float d = v - mu;
    red[tid] = d * d; __syncthreads();
    for (int s = 128; s > 0; s >>= 1) { if (tid < s) red[tid] += red[tid + s]; __syncthreads(); }
    float r = rsqrtf(red[0] * (1.0f / DV) + 1e-5f);
    float o = d * r * g[tid] + bta[tid];
    out[base] = o;
    if (outb) outb[base] = f2bf(o);
}

// pm softmax over L: single global read pass
__global__ __launch_bounds__(256) void colsoftmax_k(const float* __restrict__ pm,
                                                    u16* __restrict__ pmT)
{
    int r = blockIdx.x;
    int b = blockIdx.y;
    int tid = threadIdx.x, wave = tid >> 6, lane = tid & 63;
    const float* base = pm + (long)b * LSEQ * RR + r;
    u16* obase = pmT + ((long)b * RR + r) * LSEQ;

    float x[8];
#pragma unroll
    for (int i = 0; i < 8; ++i) x[i] = base[(long)(tid + i * 256) * RR];

    __shared__ float red[4];
    __shared__ float m_sh, d_sh;
    float mx = x[0];
#pragma unroll
    for (int i = 1; i < 8; ++i) mx = fmaxf(mx, x[i]);
#pragma unroll
    for (int m = 32; m >= 1; m >>= 1) mx = fmaxf(mx, __shfl_xor(mx, m));
    if (lane == 0) red[wave] = mx;
    __syncthreads();
    if (tid == 0) m_sh = fmaxf(fmaxf(red[0], red[1]), fmaxf(red[2], red[3]));
    __syncthreads();
    float m = m_sh;
    float sm = 0.f;
#pragma unroll
    for (int i = 0; i < 8; ++i) { x[i] = __expf(x[i] - m); sm += x[i]; }
#pragma unroll
    for (int mm = 32; mm >= 1; mm >>= 1) sm += __shfl_xor(sm, mm);
    if (lane == 0) red[wave] = sm;
    __syncthreads();
    if (tid == 0) d_sh = red[0] + red[1] + red[2] + red[3];
    __syncthreads();
    float inv = 1.0f / d_sh;
#pragma unroll
    for (int i = 0; i < 8; ++i) obase[tid + i * 256] = f2bf(x[i] * inv);
}

// sum 16 split-K partials -> bf16 kvcb, and (pair==1) transposed vcT
// grid (4 dt, 4 rt, 8 pairb), 256 threads; tile [32 r][64 d]
__global__ __launch_bounds__(256) void reduce_kvc_k(
    const float* __restrict__ part, u16* __restrict__ kvcb, u16* __restrict__ vcT)
{
    int pb = blockIdx.z;
    int pair = pb >> 2, b = pb & 3;
    int r0 = blockIdx.y * 32, d0 = blockIdx.x * 64;
    int tid = threadIdx.x;
    __shared__ float t[32][65];
    const float* pp = part + (long)pb * (16 * 32768);
    int r = tid >> 6;
    int d = tid & 63;
#pragma unroll
    for (int i = 0; i < 8; ++i) {
        int rr = r0 + r + i * 4;
        float s = 0.f;
#pragma unroll
        for (int sp = 0; sp < 16; ++sp)
            s += pp[(long)sp * 32768 + rr * 256 + d0 + d];
        kvcb[(long)pb * 32768 + rr * 256 + d0 + d] = f2bf(s);
        t[r + i * 4][d] = s;
    }
    if (pair == 0) return;
    __syncthreads();
    int dd = tid >> 2, rb = (tid & 3) * 8;
    u16 o8[8];
#pragma unroll
    for (int k = 0; k < 8; ++k) o8[k] = f2bf(t[rb + k][dd]);
    *(uint4*)(vcT + ((long)(b * 256 + d0 + dd)) * 128 + r0 + rb) = *(uint4*)o8;
}

// ---------------------------------------------------------------------------
extern "C" void kernel_launch(void* const* d_in, const int* in_sizes, int n_in,
                              void* d_out, int out_size, void* d_ws, size_t ws_size,
                              hipStream_t stream)
{
    const float* s        = (const float*)d_in[0];
    const float* gat_W    = (const float*)d_in[1];
    const float* att_src  = (const float*)d_in[2];
    const float* att_dst  = (const float*)d_in[3];
    const float* gat_b    = (const float*)d_in[4];
    const float* short_W  = (const float*)d_in[5];
    const float* short_b  = (const float*)d_in[6];
    const float* q_W      = (const float*)d_in[7];
    const float* q_b      = (const float*)d_in[8];
    const float* k_W      = (const float*)d_in[9];
    const float* k_b      = (const float*)d_in[10];
    const float* v_W      = (const float*)d_in[11];
    const float* v_b      = (const float*)d_in[12];
    const float* o_W      = (const float*)d_in[13];
    const float* o_b      = (const float*)d_in[14];
    const float* p_W      = (const float*)d_in[15];
    const float* p_b      = (const float*)d_in[16];
    const float* lnq_g    = (const float*)d_in[17];
    const float* lnq_b    = (const float*)d_in[18];
    const float* lnk_g    = (const float*)d_in[19];
    const float* lnk_b    = (const float*)d_in[20];
    const float* lnv_g    = (const float*)d_in[21];
    const float* lnv_b    = (const float*)d_in[22];
    const float* ln1_g    = (const float*)d_in[23];
    const float* ln1_b    = (const float*)d_in[24];
    const float* ln2_g    = (const float*)d_in[25];
    const float* ln2_b    = (const float*)d_in[26];
    const float* f1_W     = (const float*)d_in[27];
    const float* f1_b     = (const float*)d_in[28];
    const float* f2_W     = (const float*)d_in[29];
    const float* f2_b     = (const float*)d_in[30];
    const int*   ei       = (const int*)d_in[31];
    float* out = (float*)d_out;

    const size_t MB = 1024 * 1024;
    char* W = (char*)d_ws;
    u16*   sb      = (u16*)(W);                         // 4MB
    u16*   gatT    = (u16*)(W + 4*MB);                  // 512KB
    u16*   shortT  = (u16*)(W + 4*MB + 524288);         // 512KB
    u16*   qkvT    = (u16*)(W + 4*MB + 1048576);        // 384KB
    u16*   oT      = (u16*)(W + 4*MB + 1441792);        // 128KB
    u16*   pT      = (u16*)(W + 4*MB + 1572864);        // 64KB
    u16*   f1T     = (u16*)(W + 4*MB + 1638400);        // 512KB
    u16*   f2T     = (u16*)(W + 4*MB + 2162688);        // 512KB
    float* qkvb    = (float*)(W + 4*MB + 2686976);      // 3KB
    int*   ioff    = (int*)(W + 4*MB + 2690048);        // 2049
    int*   icnt    = (int*)(W + 4*MB + 2699264);        // 2048
    int*   ibucket = (int*)(W + 4*MB + 2707456);        // 34816
    u16*   h       = (u16*)(W + 8*MB);                  // 16MB
    u16*   ffh     = (u16*)(W + 8*MB);                  // alias h
    u16*   gat_out = (u16*)(W + 24*MB);                 // 16MB
    float* h1      = (float*)(W + 24*MB);               // alias (8MB)
    u16*   h1b     = (u16*)(W + 32*MB);                 // alias (4MB)
    float* shortb  = (float*)(W + 40*MB);               // 8MB
    float* qkv     = (float*)(W + 48*MB);               // 24MB (dead after ln_cast3)
    float* pmraw   = (float*)(W + 48*MB);               // alias 4MB (dead after colsoftmax)
    float* part    = (float*)(W + 48*MB);               // alias 16MB (kvc partials)
    u16*   lngb    = (u16*)(W + 48*MB);                 // alias 4MB (after part dead)
    float* lng2    = (float*)(W + 64*MB);               // 8MB
    u16*   qb      = (u16*)(W + 72*MB);                 // 4MB
    u16*   kvb     = (u16*)(W + 76*MB);                 // 8MB
    float* ff2     = (float*)(W + 76*MB);               // alias (after kvb dead)
    u16*   kvT     = (u16*)(W + 84*MB);                 // 8MB
    u16*   pmT     = (u16*)(W + 92*MB);                 // 2MB
    u16*   kvcb    = (u16*)(W + 94*MB);                 // 512KB
    u16*   vcT     = (u16*)(W + 94*MB + 524288);        // 256KB
    float* a_src   = (float*)(W + 95*MB);               // 128KB
    float* a_dst   = (float*)(W + 95*MB + 131072);      // 128KB

    const int ML = BB * LSEQ;  // 8192

    // ---- weights -> bf16 transposed; s cast; bias concat ----
    WTA wa;
    wa.d[0] = { gat_W,   gatT,            256, 1024, 0    };
    wa.d[1] = { short_W, shortT,         1024,  256, 256  };
    wa.d[2] = { q_W,     qkvT,            256,  256, 512  };
    wa.d[3] = { k_W,     qkvT + 65536,    256,  256, 576  };
    wa.d[4] = { v_W,     qkvT + 131072,   256,  256, 640  };
    wa.d[5] = { o_W,     oT,              256,  256, 704  };
    wa.d[6] = { p_W,     pT,              256,  128, 768  };
    wa.d[7] = { f1_W,    f1T,             256, 1024, 800  };
    wa.d[8] = { f2_W,    f2T,            1024,  256, 1056 };
    wtrans_all_k<<<1312, 256, 0, stream>>>(wa);
    castcat_k<<<2051, 256, 0, stream>>>(s, sb, q_b, k_b, v_b, qkvb);

    // ---- CSR ----
    hipMemsetAsync(icnt, 0, LSEQ * sizeof(int), stream);
    csr_count_k<<<(ETOT + 255) / 256, 256, 0, stream>>>(ei, icnt);
    csr_scan_k<<<1, 256, 0, stream>>>(icnt, ioff);
    csr_fill_k<<<(ETOT + 255) / 256, 256, 0, stream>>>(ei, ioff, icnt, ibucket);

    // ---- GAT ----
    mfma_gemm_k<128, 128, 1, 0><<<dim3(8, 64, 1), 256, 0, stream>>>(
        sb, gatT, nullptr, h, ML, 1024, 256, 256, 256, 1024,
        0, 0, 0, 0, 0, 0, 1, 0, 0, 0, 0, 1.f);
    gat_att_k<<<ML / 4, 256, 0, stream>>>(h, att_src, att_dst, a_src, a_dst);
    gat_gather_k<<<dim3(LSEQ / 4, BB), 256, 0, stream>>>(h, ei, ioff, ibucket,
                                                         a_src, a_dst, gat_b, gat_out);
    mfma_gemm_k<64, 128, 0, 0><<<dim3(2, 128, 1), 256, 0, stream>>>(
        gat_out, shortT, short_b, shortb, ML, 256, 1024, 1024, 1024, 256,
        0, 0, 0, 0, 0, 0, 1, 0, 0, 0, 0, 1.f);

    // ---- qkv projections + LN ----
    mfma_gemm_k<64, 128, 0, 0><<<dim3(6, 128, 1), 256, 0, stream>>>(
        sb, qkvT, qkvb, qkv, ML, 768, 256, 256, 256, 768,
        0, 0, 0, 0, 0, 0, 1, 0, 0, 0, 0, 1.f);
    ln_cast3_k<<<dim3(ML, 3), 256, 0, stream>>>(qkv, lnq_g, lnq_b, lnk_g, lnk_b,
                                                lnv_g, lnv_b, qb, kvb, kvb + 2097152);

    // pm = softmax_L(k @ p_W + p_b) -> pmT bf16 [b][r][l]
    mfma_gemm_k<64, 64, 0, 0><<<dim3(2, 128, 1), 256, 0, stream>>>(
        kvb, pT, p_b, pmraw, ML, 128, 256, 256, 256, 128,
        0, 0, 0, 0, 0, 0, 1, 0, 0, 0, 0, 1.f);
    colsoftmax_k<<<dim3(RR, BB), 256, 0, stream>>>(pmraw, pmT);

    // k,v -> L-major kvT [2][4][256][2048]
    ttrans_k<<<dim3(8, 64, 8), 256, 0, stream>>>(kvb, kvT, 2048, 256, 524288, 524288);

    // k_c/v_c via split-K (16 splits): part [pair][b][16][128][256]
    mfma_gemm_k<128, 128, 0, 0><<<dim3(2, 2, 64), 256, 0, stream>>>(
        pmT, kvT, nullptr, part, 128, 256, 2048, 2048, 2048, 256,
        262144, 0, 524288, 0, 524288, 32768, 16, 2097152, 2097152, 128, 1, 1.f);
    reduce_kvc_k<<<dim3(4, 4, 8), 256, 0, stream>>>(part, kvcb, vcT);

    // ---- fused attention ----
    attn_k<<<dim3(LSEQ / 64, BB * HH), 256, 0, stream>>>(qb, kvcb, vcT, lngb);

    // lng2 = lng @ o_W + o_b
    mfma_gemm_k<64, 128, 0, 0><<<dim3(2, 128, 1), 256, 0, stream>>>(
        lngb, oT, o_b, lng2, ML, 256, 256, 256, 256, 256,
        0, 0, 0, 0, 0, 0, 1, 0, 0, 0, 0, 1.f);

    // h1 = LN(s + short + lng2)
    ln3_k<<<ML, 256, 0, stream>>>(s, shortb, lng2, ln1_g, ln1_b, h1, h1b);

    // FFN
    mfma_gemm_k<128, 128, 1, 1><<<dim3(8, 64, 1), 256, 0, stream>>>(
        h1b, f1T, f1_b, ffh, ML, 1024, 256, 256, 256, 1024,
        0, 0, 0, 0, 0, 0, 1, 0, 0, 0, 0, 1.f);
    mfma_gemm_k<64, 128, 0, 0><<<dim3(2, 128, 1), 256, 0, stream>>>(
        ffh, f2T, f2_b, ff2, ML, 256, 1024, 1024, 1024, 256,
        0, 0, 0, 0, 0, 0, 1, 0, 0, 0, 0, 1.f);

    // out = LN(h1 + ff2)
    ln3_k<<<ML, 256, 0, stream>>>(h1, ff2, nullptr, ln2_g, ln2_b, out, nullptr);
}

// Round 5
// 246.597 us; speedup vs baseline: 5.4461x; 1.0029x over previous
//
#include <hip/hip_runtime.h>
#include <math.h>

#define BB   4
#define LSEQ 2048
#define DV   256
#define HH   4
#define RR   128
#define EE   32768
#define ETOT (EE + LSEQ)
#define FFD  1024

typedef unsigned short u16;
typedef __attribute__((ext_vector_type(8))) short bf16x8;
typedef __attribute__((ext_vector_type(4))) float f32x4;

__device__ __forceinline__ u16 f2bf(float f) {
    union { float f; unsigned u; } x; x.f = f;
    unsigned r = x.u + 0x7fff + ((x.u >> 16) & 1);
    return (u16)(r >> 16);
}
__device__ __forceinline__ float bf2f(u16 u) {
    union { unsigned u; float f; } x; x.u = ((unsigned)u) << 16;
    return x.f;
}

__device__ __forceinline__ void gload16(const void* g, void* l) {
    __builtin_amdgcn_global_load_lds(
        (const __attribute__((address_space(1))) unsigned int*)g,
        (__attribute__((address_space(3))) unsigned int*)l, 16, 0, 0);
}

// ---------------------------------------------------------------------------
// bf16 MFMA GEMM. BM in {128,64}, BN in {128,64}, BK=64.
// C[m,n] = act(alpha * sum_k A[m,k]*BT[n,k] + bias[n])
// ---------------------------------------------------------------------------
template<int BM, int BN, int OUTBF16, int ACT>
__global__ __launch_bounds__(256) void mfma_gemm_k(
    const u16* __restrict__ A, const u16* __restrict__ BT,
    const float* __restrict__ bias, void* __restrict__ Cv,
    int M, int N, int K, int lda, int ldb, int ldc,
    long bsA1, long bsA2, long bsB1, long bsB2, long bsC1, long bsC2,
    int subH, long pairB, long pairC, int ksl, int split, float alpha)
{
    constexpr int BK = 64;
    __shared__ u16 As[BM * BK];
    __shared__ u16 Bs[BN * BK];

    int z = blockIdx.z;
    int zb = z / subH, zh = z - zb * subH;
    int mtiles = M / BM;
    int pair = blockIdx.y / mtiles;
    int mt   = blockIdx.y - pair * mtiles;

    const u16* Ab = A  + zb * bsA1 + zh * bsA2;
    const u16* Bb = BT + zb * bsB1 + zh * bsB2 + (long)pair * pairB;
    int kstart = split ? zh * ksl : 0;
    int kcount = split ? ksl : K;
    int m0 = mt * BM, n0 = blockIdx.x * BN;

    int tid  = threadIdx.x;
    int wave = tid >> 6, lane = tid & 63;
    constexpr int WGN = (BN == 128) ? 2 : 1;
    constexpr int WGM = 4 / WGN;
    constexpr int MI  = BM / (WGM * 16);
    constexpr int NI  = BN / (WGN * 16);   // 4
    int wm = wave / WGN, wn = wave - wm * WGN;
    int wmo = wm * (MI * 16);
    int wno = wn * (NI * 16);

    f32x4 acc[MI][NI];
#pragma unroll
    for (int mi = 0; mi < MI; ++mi)
#pragma unroll
        for (int ni = 0; ni < NI; ++ni)
            acc[mi][ni] = (f32x4){0.f, 0.f, 0.f, 0.f};

    constexpr int AIT = (BM * BK / 8) / 256;
    constexpr int BIT = (BN * BK / 8) / 256;

    for (int k0 = 0; k0 < kcount; k0 += BK) {
        int kb = kstart + k0;
#pragma unroll
        for (int i = 0; i < AIT; ++i) {
            int p   = i * 256 + tid;
            int row = p >> 3;
            int kc  = (p & 7) ^ (row & 7);
            const u16* gp = Ab + (long)(m0 + row) * lda + kb + kc * 8;
            gload16(gp, (char*)As + (size_t)(i * 256 + wave * 64) * 16);
        }
#pragma unroll
        for (int i = 0; i < BIT; ++i) {
            int p   = i * 256 + tid;
            int row = p >> 3;
            int kc  = (p & 7) ^ (row & 7);
            const u16* gp = Bb + (long)(n0 + row) * ldb + kb + kc * 8;
            gload16(gp, (char*)Bs + (size_t)(i * 256 + wave * 64) * 16);
        }
        asm volatile("s_waitcnt vmcnt(0)");
        __syncthreads();

        const char* Ac = (const char*)As;
        const char* Bc = (const char*)Bs;
#pragma unroll
        for (int kh = 0; kh < 2; ++kh) {
            bf16x8 af[MI], bfr[NI];
            int kby = kh * 64 + ((lane >> 4) << 4);
#pragma unroll
            for (int mi = 0; mi < MI; ++mi) {
                int r = wmo + mi * 16 + (lane & 15);
                af[mi] = *(const bf16x8*)(Ac + r * 128 + (kby ^ ((r & 7) << 4)));
            }
#pragma unroll
            for (int ni = 0; ni < NI; ++ni) {
                int r = wno + ni * 16 + (lane & 15);
                bfr[ni] = *(const bf16x8*)(Bc + r * 128 + (kby ^ ((r & 7) << 4)));
            }
#pragma unroll
            for (int mi = 0; mi < MI; ++mi)
#pragma unroll
                for (int ni = 0; ni < NI; ++ni)
                    acc[mi][ni] = __builtin_amdgcn_mfma_f32_16x16x32_bf16(
                        af[mi], bfr[ni], acc[mi][ni], 0, 0, 0);
        }
        __syncthreads();
    }

    long cb = zb * bsC1 + zh * bsC2 + (long)pair * pairC;
#pragma unroll
    for (int mi = 0; mi < MI; ++mi) {
#pragma unroll
        for (int ni = 0; ni < NI; ++ni) {
            int col = n0 + wno + ni * 16 + (lane & 15);
            float bv = bias ? bias[col] : 0.f;
#pragma unroll
            for (int j = 0; j < 4; ++j) {
                int row = m0 + wmo + mi * 16 + ((lane >> 4) << 2) + j;
                float v = acc[mi][ni][j] * alpha + bv;
                if (ACT) v = fmaxf(v, 0.f);
                long idx = (long)row * ldc + col + cb;
                if (OUTBF16) ((u16*)Cv)[idx] = f2bf(v);
                else         ((float*)Cv)[idx] = v;
            }
        }
    }
}

// ---------------------------------------------------------------------------
// Fused long-range attention (unchanged, verified round 2)
// ---------------------------------------------------------------------------
__global__ __launch_bounds__(256) void attn_k(
    const u16* __restrict__ qb, const u16* __restrict__ kcb,
    const u16* __restrict__ vcT, u16* __restrict__ lngb)
{
    __shared__ u16 Ps[64 * 128];

    int bh = blockIdx.y;
    int b = bh >> 2, h = bh & 3;
    int l0 = blockIdx.x * 64;
    int tid = threadIdx.x, wave = tid >> 6, lane = tid & 63;
    int c = lane & 15, g = lane >> 4;

    const u16* kc = kcb + (long)b * (RR * DV) + h * 64;
    const u16* qg = qb + ((long)(b * LSEQ + l0)) * DV + h * 64;
    const u16* vg = vcT + ((long)b * DV + h * 64) * RR;

    f32x4 acc[8];
#pragma unroll
    for (int mi = 0; mi < 8; ++mi) acc[mi] = (f32x4){0.f, 0.f, 0.f, 0.f};

#pragma unroll
    for (int kh = 0; kh < 2; ++kh) {
        bf16x8 bq = *(const bf16x8*)(qg + (long)(wave * 16 + c) * DV + kh * 32 + g * 8);
#pragma unroll
        for (int mi = 0; mi < 8; ++mi) {
            bf16x8 af = *(const bf16x8*)(kc + (long)(mi * 16 + c) * DV + kh * 32 + g * 8);
            acc[mi] = __builtin_amdgcn_mfma_f32_16x16x32_bf16(af, bq, acc[mi], 0, 0, 0);
        }
    }

    float mx = -INFINITY;
#pragma unroll
    for (int mi = 0; mi < 8; ++mi)
#pragma unroll
        for (int j = 0; j < 4; ++j) {
            acc[mi][j] *= 0.125f;
            mx = fmaxf(mx, acc[mi][j]);
        }
    mx = fmaxf(mx, __shfl_xor(mx, 16));
    mx = fmaxf(mx, __shfl_xor(mx, 32));
    float den = 0.f;
#pragma unroll
    for (int mi = 0; mi < 8; ++mi)
#pragma unroll
        for (int j = 0; j < 4; ++j) {
            acc[mi][j] = __expf(acc[mi][j] - mx);
            den += acc[mi][j];
        }
    den += __shfl_xor(den, 16);
    den += __shfl_xor(den, 32);
    float inv = 1.0f / den;

    int l = wave * 16 + c;
#pragma unroll
    for (int mi = 0; mi < 8; ++mi) {
        short4 sv;
        sv.x = (short)f2bf(acc[mi][0] * inv);
        sv.y = (short)f2bf(acc[mi][1] * inv);
        sv.z = (short)f2bf(acc[mi][2] * inv);
        sv.w = (short)f2bf(acc[mi][3] * inv);
        int byte = l * 256 + ((mi * 32 + g * 8) ^ ((l & 7) << 4));
        *(short4*)((char*)Ps + byte) = sv;
    }
    __syncthreads();

    f32x4 a2[4];
#pragma unroll
    for (int ni = 0; ni < 4; ++ni) a2[ni] = (f32x4){0.f, 0.f, 0.f, 0.f};
#pragma unroll
    for (int kb = 0; kb < 4; ++kb) {
        int kby = kb * 64 + (g << 4);
        bf16x8 pa = *(const bf16x8*)((char*)Ps + l * 256 + (kby ^ ((l & 7) << 4)));
#pragma unroll
        for (int ni = 0; ni < 4; ++ni) {
            bf16x8 vf = *(const bf16x8*)(vg + (long)(ni * 16 + c) * RR + kb * 32 + g * 8);
            a2[ni] = __builtin_amdgcn_mfma_f32_16x16x32_bf16(pa, vf, a2[ni], 0, 0, 0);
        }
    }
#pragma unroll
    for (int ni = 0; ni < 4; ++ni)
#pragma unroll
        for (int j = 0; j < 4; ++j) {
            int lr = wave * 16 + g * 4 + j;
            int dh = ni * 16 + c;
            lngb[((long)(b * LSEQ + l0 + lr)) * DV + h * 64 + dh] = f2bf(a2[ni][j]);
        }
}

// ---------------------------------------------------------------------------
// All weight transposes in one kernel
// ---------------------------------------------------------------------------
struct WTD { const float* src; u16* dst; int K, N, toff; };
struct WTA { WTD d[9]; };

__global__ __launch_bounds__(256) void wtrans_all_k(WTA a)
{
    int bid = blockIdx.x;
    int di = 0;
#pragma unroll
    for (int i = 1; i < 9; ++i) if (bid >= a.d[i].toff) di = i;
    const float* src = a.d[di].src;
    u16* dst = a.d[di].dst;
    int K = a.d[di].K, N = a.d[di].N;
    int tix = bid - a.d[di].toff;
    int nx = N >> 5;
    int tn = tix % nx, tk = tix / nx;
    int n0 = tn * 32, k0 = tk * 32;

    __shared__ float t[32][33];
    int tx = threadIdx.x & 31, ty = threadIdx.x >> 5;
#pragma unroll
    for (int i = 0; i < 32; i += 8)
        t[ty + i][tx] = src[(long)(k0 + ty + i) * N + n0 + tx];
    __syncthreads();
#pragma unroll
    for (int i = 0; i < 32; i += 8)
        dst[(long)(n0 + ty + i) * K + k0 + tx] = f2bf(t[tx][ty + i]);
}

// bf16 [R][C] -> bf16 [C][R] transpose, batched over z
__global__ __launch_bounds__(256) void ttrans_k(const u16* __restrict__ in,
                                                u16* __restrict__ out,
                                                int R, int C, long isb, long osb)
{
    in  += blockIdx.z * isb;
    out += blockIdx.z * osb;
    __shared__ u16 t[32][33];
    int c0 = blockIdx.x * 32, r0 = blockIdx.y * 32;
    int tx = threadIdx.x & 31, ty = threadIdx.x >> 5;
#pragma unroll
    for (int i = 0; i < 32; i += 8)
        t[ty + i][tx] = in[(long)(r0 + ty + i) * C + c0 + tx];
    __syncthreads();
#pragma unroll
    for (int i = 0; i < 32; i += 8)
        out[(long)(c0 + ty + i) * R + r0 + tx] = t[tx][ty + i];
}

// s -> bf16 cast + qkv bias concat, one kernel
__global__ void castcat_k(const float* __restrict__ in, u16* __restrict__ out,
                          const float* qb_, const float* kb_, const float* vb_,
                          float* qkvb)
{
    int bid = blockIdx.x;
    if (bid < 2048) {
        int i = (bid * 256 + threadIdx.x) * 4;
        float4 v = *(const float4*)(in + i);
        out[i]     = f2bf(v.x);
        out[i + 1] = f2bf(v.y);
        out[i + 2] = f2bf(v.z);
        out[i + 3] = f2bf(v.w);
    } else {
        int i = (bid - 2048) * 256 + threadIdx.x;
        if (i < 768)
            qkvb[i] = (i < 256) ? qb_[i] : ((i < 512) ? kb_[i - 256] : vb_[i - 512]);
    }
}

// ---------------------------------------------------------------------------
// GAT attention logits: wave-per-row, shfl reduce
// ---------------------------------------------------------------------------
__global__ __launch_bounds__(256) void gat_att_k(
    const u16* __restrict__ h, const float* __restrict__ att_src,
    const float* __restrict__ att_dst, float* __restrict__ a_src,
    float* __restrict__ a_dst)
{
    int row  = blockIdx.x * 4 + (threadIdx.x >> 6);
    int lane = threadIdx.x & 63;
    int c0   = lane * 16;
    int head = lane >> 4;

    float as[16], ad[16];
#pragma unroll
    for (int i = 0; i < 16; ++i) { as[i] = att_src[c0 + i]; ad[i] = att_dst[c0 + i]; }

    const u16* hr = h + (long)row * (HH * DV) + c0;
    bf16x8 v0 = *(const bf16x8*)(hr);
    bf16x8 v1 = *(const bf16x8*)(hr + 8);
    float ps = 0.f, pd = 0.f;
#pragma unroll
    for (int i = 0; i < 8; ++i) {
        float f0 = bf2f((u16)v0[i]), f1 = bf2f((u16)v1[i]);
        ps += f0 * as[i] + f1 * as[i + 8];
        pd += f0 * ad[i] + f1 * ad[i + 8];
    }
#pragma unroll
    for (int m = 1; m <= 8; m <<= 1) {
        ps += __shfl_xor(ps, m);
        pd += __shfl_xor(pd, m);
    }
    if ((lane & 15) == 0) {
        a_src[(long)row * HH + head] = ps;
        a_dst[(long)row * HH + head] = pd;
    }
}

// ---------------------------------------------------------------------------
// CSR build over dst (batch-shared)
// ---------------------------------------------------------------------------
__global__ void zero_icnt_k(int* __restrict__ cnt)
{
    // 2048 ints = 512 int4
    int t = threadIdx.x;
    ((int4*)cnt)[t]       = (int4){0, 0, 0, 0};
    ((int4*)cnt)[t + 256] = (int4){0, 0, 0, 0};
}

__global__ void csr_count_k(const int* __restrict__ ei, int* __restrict__ cnt)
{
    int i = blockIdx.x * blockDim.x + threadIdx.x;
    if (i >= ETOT) return;
    int dst = (i < EE) ? ei[EE + i] : (i - EE);
    atomicAdd(&cnt[dst], 1);
}

__global__ __launch_bounds__(256) void csr_scan_k(const int* __restrict__ cnt, int* __restrict__ off)
{
    __shared__ int chunk[256];
    int tid = threadIdx.x;
    int base = tid * 8;
    int loc[8];
    int s = 0;
#pragma unroll
    for (int i = 0; i < 8; ++i) { loc[i] = s; s += cnt[base + i]; }
    chunk[tid] = s;
    __syncthreads();
    for (int st = 1; st < 256; st <<= 1) {
        int v = (tid >= st) ? chunk[tid - st] : 0;
        __syncthreads();
        chunk[tid] += v;
        __syncthreads();
    }
    int pre = (tid == 0) ? 0 : chunk[tid - 1];
#pragma unroll
    for (int i = 0; i < 8; ++i) off[base + i] = pre + loc[i];
    if (tid == 255) off[LSEQ] = chunk[255];
}

// fill uses atomicSub on counts (no second zeroing needed)
__global__ void csr_fill_k(const int* __restrict__ ei, const int* __restrict__ off,
                           int* __restrict__ cnt, int* __restrict__ bucket)
{
    int i = blockIdx.x * blockDim.x + threadIdx.x;
    if (i >= ETOT) return;
    int dst = (i < EE) ? ei[EE + i] : (i - EE);
    int p = atomicSub(&cnt[dst], 1) - 1;
    bucket[off[dst] + p] = i;
}

// ---------------------------------------------------------------------------
// GAT scatter-softmax + aggregate: ONE WAVE PER (b,n), no block barriers.
// Each wave owns its LDS slice; intra-wave LDS is program-ordered.
// ---------------------------------------------------------------------------
__global__ __launch_bounds__(256) void gat_gather_k(
    const u16* __restrict__ h, const int* __restrict__ ei,
    const int* __restrict__ off, const int* __restrict__ bucket,
    const float* __restrict__ a_src, const float* __restrict__ a_dst,
    const float* __restrict__ gat_b, u16* __restrict__ out)
{
    int wv = threadIdx.x >> 6, lane = threadIdx.x & 63;
    int n = blockIdx.x * 4 + wv;
    int b = blockIdx.y;
    int beg = off[n], deg = off[n + 1] - beg;

    __shared__ int   src_sh[4][64];
    __shared__ float ex_sh[4][64][4];

    const float* asrc_b = a_src + (long)b * LSEQ * HH;
    const float4 ad4 = *(const float4*)(a_dst + ((long)b * LSEQ + n) * HH);
    float adst[4] = { ad4.x, ad4.y, ad4.z, ad4.w };

    // pass 1: global max per head (wave shfl reduce)
    float mx[4] = { -INFINITY, -INFINITY, -INFINITY, -INFINITY };
    for (int c0 = 0; c0 < deg; c0 += 64) {
        int idx = c0 + lane;
        if (idx < deg) {
            int eid = bucket[beg + idx];
            int src = (eid < EE) ? ei[eid] : (eid - EE);
            float4 as4 = *(const float4*)(asrc_b + (long)src * HH);
            float as[4] = { as4.x, as4.y, as4.z, as4.w };
#pragma unroll
            for (int hh = 0; hh < 4; ++hh) {
                float e = as[hh] + adst[hh];
                e = (e >= 0.f) ? e : 0.2f * e;
                mx[hh] = fmaxf(mx[hh], e);
            }
        }
    }
#pragma unroll
    for (int hh = 0; hh < 4; ++hh)
#pragma unroll
        for (int m = 32; m >= 1; m >>= 1)
            mx[hh] = fmaxf(mx[hh], __shfl_xor(mx[hh], m));

    // pass 2: exp -> wave-private LDS, gather with all 64 lanes
    int hd = lane >> 4;
    const u16* hb = h + (long)b * LSEQ * (HH * DV) + lane * 16;
    float acc[16];
#pragma unroll
    for (int i = 0; i < 16; ++i) acc[i] = 0.f;
    float sm[4] = { 0.f, 0.f, 0.f, 0.f };

    for (int c0 = 0; c0 < deg; c0 += 64) {
        int idx = c0 + lane;
        if (idx < deg) {
            int eid = bucket[beg + idx];
            int src = (eid < EE) ? ei[eid] : (eid - EE);
            src_sh[wv][lane] = src;
            float4 as4 = *(const float4*)(asrc_b + (long)src * HH);
            float as[4] = { as4.x, as4.y, as4.z, as4.w };
#pragma unroll
            for (int hh = 0; hh < 4; ++hh) {
                float e = as[hh] + adst[hh];
                e = (e >= 0.f) ? e : 0.2f * e;
                float ex = __expf(e - mx[hh]);
                ex_sh[wv][lane][hh] = ex;
                sm[hh] += ex;
            }
        }
        int cn = deg - c0; if (cn > 64) cn = 64;
#pragma unroll 2
        for (int j = 0; j < cn; ++j) {
            int src = src_sh[wv][j];
            float al = ex_sh[wv][j][hd];
            const u16* p = hb + (long)src * (HH * DV);
            bf16x8 v0 = *(const bf16x8*)p;
            bf16x8 v1 = *(const bf16x8*)(p + 8);
#pragma unroll
            for (int i = 0; i < 8; ++i) {
                acc[i]     += al * bf2f((u16)v0[i]);
                acc[i + 8] += al * bf2f((u16)v1[i]);
            }
        }
    }

#pragma unroll
    for (int hh = 0; hh < 4; ++hh)
#pragma unroll
        for (int m = 32; m >= 1; m >>= 1)
            sm[hh] += __shfl_xor(sm[hh], m);
    float inv = 1.0f / sm[hd];

    u16 o16[16];
    const float* gb = gat_b + lane * 16;
#pragma unroll
    for (int i = 0; i < 16; ++i) o16[i] = f2bf(acc[i] * inv + gb[i]);
    uint4* op = (uint4*)(out + ((long)b * LSEQ + n) * (HH * DV) + lane * 16);
    op[0] = ((uint4*)o16)[0];
    op[1] = ((uint4*)o16)[1];
}

// ---------------------------------------------------------------------------
// Fused LN of q/k/v segments: grid (ML, 3)
// ---------------------------------------------------------------------------
__global__ __launch_bounds__(256) void ln_cast3_k(
    const float* __restrict__ x,
    const float* g0, const float* b0, const float* g1, const float* b1,
    const float* g2, const float* b2,
    u16* o0, u16* o1, u16* o2)
{
    int seg = blockIdx.y;
    long row = blockIdx.x;
    int tid = threadIdx.x;
    const float* g = (seg == 0) ? g0 : (seg == 1) ? g1 : g2;
    const float* bt = (seg == 0) ? b0 : (seg == 1) ? b1 : b2;
    u16* o = (seg == 0) ? o0 : (seg == 1) ? o1 : o2;

    float v = x[row * 768 + seg * 256 + tid];
    __shared__ float red[256];
    red[tid] = v; __syncthreads();
    for (int s = 128; s > 0; s >>= 1) { if (tid < s) red[tid] += red[tid + s]; __syncthreads(); }
    float mu = red[0] * (1.0f / DV);
    __syncthreads();
    float d = v - mu;
    red[tid] = d * d; __syncthreads();
    for (int s = 128; s > 0; s >>= 1) { if (tid < s) red[tid] += red[tid + s]; __syncthreads(); }
    float r = rsqrtf(red[0] * (1.0f / DV) + 1e-5f);
    o[row * DV + tid] = f2bf(d * r * g[tid] + bt[tid]);
}

// LN of (x0 [+x1] [+x2]) -> fp32 out (+ optional bf16 outb)
__global__ __launch_bounds__(256) void ln3_k(
    const float* __restrict__ x0, const float* __restrict__ x1,
    const float* __restrict__ x2, const float* __restrict__ g,
    const float* __restrict__ bta, float* __restrict__ out,
    u16* __restrict__ outb)
{
    long row = blockIdx.x;
    int tid = threadIdx.x;
    long base = row * DV + tid;
    float v = x0[base];
    if (x1) v += x1[base];
    if (x2) v += x2[base];
    __shared__ float red[256];
    red[tid] = v; __syncthreads();
    for (int s = 128; s > 0; s >>= 1) { if (tid < s) red[tid] += red[tid + s]; __syncthreads(); }
    float mu = red[0] * (1.0f / DV);
    __syncthreads();
    float d = v - mu;
    red[tid] = d * d; __syncthreads();
    for (int s = 128; s > 0; s >>= 1) { if (tid < s) red[tid] += red[tid + s]; __syncthreads(); }
    float r = rsqrtf(red[0] * (1.0f / DV) + 1e-5f);
    float o = d * r * g[tid] + bta[tid];
    out[base] = o;
    if (outb) outb[base] = f2bf(o);
}

// pm softmax over L: single global read pass
__global__ __launch_bounds__(256) void colsoftmax_k(const float* __restrict__ pm,
                                                    u16* __restrict__ pmT)
{
    int r = blockIdx.x;
    int b = blockIdx.y;
    int tid = threadIdx.x, wave = tid >> 6, lane = tid & 63;
    const float* base = pm + (long)b * LSEQ * RR + r;
    u16* obase = pmT + ((long)b * RR + r) * LSEQ;

    float x[8];
#pragma unroll
    for (int i = 0; i < 8; ++i) x[i] = base[(long)(tid + i * 256) * RR];

    __shared__ float red[4];
    __shared__ float m_sh, d_sh;
    float mx = x[0];
#pragma unroll
    for (int i = 1; i < 8; ++i) mx = fmaxf(mx, x[i]);
#pragma unroll
    for (int m = 32; m >= 1; m >>= 1) mx = fmaxf(mx, __shfl_xor(mx, m));
    if (lane == 0) red[wave] = mx;
    __syncthreads();
    if (tid == 0) m_sh = fmaxf(fmaxf(red[0], red[1]), fmaxf(red[2], red[3]));
    __syncthreads();
    float m = m_sh;
    float sm = 0.f;
#pragma unroll
    for (int i = 0; i < 8; ++i) { x[i] = __expf(x[i] - m); sm += x[i]; }
#pragma unroll
    for (int mm = 32; mm >= 1; mm >>= 1) sm += __shfl_xor(sm, mm);
    if (lane == 0) red[wave] = sm;
    __syncthreads();
    if (tid == 0) d_sh = red[0] + red[1] + red[2] + red[3];
    __syncthreads();
    float inv = 1.0f / d_sh;
#pragma unroll
    for (int i = 0; i < 8; ++i) obase[tid + i * 256] = f2bf(x[i] * inv);
}

// sum 16 split-K partials -> bf16 kvcb, and (pair==1) transposed vcT
__global__ __launch_bounds__(256) void reduce_kvc_k(
    const float* __restrict__ part, u16* __restrict__ kvcb, u16* __restrict__ vcT)
{
    int pb = blockIdx.z;
    int pair = pb >> 2, b = pb & 3;
    int r0 = blockIdx.y * 32, d0 = blockIdx.x * 64;
    int tid = threadIdx.x;
    __shared__ float t[32][65];
    const float* pp = part + (long)pb * (16 * 32768);
    int r = tid >> 6;
    int d = tid & 63;
#pragma unroll
    for (int i = 0; i < 8; ++i) {
        int rr = r0 + r + i * 4;
        float s = 0.f;
#pragma unroll
        for (int sp = 0; sp < 16; ++sp)
            s += pp[(long)sp * 32768 + rr * 256 + d0 + d];
        kvcb[(long)pb * 32768 + rr * 256 + d0 + d] = f2bf(s);
        t[r + i * 4][d] = s;
    }
    if (pair == 0) return;
    __syncthreads();
    int dd = tid >> 2, rb = (tid & 3) * 8;
    u16 o8[8];
#pragma unroll
    for (int k = 0; k < 8; ++k) o8[k] = f2bf(t[rb + k][dd]);
    *(uint4*)(vcT + ((long)(b * 256 + d0 + dd)) * 128 + r0 + rb) = *(uint4*)o8;
}

// ---------------------------------------------------------------------------
extern "C" void kernel_launch(void* const* d_in, const int* in_sizes, int n_in,
                              void* d_out, int out_size, void* d_ws, size_t ws_size,
                              hipStream_t stream)
{
    const float* s        = (const float*)d_in[0];
    const float* gat_W    = (const float*)d_in[1];
    const float* att_src  = (const float*)d_in[2];
    const float* att_dst  = (const float*)d_in[3];
    const float* gat_b    = (const float*)d_in[4];
    const float* short_W  = (const float*)d_in[5];
    const float* short_b  = (const float*)d_in[6];
    const float* q_W      = (const float*)d_in[7];
    const float* q_b      = (const float*)d_in[8];
    const float* k_W      = (const float*)d_in[9];
    const float* k_b      = (const float*)d_in[10];
    const float* v_W      = (const float*)d_in[11];
    const float* v_b      = (const float*)d_in[12];
    const float* o_W      = (const float*)d_in[13];
    const float* o_b      = (const float*)d_in[14];
    const float* p_W      = (const float*)d_in[15];
    const float* p_b      = (const float*)d_in[16];
    const float* lnq_g    = (const float*)d_in[17];
    const float* lnq_b    = (const float*)d_in[18];
    const float* lnk_g    = (const float*)d_in[19];
    const float* lnk_b    = (const float*)d_in[20];
    const float* lnv_g    = (const float*)d_in[21];
    const float* lnv_b    = (const float*)d_in[22];
    const float* ln1_g    = (const float*)d_in[23];
    const float* ln1_b    = (const float*)d_in[24];
    const float* ln2_g    = (const float*)d_in[25];
    const float* ln2_b    = (const float*)d_in[26];
    const float* f1_W     = (const float*)d_in[27];
    const float* f1_b     = (const float*)d_in[28];
    const float* f2_W     = (const float*)d_in[29];
    const float* f2_b     = (const float*)d_in[30];
    const int*   ei       = (const int*)d_in[31];
    float* out = (float*)d_out;

    const size_t MB = 1024 * 1024;
    char* W = (char*)d_ws;
    u16*   sb      = (u16*)(W);                         // 4MB
    u16*   gatT    = (u16*)(W + 4*MB);                  // 512KB
    u16*   shortT  = (u16*)(W + 4*MB + 524288);         // 512KB
    u16*   qkvT    = (u16*)(W + 4*MB + 1048576);        // 384KB
    u16*   oT      = (u16*)(W + 4*MB + 1441792);        // 128KB
    u16*   pT      = (u16*)(W + 4*MB + 1572864);        // 64KB
    u16*   f1T     = (u16*)(W + 4*MB + 1638400);        // 512KB
    u16*   f2T     = (u16*)(W + 4*MB + 2162688);        // 512KB
    float* qkvb    = (float*)(W + 4*MB + 2686976);      // 3KB
    int*   ioff    = (int*)(W + 4*MB + 2690048);        // 2049
    int*   icnt    = (int*)(W + 4*MB + 2699264);        // 2048
    int*   ibucket = (int*)(W + 4*MB + 2707456);        // 34816
    u16*   h       = (u16*)(W + 8*MB);                  // 16MB
    u16*   ffh     = (u16*)(W + 8*MB);                  // alias h
    u16*   gat_out = (u16*)(W + 24*MB);                 // 16MB
    float* h1      = (float*)(W + 24*MB);               // alias (8MB)
    u16*   h1b     = (u16*)(W + 32*MB);                 // alias (4MB)
    float* shortb  = (float*)(W + 40*MB);               // 8MB
    float* qkv     = (float*)(W + 48*MB);               // 24MB (dead after ln_cast3)
    float* pmraw   = (float*)(W + 48*MB);               // alias 4MB (dead after colsoftmax)
    float* part    = (float*)(W + 48*MB);               // alias 16MB (kvc partials)
    u16*   lngb    = (u16*)(W + 48*MB);                 // alias 4MB (after part dead)
    float* lng2    = (float*)(W + 64*MB);               // 8MB
    u16*   qb      = (u16*)(W + 72*MB);                 // 4MB
    u16*   kvb     = (u16*)(W + 76*MB);                 // 8MB
    float* ff2     = (float*)(W + 76*MB);               // alias (after kvb dead)
    u16*   kvT     = (u16*)(W + 84*MB);                 // 8MB
    u16*   pmT     = (u16*)(W + 92*MB);                 // 2MB
    u16*   kvcb    = (u16*)(W + 94*MB);                 // 512KB
    u16*   vcT     = (u16*)(W + 94*MB + 524288);        // 256KB
    float* a_src   = (float*)(W + 95*MB);               // 128KB
    float* a_dst   = (float*)(W + 95*MB + 131072);      // 128KB

    const int ML = BB * LSEQ;  // 8192

    // ---- weights -> bf16 transposed; s cast; bias concat ----
    WTA wa;
    wa.d[0] = { gat_W,   gatT,            256, 1024, 0    };
    wa.d[1] = { short_W, shortT,         1024,  256, 256  };
    wa.d[2] = { q_W,     qkvT,            256,  256, 512  };
    wa.d[3] = { k_W,     qkvT + 65536,    256,  256, 576  };
    wa.d[4] = { v_W,     qkvT + 131072,   256,  256, 640  };
    wa.d[5] = { o_W,     oT,              256,  256, 704  };
    wa.d[6] = { p_W,     pT,              256,  128, 768  };
    wa.d[7] = { f1_W,    f1T,             256, 1024, 800  };
    wa.d[8] = { f2_W,    f2T,            1024,  256, 1056 };
    wtrans_all_k<<<1312, 256, 0, stream>>>(wa);
    castcat_k<<<2051, 256, 0, stream>>>(s, sb, q_b, k_b, v_b, qkvb);

    // ---- CSR (custom zero kernel — rocclr fillBuffer was 42 µs/call) ----
    zero_icnt_k<<<1, 256, 0, stream>>>(icnt);
    csr_count_k<<<(ETOT + 255) / 256, 256, 0, stream>>>(ei, icnt);
    csr_scan_k<<<1, 256, 0, stream>>>(icnt, ioff);
    csr_fill_k<<<(ETOT + 255) / 256, 256, 0, stream>>>(ei, ioff, icnt, ibucket);

    // ---- GAT ----
    mfma_gemm_k<128, 128, 1, 0><<<dim3(8, 64, 1), 256, 0, stream>>>(
        sb, gatT, nullptr, h, ML, 1024, 256, 256, 256, 1024,
        0, 0, 0, 0, 0, 0, 1, 0, 0, 0, 0, 1.f);
    gat_att_k<<<ML / 4, 256, 0, stream>>>(h, att_src, att_dst, a_src, a_dst);
    gat_gather_k<<<dim3(LSEQ / 4, BB), 256, 0, stream>>>(h, ei, ioff, ibucket,
                                                         a_src, a_dst, gat_b, gat_out);
    mfma_gemm_k<64, 128, 0, 0><<<dim3(2, 128, 1), 256, 0, stream>>>(
        gat_out, shortT, short_b, shortb, ML, 256, 1024, 1024, 1024, 256,
        0, 0, 0, 0, 0, 0, 1, 0, 0, 0, 0, 1.f);

    // ---- qkv projections + LN ----
    mfma_gemm_k<64, 128, 0, 0><<<dim3(6, 128, 1), 256, 0, stream>>>(
        sb, qkvT, qkvb, qkv, ML, 768, 256, 256, 256, 768,
        0, 0, 0, 0, 0, 0, 1, 0, 0, 0, 0, 1.f);
    ln_cast3_k<<<dim3(ML, 3), 256, 0, stream>>>(qkv, lnq_g, lnq_b, lnk_g, lnk_b,
                                                lnv_g, lnv_b, qb, kvb, kvb + 2097152);

    // pm = softmax_L(k @ p_W + p_b) -> pmT bf16 [b][r][l]
    mfma_gemm_k<64, 64, 0, 0><<<dim3(2, 128, 1), 256, 0, stream>>>(
        kvb, pT, p_b, pmraw, ML, 128, 256, 256, 256, 128,
        0, 0, 0, 0, 0, 0, 1, 0, 0, 0, 0, 1.f);
    colsoftmax_k<<<dim3(RR, BB), 256, 0, stream>>>(pmraw, pmT);

    // k,v -> L-major kvT [2][4][256][2048]
    ttrans_k<<<dim3(8, 64, 8), 256, 0, stream>>>(kvb, kvT, 2048, 256, 524288, 524288);

    // k_c/v_c via split-K (16 splits): part [pair][b][16][128][256]
    mfma_gemm_k<128, 128, 0, 0><<<dim3(2, 2, 64), 256, 0, stream>>>(
        pmT, kvT, nullptr, part, 128, 256, 2048, 2048, 2048, 256,
        262144, 0, 524288, 0, 524288, 32768, 16, 2097152, 2097152, 128, 1, 1.f);
    reduce_kvc_k<<<dim3(4, 4, 8), 256, 0, stream>>>(part, kvcb, vcT);

    // ---- fused attention ----
    attn_k<<<dim3(LSEQ / 64, BB * HH), 256, 0, stream>>>(qb, kvcb, vcT, lngb);

    // lng2 = lng @ o_W + o_b
    mfma_gemm_k<64, 128, 0, 0><<<dim3(2, 128, 1), 256, 0, stream>>>(
        lngb, oT, o_b, lng2, ML, 256, 256, 256, 256, 256,
        0, 0, 0, 0, 0, 0, 1, 0, 0, 0, 0, 1.f);

    // h1 = LN(s + short + lng2)
    ln3_k<<<ML, 256, 0, stream>>>(s, shortb, lng2, ln1_g, ln1_b, h1, h1b);

    // FFN
    mfma_gemm_k<128, 128, 1, 1><<<dim3(8, 64, 1), 256, 0, stream>>>(
        h1b, f1T, f1_b, ffh, ML, 1024, 256, 256, 256, 1024,
        0, 0, 0, 0, 0, 0, 1, 0, 0, 0, 0, 1.f);
    mfma_gemm_k<64, 128, 0, 0><<<dim3(2, 128, 1), 256, 0, stream>>>(
        ffh, f2T, f2_b, ff2, ML, 256, 1024, 1024, 1024, 256,
        0, 0, 0, 0, 0, 0, 1, 0, 0, 0, 0, 1.f);

    // out = LN(h1 + ff2)
    ln3_k<<<ML, 256, 0, stream>>>(h1, ff2, nullptr, ln2_g, ln2_b, out, nullptr);
}

// Round 6
// 245.822 us; speedup vs baseline: 5.4632x; 1.0032x over previous
//
#include <hip/hip_runtime.h>
#include <math.h>

#define BB   4
#define LSEQ 2048
#define DV   256
#define HH   4
#define RR   128
#define EE   32768
#define ETOT (EE + LSEQ)
#define FFD  1024

typedef unsigned short u16;
typedef __attribute__((ext_vector_type(8))) short bf16x8;
typedef __attribute__((ext_vector_type(4))) float f32x4;

__device__ __forceinline__ u16 f2bf(float f) {
    union { float f; unsigned u; } x; x.f = f;
    unsigned r = x.u + 0x7fff + ((x.u >> 16) & 1);
    return (u16)(r >> 16);
}
__device__ __forceinline__ float bf2f(u16 u) {
    union { unsigned u; float f; } x; x.u = ((unsigned)u) << 16;
    return x.f;
}

__device__ __forceinline__ void gload16(const void* g, void* l) {
    __builtin_amdgcn_global_load_lds(
        (const __attribute__((address_space(1))) unsigned int*)g,
        (__attribute__((address_space(3))) unsigned int*)l, 16, 0, 0);
}

// ---------------------------------------------------------------------------
// bf16 MFMA GEMM. BM in {128,64}, BN in {128,64}, BK=64.
// C[m,n] = act(alpha * sum_k A[m,k]*BT[n,k] + bias[n])
// ---------------------------------------------------------------------------
template<int BM, int BN, int OUTBF16, int ACT>
__global__ __launch_bounds__(256) void mfma_gemm_k(
    const u16* __restrict__ A, const u16* __restrict__ BT,
    const float* __restrict__ bias, void* __restrict__ Cv,
    int M, int N, int K, int lda, int ldb, int ldc,
    long bsA1, long bsA2, long bsB1, long bsB2, long bsC1, long bsC2,
    int subH, long pairB, long pairC, int ksl, int split, float alpha)
{
    constexpr int BK = 64;
    __shared__ u16 As[BM * BK];
    __shared__ u16 Bs[BN * BK];

    int z = blockIdx.z;
    int zb = z / subH, zh = z - zb * subH;
    int mtiles = M / BM;
    int pair = blockIdx.y / mtiles;
    int mt   = blockIdx.y - pair * mtiles;

    const u16* Ab = A  + zb * bsA1 + zh * bsA2;
    const u16* Bb = BT + zb * bsB1 + zh * bsB2 + (long)pair * pairB;
    int kstart = split ? zh * ksl : 0;
    int kcount = split ? ksl : K;
    int m0 = mt * BM, n0 = blockIdx.x * BN;

    int tid  = threadIdx.x;
    int wave = tid >> 6, lane = tid & 63;
    constexpr int WGN = (BN == 128) ? 2 : 1;
    constexpr int WGM = 4 / WGN;
    constexpr int MI  = BM / (WGM * 16);
    constexpr int NI  = BN / (WGN * 16);   // 4
    int wm = wave / WGN, wn = wave - wm * WGN;
    int wmo = wm * (MI * 16);
    int wno = wn * (NI * 16);

    f32x4 acc[MI][NI];
#pragma unroll
    for (int mi = 0; mi < MI; ++mi)
#pragma unroll
        for (int ni = 0; ni < NI; ++ni)
            acc[mi][ni] = (f32x4){0.f, 0.f, 0.f, 0.f};

    constexpr int AIT = (BM * BK / 8) / 256;
    constexpr int BIT = (BN * BK / 8) / 256;

    for (int k0 = 0; k0 < kcount; k0 += BK) {
        int kb = kstart + k0;
#pragma unroll
        for (int i = 0; i < AIT; ++i) {
            int p   = i * 256 + tid;
            int row = p >> 3;
            int kc  = (p & 7) ^ (row & 7);
            const u16* gp = Ab + (long)(m0 + row) * lda + kb + kc * 8;
            gload16(gp, (char*)As + (size_t)(i * 256 + wave * 64) * 16);
        }
#pragma unroll
        for (int i = 0; i < BIT; ++i) {
            int p   = i * 256 + tid;
            int row = p >> 3;
            int kc  = (p & 7) ^ (row & 7);
            const u16* gp = Bb + (long)(n0 + row) * ldb + kb + kc * 8;
            gload16(gp, (char*)Bs + (size_t)(i * 256 + wave * 64) * 16);
        }
        asm volatile("s_waitcnt vmcnt(0)");
        __syncthreads();

        const char* Ac = (const char*)As;
        const char* Bc = (const char*)Bs;
#pragma unroll
        for (int kh = 0; kh < 2; ++kh) {
            bf16x8 af[MI], bfr[NI];
            int kby = kh * 64 + ((lane >> 4) << 4);
#pragma unroll
            for (int mi = 0; mi < MI; ++mi) {
                int r = wmo + mi * 16 + (lane & 15);
                af[mi] = *(const bf16x8*)(Ac + r * 128 + (kby ^ ((r & 7) << 4)));
            }
#pragma unroll
            for (int ni = 0; ni < NI; ++ni) {
                int r = wno + ni * 16 + (lane & 15);
                bfr[ni] = *(const bf16x8*)(Bc + r * 128 + (kby ^ ((r & 7) << 4)));
            }
#pragma unroll
            for (int mi = 0; mi < MI; ++mi)
#pragma unroll
                for (int ni = 0; ni < NI; ++ni)
                    acc[mi][ni] = __builtin_amdgcn_mfma_f32_16x16x32_bf16(
                        af[mi], bfr[ni], acc[mi][ni], 0, 0, 0);
        }
        __syncthreads();
    }

    long cb = zb * bsC1 + zh * bsC2 + (long)pair * pairC;
#pragma unroll
    for (int mi = 0; mi < MI; ++mi) {
#pragma unroll
        for (int ni = 0; ni < NI; ++ni) {
            int col = n0 + wno + ni * 16 + (lane & 15);
            float bv = bias ? bias[col] : 0.f;
#pragma unroll
            for (int j = 0; j < 4; ++j) {
                int row = m0 + wmo + mi * 16 + ((lane >> 4) << 2) + j;
                float v = acc[mi][ni][j] * alpha + bv;
                if (ACT) v = fmaxf(v, 0.f);
                long idx = (long)row * ldc + col + cb;
                if (OUTBF16) ((u16*)Cv)[idx] = f2bf(v);
                else         ((float*)Cv)[idx] = v;
            }
        }
    }
}

// ---------------------------------------------------------------------------
// Fused long-range attention (unchanged, verified round 2)
// ---------------------------------------------------------------------------
__global__ __launch_bounds__(256) void attn_k(
    const u16* __restrict__ qb, const u16* __restrict__ kcb,
    const u16* __restrict__ vcT, u16* __restrict__ lngb)
{
    __shared__ u16 Ps[64 * 128];

    int bh = blockIdx.y;
    int b = bh >> 2, h = bh & 3;
    int l0 = blockIdx.x * 64;
    int tid = threadIdx.x, wave = tid >> 6, lane = tid & 63;
    int c = lane & 15, g = lane >> 4;

    const u16* kc = kcb + (long)b * (RR * DV) + h * 64;
    const u16* qg = qb + ((long)(b * LSEQ + l0)) * DV + h * 64;
    const u16* vg = vcT + ((long)b * DV + h * 64) * RR;

    f32x4 acc[8];
#pragma unroll
    for (int mi = 0; mi < 8; ++mi) acc[mi] = (f32x4){0.f, 0.f, 0.f, 0.f};

#pragma unroll
    for (int kh = 0; kh < 2; ++kh) {
        bf16x8 bq = *(const bf16x8*)(qg + (long)(wave * 16 + c) * DV + kh * 32 + g * 8);
#pragma unroll
        for (int mi = 0; mi < 8; ++mi) {
            bf16x8 af = *(const bf16x8*)(kc + (long)(mi * 16 + c) * DV + kh * 32 + g * 8);
            acc[mi] = __builtin_amdgcn_mfma_f32_16x16x32_bf16(af, bq, acc[mi], 0, 0, 0);
        }
    }

    float mx = -INFINITY;
#pragma unroll
    for (int mi = 0; mi < 8; ++mi)
#pragma unroll
        for (int j = 0; j < 4; ++j) {
            acc[mi][j] *= 0.125f;
            mx = fmaxf(mx, acc[mi][j]);
        }
    mx = fmaxf(mx, __shfl_xor(mx, 16));
    mx = fmaxf(mx, __shfl_xor(mx, 32));
    float den = 0.f;
#pragma unroll
    for (int mi = 0; mi < 8; ++mi)
#pragma unroll
        for (int j = 0; j < 4; ++j) {
            acc[mi][j] = __expf(acc[mi][j] - mx);
            den += acc[mi][j];
        }
    den += __shfl_xor(den, 16);
    den += __shfl_xor(den, 32);
    float inv = 1.0f / den;

    int l = wave * 16 + c;
#pragma unroll
    for (int mi = 0; mi < 8; ++mi) {
        short4 sv;
        sv.x = (short)f2bf(acc[mi][0] * inv);
        sv.y = (short)f2bf(acc[mi][1] * inv);
        sv.z = (short)f2bf(acc[mi][2] * inv);
        sv.w = (short)f2bf(acc[mi][3] * inv);
        int byte = l * 256 + ((mi * 32 + g * 8) ^ ((l & 7) << 4));
        *(short4*)((char*)Ps + byte) = sv;
    }
    __syncthreads();

    f32x4 a2[4];
#pragma unroll
    for (int ni = 0; ni < 4; ++ni) a2[ni] = (f32x4){0.f, 0.f, 0.f, 0.f};
#pragma unroll
    for (int kb = 0; kb < 4; ++kb) {
        int kby = kb * 64 + (g << 4);
        bf16x8 pa = *(const bf16x8*)((char*)Ps + l * 256 + (kby ^ ((l & 7) << 4)));
#pragma unroll
        for (int ni = 0; ni < 4; ++ni) {
            bf16x8 vf = *(const bf16x8*)(vg + (long)(ni * 16 + c) * RR + kb * 32 + g * 8);
            a2[ni] = __builtin_amdgcn_mfma_f32_16x16x32_bf16(pa, vf, a2[ni], 0, 0, 0);
        }
    }
#pragma unroll
    for (int ni = 0; ni < 4; ++ni)
#pragma unroll
        for (int j = 0; j < 4; ++j) {
            int lr = wave * 16 + g * 4 + j;
            int dh = ni * 16 + c;
            lngb[((long)(b * LSEQ + l0 + lr)) * DV + h * 64 + dh] = f2bf(a2[ni][j]);
        }
}

// ---------------------------------------------------------------------------
// All weight transposes in one kernel
// ---------------------------------------------------------------------------
struct WTD { const float* src; u16* dst; int K, N, toff; };
struct WTA { WTD d[9]; };

__global__ __launch_bounds__(256) void wtrans_all_k(WTA a)
{
    int bid = blockIdx.x;
    int di = 0;
#pragma unroll
    for (int i = 1; i < 9; ++i) if (bid >= a.d[i].toff) di = i;
    const float* src = a.d[di].src;
    u16* dst = a.d[di].dst;
    int K = a.d[di].K, N = a.d[di].N;
    int tix = bid - a.d[di].toff;
    int nx = N >> 5;
    int tn = tix % nx, tk = tix / nx;
    int n0 = tn * 32, k0 = tk * 32;

    __shared__ float t[32][33];
    int tx = threadIdx.x & 31, ty = threadIdx.x >> 5;
#pragma unroll
    for (int i = 0; i < 32; i += 8)
        t[ty + i][tx] = src[(long)(k0 + ty + i) * N + n0 + tx];
    __syncthreads();
#pragma unroll
    for (int i = 0; i < 32; i += 8)
        dst[(long)(n0 + ty + i) * K + k0 + tx] = f2bf(t[tx][ty + i]);
}

// bf16 [R][C] -> bf16 [C][R] transpose, batched over z
__global__ __launch_bounds__(256) void ttrans_k(const u16* __restrict__ in,
                                                u16* __restrict__ out,
                                                int R, int C, long isb, long osb)
{
    in  += blockIdx.z * isb;
    out += blockIdx.z * osb;
    __shared__ u16 t[32][33];
    int c0 = blockIdx.x * 32, r0 = blockIdx.y * 32;
    int tx = threadIdx.x & 31, ty = threadIdx.x >> 5;
#pragma unroll
    for (int i = 0; i < 32; i += 8)
        t[ty + i][tx] = in[(long)(r0 + ty + i) * C + c0 + tx];
    __syncthreads();
#pragma unroll
    for (int i = 0; i < 32; i += 8)
        out[(long)(c0 + ty + i) * R + r0 + tx] = t[tx][ty + i];
}

// s -> bf16 cast + qkv bias concat, one kernel
__global__ void castcat_k(const float* __restrict__ in, u16* __restrict__ out,
                          const float* qb_, const float* kb_, const float* vb_,
                          float* qkvb)
{
    int bid = blockIdx.x;
    if (bid < 2048) {
        int i = (bid * 256 + threadIdx.x) * 4;
        float4 v = *(const float4*)(in + i);
        out[i]     = f2bf(v.x);
        out[i + 1] = f2bf(v.y);
        out[i + 2] = f2bf(v.z);
        out[i + 3] = f2bf(v.w);
    } else {
        int i = (bid - 2048) * 256 + threadIdx.x;
        if (i < 768)
            qkvb[i] = (i < 256) ? qb_[i] : ((i < 512) ? kb_[i - 256] : vb_[i - 512]);
    }
}

// ---------------------------------------------------------------------------
// GAT attention logits: wave-per-row, shfl reduce
// ---------------------------------------------------------------------------
__global__ __launch_bounds__(256) void gat_att_k(
    const u16* __restrict__ h, const float* __restrict__ att_src,
    const float* __restrict__ att_dst, float* __restrict__ a_src,
    float* __restrict__ a_dst)
{
    int row  = blockIdx.x * 4 + (threadIdx.x >> 6);
    int lane = threadIdx.x & 63;
    int c0   = lane * 16;
    int head = lane >> 4;

    float as[16], ad[16];
#pragma unroll
    for (int i = 0; i < 16; ++i) { as[i] = att_src[c0 + i]; ad[i] = att_dst[c0 + i]; }

    const u16* hr = h + (long)row * (HH * DV) + c0;
    bf16x8 v0 = *(const bf16x8*)(hr);
    bf16x8 v1 = *(const bf16x8*)(hr + 8);
    float ps = 0.f, pd = 0.f;
#pragma unroll
    for (int i = 0; i < 8; ++i) {
        float f0 = bf2f((u16)v0[i]), f1 = bf2f((u16)v1[i]);
        ps += f0 * as[i] + f1 * as[i + 8];
        pd += f0 * ad[i] + f1 * ad[i + 8];
    }
#pragma unroll
    for (int m = 1; m <= 8; m <<= 1) {
        ps += __shfl_xor(ps, m);
        pd += __shfl_xor(pd, m);
    }
    if ((lane & 15) == 0) {
        a_src[(long)row * HH + head] = ps;
        a_dst[(long)row * HH + head] = pd;
    }
}

// ---------------------------------------------------------------------------
// CSR build over dst (batch-shared)
// ---------------------------------------------------------------------------
__global__ void zero_icnt_k(int* __restrict__ cnt)
{
    // 2048 ints = 512 int4
    int t = threadIdx.x;
    ((int4*)cnt)[t]       = (int4){0, 0, 0, 0};
    ((int4*)cnt)[t + 256] = (int4){0, 0, 0, 0};
}

__global__ void csr_count_k(const int* __restrict__ ei, int* __restrict__ cnt)
{
    int i = blockIdx.x * blockDim.x + threadIdx.x;
    if (i >= ETOT) return;
    int dst = (i < EE) ? ei[EE + i] : (i - EE);
    atomicAdd(&cnt[dst], 1);
}

__global__ __launch_bounds__(256) void csr_scan_k(const int* __restrict__ cnt, int* __restrict__ off)
{
    __shared__ int chunk[256];
    int tid = threadIdx.x;
    int base = tid * 8;
    int loc[8];
    int s = 0;
#pragma unroll
    for (int i = 0; i < 8; ++i) { loc[i] = s; s += cnt[base + i]; }
    chunk[tid] = s;
    __syncthreads();
    for (int st = 1; st < 256; st <<= 1) {
        int v = (tid >= st) ? chunk[tid - st] : 0;
        __syncthreads();
        chunk[tid] += v;
        __syncthreads();
    }
    int pre = (tid == 0) ? 0 : chunk[tid - 1];
#pragma unroll
    for (int i = 0; i < 8; ++i) off[base + i] = pre + loc[i];
    if (tid == 255) off[LSEQ] = chunk[255];
}

// fill uses atomicSub on counts (no second zeroing needed)
__global__ void csr_fill_k(const int* __restrict__ ei, const int* __restrict__ off,
                           int* __restrict__ cnt, int* __restrict__ bucket)
{
    int i = blockIdx.x * blockDim.x + threadIdx.x;
    if (i >= ETOT) return;
    int dst = (i < EE) ? ei[EE + i] : (i - EE);
    int p = atomicSub(&cnt[dst], 1) - 1;
    bucket[off[dst] + p] = i;
}

// ---------------------------------------------------------------------------
// GAT scatter-softmax + aggregate: ONE WAVE PER (b,n), no block barriers.
// Each wave owns its LDS slice; intra-wave LDS is program-ordered.
// ---------------------------------------------------------------------------
__global__ __launch_bounds__(256) void gat_gather_k(
    const u16* __restrict__ h, const int* __restrict__ ei,
    const int* __restrict__ off, const int* __restrict__ bucket,
    const float* __restrict__ a_src, const float* __restrict__ a_dst,
    const float* __restrict__ gat_b, u16* __restrict__ out)
{
    int wv = threadIdx.x >> 6, lane = threadIdx.x & 63;
    int n = blockIdx.x * 4 + wv;
    int b = blockIdx.y;
    int beg = off[n], deg = off[n + 1] - beg;

    __shared__ int   src_sh[4][64];
    __shared__ float ex_sh[4][64][4];

    const float* asrc_b = a_src + (long)b * LSEQ * HH;
    const float4 ad4 = *(const float4*)(a_dst + ((long)b * LSEQ + n) * HH);
    float adst[4] = { ad4.x, ad4.y, ad4.z, ad4.w };

    // pass 1: global max per head (wave shfl reduce)
    float mx[4] = { -INFINITY, -INFINITY, -INFINITY, -INFINITY };
    for (int c0 = 0; c0 < deg; c0 += 64) {
        int idx = c0 + lane;
        if (idx < deg) {
            int eid = bucket[beg + idx];
            int src = (eid < EE) ? ei[eid] : (eid - EE);
            float4 as4 = *(const float4*)(asrc_b + (long)src * HH);
            float as[4] = { as4.x, as4.y, as4.z, as4.w };
#pragma unroll
            for (int hh = 0; hh < 4; ++hh) {
                float e = as[hh] + adst[hh];
                e = (e >= 0.f) ? e : 0.2f * e;
                mx[hh] = fmaxf(mx[hh], e);
            }
        }
    }
#pragma unroll
    for (int hh = 0; hh < 4; ++hh)
#pragma unroll
        for (int m = 32; m >= 1; m >>= 1)
            mx[hh] = fmaxf(mx[hh], __shfl_xor(mx[hh], m));

    // pass 2: exp -> wave-private LDS, gather with all 64 lanes
    int hd = lane >> 4;
    const u16* hb = h + (long)b * LSEQ * (HH * DV) + lane * 16;
    float acc[16];
#pragma unroll
    for (int i = 0; i < 16; ++i) acc[i] = 0.f;
    float sm[4] = { 0.f, 0.f, 0.f, 0.f };

    for (int c0 = 0; c0 < deg; c0 += 64) {
        int idx = c0 + lane;
        if (idx < deg) {
            int eid = bucket[beg + idx];
            int src = (eid < EE) ? ei[eid] : (eid - EE);
            src_sh[wv][lane] = src;
            float4 as4 = *(const float4*)(asrc_b + (long)src * HH);
            float as[4] = { as4.x, as4.y, as4.z, as4.w };
#pragma unroll
            for (int hh = 0; hh < 4; ++hh) {
                float e = as[hh] + adst[hh];
                e = (e >= 0.f) ? e : 0.2f * e;
                float ex = __expf(e - mx[hh]);
                ex_sh[wv][lane][hh] = ex;
                sm[hh] += ex;
            }
        }
        int cn = deg - c0; if (cn > 64) cn = 64;
#pragma unroll 2
        for (int j = 0; j < cn; ++j) {
            int src = src_sh[wv][j];
            float al = ex_sh[wv][j][hd];
            const u16* p = hb + (long)src * (HH * DV);
            bf16x8 v0 = *(const bf16x8*)p;
            bf16x8 v1 = *(const bf16x8*)(p + 8);
#pragma unroll
            for (int i = 0; i < 8; ++i) {
                acc[i]     += al * bf2f((u16)v0[i]);
                acc[i + 8] += al * bf2f((u16)v1[i]);
            }
        }
    }

#pragma unroll
    for (int hh = 0; hh < 4; ++hh)
#pragma unroll
        for (int m = 32; m >= 1; m >>= 1)
            sm[hh] += __shfl_xor(sm[hh], m);
    float inv = 1.0f / sm[hd];

    u16 o16[16];
    const float* gb = gat_b + lane * 16;
#pragma unroll
    for (int i = 0; i < 16; ++i) o16[i] = f2bf(acc[i] * inv + gb[i]);
    uint4* op = (uint4*)(out + ((long)b * LSEQ + n) * (HH * DV) + lane * 16);
    op[0] = ((uint4*)o16)[0];
    op[1] = ((uint4*)o16)[1];
}

// ---------------------------------------------------------------------------
// Fused LN of q/k/v segments: grid (ML, 3)
// ---------------------------------------------------------------------------
__global__ __launch_bounds__(256) void ln_cast3_k(
    const float* __restrict__ x,
    const float* g0, const float* b0, const float* g1, const float* b1,
    const float* g2, const float* b2,
    u16* o0, u16* o1, u16* o2)
{
    int seg = blockIdx.y;
    long row = blockIdx.x;
    int tid = threadIdx.x;
    const float* g = (seg == 0) ? g0 : (seg == 1) ? g1 : g2;
    const float* bt = (seg == 0) ? b0 : (seg == 1) ? b1 : b2;
    u16* o = (seg == 0) ? o0 : (seg == 1) ? o1 : o2;

    float v = x[row * 768 + seg * 256 + tid];
    __shared__ float red[256];
    red[tid] = v; __syncthreads();
    for (int s = 128; s > 0; s >>= 1) { if (tid < s) red[tid] += red[tid + s]; __syncthreads(); }
    float mu = red[0] * (1.0f / DV);
    __syncthreads();
    float d = v - mu;
    red[tid] = d * d; __syncthreads();
    for (int s = 128; s > 0; s >>= 1) { if (tid < s) red[tid] += red[tid + s]; __syncthreads(); }
    float r = rsqrtf(red[0] * (1.0f / DV) + 1e-5f);
    o[row * DV + tid] = f2bf(d * r * g[tid] + bt[tid]);
}

// LN of (x0 [+x1] [+x2]) -> fp32 out (+ optional bf16 outb)
__global__ __launch_bounds__(256) void ln3_k(
    const float* __restrict__ x0, const float* __restrict__ x1,
    const float* __restrict__ x2, const float* __restrict__ g,
    const float* __restrict__ bta, float* __restrict__ out,
    u16* __restrict__ outb)
{
    long row = blockIdx.x;
    int tid = threadIdx.x;
    long base = row * DV + tid;
    float v = x0[base];
    if (x1) v += x1[base];
    if (x2) v += x2[base];
    __shared__ float red[256];
    red[tid] = v; __syncthreads();
    for (int s = 128; s > 0; s >>= 1) { if (tid < s) red[tid] += red[tid + s]; __syncthreads(); }
    float mu = red[0] * (1.0f / DV);
    __syncthreads();
    float d = v - mu;
    red[tid] = d * d; __syncthreads();
    for (int s = 128; s > 0; s >>= 1) { if (tid < s) red[tid] += red[tid + s]; __syncthreads(); }
    float r = rsqrtf(red[0] * (1.0f / DV) + 1e-5f);
    float o = d * r * g[tid] + bta[tid];
    out[base] = o;
    if (outb) outb[base] = f2bf(o);
}

// pm softmax over L: single global read pass
__global__ __launch_bounds__(256) void colsoftmax_k(const float* __restrict__ pm,
                                                    u16* __restrict__ pmT)
{
    int r = blockIdx.x;
    int b = blockIdx.y;
    int tid = threadIdx.x, wave = tid >> 6, lane = tid & 63;
    const float* base = pm + (long)b * LSEQ * RR + r;
    u16* obase = pmT + ((long)b * RR + r) * LSEQ;

    float x[8];
#pragma unroll
    for (int i = 0; i < 8; ++i) x[i] = base[(long)(tid + i * 256) * RR];

    __shared__ float red[4];
    __shared__ float m_sh, d_sh;
    float mx = x[0];
#pragma unroll
    for (int i = 1; i < 8; ++i) mx = fmaxf(mx, x[i]);
#pragma unroll
    for (int m = 32; m >= 1; m >>= 1) mx = fmaxf(mx, __shfl_xor(mx, m));
    if (lane == 0) red[wave] = mx;
    __syncthreads();
    if (tid == 0) m_sh = fmaxf(fmaxf(red[0], red[1]), fmaxf(red[2], red[3]));
    __syncthreads();
    float m = m_sh;
    float sm = 0.f;
#pragma unroll
    for (int i = 0; i < 8; ++i) { x[i] = __expf(x[i] - m); sm += x[i]; }
#pragma unroll
    for (int mm = 32; mm >= 1; mm >>= 1) sm += __shfl_xor(sm, mm);
    if (lane == 0) red[wave] = sm;
    __syncthreads();
    if (tid == 0) d_sh = red[0] + red[1] + red[2] + red[3];
    __syncthreads();
    float inv = 1.0f / d_sh;
#pragma unroll
    for (int i = 0; i < 8; ++i) obase[tid + i * 256] = f2bf(x[i] * inv);
}

// sum 16 split-K partials -> bf16 kvcb, and (pair==1) transposed vcT
__global__ __launch_bounds__(256) void reduce_kvc_k(
    const float* __restrict__ part, u16* __restrict__ kvcb, u16* __restrict__ vcT)
{
    int pb = blockIdx.z;
    int pair = pb >> 2, b = pb & 3;
    int r0 = blockIdx.y * 32, d0 = blockIdx.x * 64;
    int tid = threadIdx.x;
    __shared__ float t[32][65];
    const float* pp = part + (long)pb * (16 * 32768);
    int r = tid >> 6;
    int d = tid & 63;
#pragma unroll
    for (int i = 0; i < 8; ++i) {
        int rr = r0 + r + i * 4;
        float s = 0.f;
#pragma unroll
        for (int sp = 0; sp < 16; ++sp)
            s += pp[(long)sp * 32768 + rr * 256 + d0 + d];
        kvcb[(long)pb * 32768 + rr * 256 + d0 + d] = f2bf(s);
        t[r + i * 4][d] = s;
    }
    if (pair == 0) return;
    __syncthreads();
    int dd = tid >> 2, rb = (tid & 3) * 8;
    u16 o8[8];
#pragma unroll
    for (int k = 0; k < 8; ++k) o8[k] = f2bf(t[rb + k][dd]);
    *(uint4*)(vcT + ((long)(b * 256 + d0 + dd)) * 128 + r0 + rb) = *(uint4*)o8;
}

// ---------------------------------------------------------------------------
extern "C" void kernel_launch(void* const* d_in, const int* in_sizes, int n_in,
                              void* d_out, int out_size, void* d_ws, size_t ws_size,
                              hipStream_t stream)
{
    const float* s        = (const float*)d_in[0];
    const float* gat_W    = (const float*)d_in[1];
    const float* att_src  = (const float*)d_in[2];
    const float* att_dst  = (const float*)d_in[3];
    const float* gat_b    = (const float*)d_in[4];
    const float* short_W  = (const float*)d_in[5];
    const float* short_b  = (const float*)d_in[6];
    const float* q_W      = (const float*)d_in[7];
    const float* q_b      = (const float*)d_in[8];
    const float* k_W      = (const float*)d_in[9];
    const float* k_b      = (const float*)d_in[10];
    const float* v_W      = (const float*)d_in[11];
    const float* v_b      = (const float*)d_in[12];
    const float* o_W      = (const float*)d_in[13];
    const float* o_b      = (const float*)d_in[14];
    const float* p_W      = (const float*)d_in[15];
    const float* p_b      = (const float*)d_in[16];
    const float* lnq_g    = (const float*)d_in[17];
    const float* lnq_b    = (const float*)d_in[18];
    const float* lnk_g    = (const float*)d_in[19];
    const float* lnk_b    = (const float*)d_in[20];
    const float* lnv_g    = (const float*)d_in[21];
    const float* lnv_b    = (const float*)d_in[22];
    const float* ln1_g    = (const float*)d_in[23];
    const float* ln1_b    = (const float*)d_in[24];
    const float* ln2_g    = (const float*)d_in[25];
    const float* ln2_b    = (const float*)d_in[26];
    const float* f1_W     = (const float*)d_in[27];
    const float* f1_b     = (const float*)d_in[28];
    const float* f2_W     = (const float*)d_in[29];
    const float* f2_b     = (const float*)d_in[30];
    const int*   ei       = (const int*)d_in[31];
    float* out = (float*)d_out;

    const size_t MB = 1024 * 1024;
    char* W = (char*)d_ws;
    u16*   sb      = (u16*)(W);                         // 4MB
    u16*   gatT    = (u16*)(W + 4*MB);                  // 512KB
    u16*   shortT  = (u16*)(W + 4*MB + 524288);         // 512KB
    u16*   qkvT    = (u16*)(W + 4*MB + 1048576);        // 384KB
    u16*   oT      = (u16*)(W + 4*MB + 1441792);        // 128KB
    u16*   pT      = (u16*)(W + 4*MB + 1572864);        // 64KB
    u16*   f1T     = (u16*)(W + 4*MB + 1638400);        // 512KB
    u16*   f2T     = (u16*)(W + 4*MB + 2162688);        // 512KB
    float* qkvb    = (float*)(W + 4*MB + 2686976);      // 3KB
    int*   ioff    = (int*)(W + 4*MB + 2690048);        // 2049
    int*   icnt    = (int*)(W + 4*MB + 2699264);        // 2048
    int*   ibucket = (int*)(W + 4*MB + 2707456);        // 34816
    u16*   h       = (u16*)(W + 8*MB);                  // 16MB
    u16*   ffh     = (u16*)(W + 8*MB);                  // alias h
    u16*   gat_out = (u16*)(W + 24*MB);                 // 16MB
    float* h1      = (float*)(W + 24*MB);               // alias (8MB)
    u16*   h1b     = (u16*)(W + 32*MB);                 // alias (4MB)
    float* shortb  = (float*)(W + 40*MB);               // 8MB
    float* qkv     = (float*)(W + 48*MB);               // 24MB (dead after ln_cast3)
    float* pmraw   = (float*)(W + 48*MB);               // alias 4MB (dead after colsoftmax)
    float* part    = (float*)(W + 48*MB);               // alias 16MB (kvc partials)
    u16*   lngb    = (u16*)(W + 48*MB);                 // alias 4MB (after part dead)
    float* lng2    = (float*)(W + 64*MB);               // 8MB
    u16*   qb      = (u16*)(W + 72*MB);                 // 4MB
    u16*   kvb     = (u16*)(W + 76*MB);                 // 8MB
    float* ff2     = (float*)(W + 76*MB);               // alias (after kvb dead)
    u16*   kvT     = (u16*)(W + 84*MB);                 // 8MB
    u16*   pmT     = (u16*)(W + 92*MB);                 // 2MB
    u16*   kvcb    = (u16*)(W + 94*MB);                 // 512KB
    u16*   vcT     = (u16*)(W + 94*MB + 524288);        // 256KB
    float* a_src   = (float*)(W + 95*MB);               // 128KB
    float* a_dst   = (float*)(W + 95*MB + 131072);      // 128KB

    const int ML = BB * LSEQ;  // 8192

    // ---- weights -> bf16 transposed; s cast; bias concat ----
    WTA wa;
    wa.d[0] = { gat_W,   gatT,            256, 1024, 0    };
    wa.d[1] = { short_W, shortT,         1024,  256, 256  };
    wa.d[2] = { q_W,     qkvT,            256,  256, 512  };
    wa.d[3] = { k_W,     qkvT + 65536,    256,  256, 576  };
    wa.d[4] = { v_W,     qkvT + 131072,   256,  256, 640  };
    wa.d[5] = { o_W,     oT,              256,  256, 704  };
    wa.d[6] = { p_W,     pT,              256,  128, 768  };
    wa.d[7] = { f1_W,    f1T,             256, 1024, 800  };
    wa.d[8] = { f2_W,    f2T,            1024,  256, 1056 };
    wtrans_all_k<<<1312, 256, 0, stream>>>(wa);
    castcat_k<<<2051, 256, 0, stream>>>(s, sb, q_b, k_b, v_b, qkvb);

    // ---- CSR (custom zero kernel — rocclr fillBuffer was 42 µs/call) ----
    zero_icnt_k<<<1, 256, 0, stream>>>(icnt);
    csr_count_k<<<(ETOT + 255) / 256, 256, 0, stream>>>(ei, icnt);
    csr_scan_k<<<1, 256, 0, stream>>>(icnt, ioff);
    csr_fill_k<<<(ETOT + 255) / 256, 256, 0, stream>>>(ei, ioff, icnt, ibucket);

    // ---- GAT ----
    mfma_gemm_k<128, 128, 1, 0><<<dim3(8, 64, 1), 256, 0, stream>>>(
        sb, gatT, nullptr, h, ML, 1024, 256, 256, 256, 1024,
        0, 0, 0, 0, 0, 0, 1, 0, 0, 0, 0, 1.f);
    gat_att_k<<<ML / 4, 256, 0, stream>>>(h, att_src, att_dst, a_src, a_dst);
    gat_gather_k<<<dim3(LSEQ / 4, BB), 256, 0, stream>>>(h, ei, ioff, ibucket,
                                                         a_src, a_dst, gat_b, gat_out);
    mfma_gemm_k<64, 128, 0, 0><<<dim3(2, 128, 1), 256, 0, stream>>>(
        gat_out, shortT, short_b, shortb, ML, 256, 1024, 1024, 1024, 256,
        0, 0, 0, 0, 0, 0, 1, 0, 0, 0, 0, 1.f);

    // ---- qkv projections + LN ----
    mfma_gemm_k<64, 128, 0, 0><<<dim3(6, 128, 1), 256, 0, stream>>>(
        sb, qkvT, qkvb, qkv, ML, 768, 256, 256, 256, 768,
        0, 0, 0, 0, 0, 0, 1, 0, 0, 0, 0, 1.f);
    ln_cast3_k<<<dim3(ML, 3), 256, 0, stream>>>(qkv, lnq_g, lnq_b, lnk_g, lnk_b,
                                                lnv_g, lnv_b, qb, kvb, kvb + 2097152);

    // pm = softmax_L(k @ p_W + p_b) -> pmT bf16 [b][r][l]
    mfma_gemm_k<64, 64, 0, 0><<<dim3(2, 128, 1), 256, 0, stream>>>(
        kvb, pT, p_b, pmraw, ML, 128, 256, 256, 256, 128,
        0, 0, 0, 0, 0, 0, 1, 0, 0, 0, 0, 1.f);
    colsoftmax_k<<<dim3(RR, BB), 256, 0, stream>>>(pmraw, pmT);

    // k,v -> L-major kvT [2][4][256][2048]
    ttrans_k<<<dim3(8, 64, 8), 256, 0, stream>>>(kvb, kvT, 2048, 256, 524288, 524288);

    // k_c/v_c via split-K (16 splits): part [pair][b][16][128][256]
    mfma_gemm_k<128, 128, 0, 0><<<dim3(2, 2, 64), 256, 0, stream>>>(
        pmT, kvT, nullptr, part, 128, 256, 2048, 2048, 2048, 256,
        262144, 0, 524288, 0, 524288, 32768, 16, 2097152, 2097152, 128, 1, 1.f);
    reduce_kvc_k<<<dim3(4, 4, 8), 256, 0, stream>>>(part, kvcb, vcT);

    // ---- fused attention ----
    attn_k<<<dim3(LSEQ / 64, BB * HH), 256, 0, stream>>>(qb, kvcb, vcT, lngb);

    // lng2 = lng @ o_W + o_b
    mfma_gemm_k<64, 128, 0, 0><<<dim3(2, 128, 1), 256, 0, stream>>>(
        lngb, oT, o_b, lng2, ML, 256, 256, 256, 256, 256,
        0, 0, 0, 0, 0, 0, 1, 0, 0, 0, 0, 1.f);

    // h1 = LN(s + short + lng2)
    ln3_k<<<ML, 256, 0, stream>>>(s, shortb, lng2, ln1_g, ln1_b, h1, h1b);

    // FFN
    mfma_gemm_k<128, 128, 1, 1><<<dim3(8, 64, 1), 256, 0, stream>>>(
        h1b, f1T, f1_b, ffh, ML, 1024, 256, 256, 256, 1024,
        0, 0, 0, 0, 0, 0, 1, 0, 0, 0, 0, 1.f);
    mfma_gemm_k<64, 128, 0, 0><<<dim3(2, 128, 1), 256, 0, stream>>>(
        ffh, f2T, f2_b, ff2, ML, 256, 1024, 1024, 1024, 256,
        0, 0, 0, 0, 0, 0, 1, 0, 0, 0, 0, 1.f);

    // out = LN(h1 + ff2)
    ln3_k<<<ML, 256, 0, stream>>>(h1, ff2, nullptr, ln2_g, ln2_b, out, nullptr);
}

// Round 7
// 245.101 us; speedup vs baseline: 5.4793x; 1.0029x over previous
//
#include <hip/hip_runtime.h>
#include <math.h>

#define BB   4
#define LSEQ 2048
#define DV   256
#define HH   4
#define RR   128
#define EE   32768
#define ETOT (EE + LSEQ)
#define FFD  1024

typedef unsigned short u16;
typedef __attribute__((ext_vector_type(8))) short bf16x8;
typedef __attribute__((ext_vector_type(4))) float f32x4;

__device__ __forceinline__ u16 f2bf(float f) {
    union { float f; unsigned u; } x; x.f = f;
    unsigned r = x.u + 0x7fff + ((x.u >> 16) & 1);
    return (u16)(r >> 16);
}
__device__ __forceinline__ float bf2f(u16 u) {
    union { unsigned u; float f; } x; x.u = ((unsigned)u) << 16;
    return x.f;
}

__device__ __forceinline__ void gload16(const void* g, void* l) {
    __builtin_amdgcn_global_load_lds(
        (const __attribute__((address_space(1))) unsigned int*)g,
        (__attribute__((address_space(3))) unsigned int*)l, 16, 0, 0);
}

// ---------------------------------------------------------------------------
// bf16 MFMA GEMM. BM in {128,64}, BN in {128,64}, BK=64.
// C[m,n] = act(alpha * sum_k A[m,k]*BT[n,k] + bias[n])
// ---------------------------------------------------------------------------
template<int BM, int BN, int OUTBF16, int ACT>
__global__ __launch_bounds__(256) void mfma_gemm_k(
    const u16* __restrict__ A, const u16* __restrict__ BT,
    const float* __restrict__ bias, void* __restrict__ Cv,
    int M, int N, int K, int lda, int ldb, int ldc,
    long bsA1, long bsA2, long bsB1, long bsB2, long bsC1, long bsC2,
    int subH, long pairB, long pairC, int ksl, int split, float alpha)
{
    constexpr int BK = 64;
    __shared__ u16 As[BM * BK];
    __shared__ u16 Bs[BN * BK];

    int z = blockIdx.z;
    int zb = z / subH, zh = z - zb * subH;
    int mtiles = M / BM;
    int pair = blockIdx.y / mtiles;
    int mt   = blockIdx.y - pair * mtiles;

    const u16* Ab = A  + zb * bsA1 + zh * bsA2;
    const u16* Bb = BT + zb * bsB1 + zh * bsB2 + (long)pair * pairB;
    int kstart = split ? zh * ksl : 0;
    int kcount = split ? ksl : K;
    int m0 = mt * BM, n0 = blockIdx.x * BN;

    int tid  = threadIdx.x;
    int wave = tid >> 6, lane = tid & 63;
    constexpr int WGN = (BN == 128) ? 2 : 1;
    constexpr int WGM = 4 / WGN;
    constexpr int MI  = BM / (WGM * 16);
    constexpr int NI  = BN / (WGN * 16);   // 4
    int wm = wave / WGN, wn = wave - wm * WGN;
    int wmo = wm * (MI * 16);
    int wno = wn * (NI * 16);

    f32x4 acc[MI][NI];
#pragma unroll
    for (int mi = 0; mi < MI; ++mi)
#pragma unroll
        for (int ni = 0; ni < NI; ++ni)
            acc[mi][ni] = (f32x4){0.f, 0.f, 0.f, 0.f};

    constexpr int AIT = (BM * BK / 8) / 256;
    constexpr int BIT = (BN * BK / 8) / 256;

    for (int k0 = 0; k0 < kcount; k0 += BK) {
        int kb = kstart + k0;
#pragma unroll
        for (int i = 0; i < AIT; ++i) {
            int p   = i * 256 + tid;
            int row = p >> 3;
            int kc  = (p & 7) ^ (row & 7);
            const u16* gp = Ab + (long)(m0 + row) * lda + kb + kc * 8;
            gload16(gp, (char*)As + (size_t)(i * 256 + wave * 64) * 16);
        }
#pragma unroll
        for (int i = 0; i < BIT; ++i) {
            int p   = i * 256 + tid;
            int row = p >> 3;
            int kc  = (p & 7) ^ (row & 7);
            const u16* gp = Bb + (long)(n0 + row) * ldb + kb + kc * 8;
            gload16(gp, (char*)Bs + (size_t)(i * 256 + wave * 64) * 16);
        }
        asm volatile("s_waitcnt vmcnt(0)");
        __syncthreads();

        const char* Ac = (const char*)As;
        const char* Bc = (const char*)Bs;
#pragma unroll
        for (int kh = 0; kh < 2; ++kh) {
            bf16x8 af[MI], bfr[NI];
            int kby = kh * 64 + ((lane >> 4) << 4);
#pragma unroll
            for (int mi = 0; mi < MI; ++mi) {
                int r = wmo + mi * 16 + (lane & 15);
                af[mi] = *(const bf16x8*)(Ac + r * 128 + (kby ^ ((r & 7) << 4)));
            }
#pragma unroll
            for (int ni = 0; ni < NI; ++ni) {
                int r = wno + ni * 16 + (lane & 15);
                bfr[ni] = *(const bf16x8*)(Bc + r * 128 + (kby ^ ((r & 7) << 4)));
            }
#pragma unroll
            for (int mi = 0; mi < MI; ++mi)
#pragma unroll
                for (int ni = 0; ni < NI; ++ni)
                    acc[mi][ni] = __builtin_amdgcn_mfma_f32_16x16x32_bf16(
                        af[mi], bfr[ni], acc[mi][ni], 0, 0, 0);
        }
        __syncthreads();
    }

    long cb = zb * bsC1 + zh * bsC2 + (long)pair * pairC;
#pragma unroll
    for (int mi = 0; mi < MI; ++mi) {
#pragma unroll
        for (int ni = 0; ni < NI; ++ni) {
            int col = n0 + wno + ni * 16 + (lane & 15);
            float bv = bias ? bias[col] : 0.f;
#pragma unroll
            for (int j = 0; j < 4; ++j) {
                int row = m0 + wmo + mi * 16 + ((lane >> 4) << 2) + j;
                float v = acc[mi][ni][j] * alpha + bv;
                if (ACT) v = fmaxf(v, 0.f);
                long idx = (long)row * ldc + col + cb;
                if (OUTBF16) ((u16*)Cv)[idx] = f2bf(v);
                else         ((float*)Cv)[idx] = v;
            }
        }
    }
}

// ---------------------------------------------------------------------------
// Fused long-range attention (unchanged, verified round 2)
// ---------------------------------------------------------------------------
__global__ __launch_bounds__(256) void attn_k(
    const u16* __restrict__ qb, const u16* __restrict__ kcb,
    const u16* __restrict__ vcT, u16* __restrict__ lngb)
{
    __shared__ u16 Ps[64 * 128];

    int bh = blockIdx.y;
    int b = bh >> 2, h = bh & 3;
    int l0 = blockIdx.x * 64;
    int tid = threadIdx.x, wave = tid >> 6, lane = tid & 63;
    int c = lane & 15, g = lane >> 4;

    const u16* kc = kcb + (long)b * (RR * DV) + h * 64;
    const u16* qg = qb + ((long)(b * LSEQ + l0)) * DV + h * 64;
    const u16* vg = vcT + ((long)b * DV + h * 64) * RR;

    f32x4 acc[8];
#pragma unroll
    for (int mi = 0; mi < 8; ++mi) acc[mi] = (f32x4){0.f, 0.f, 0.f, 0.f};

#pragma unroll
    for (int kh = 0; kh < 2; ++kh) {
        bf16x8 bq = *(const bf16x8*)(qg + (long)(wave * 16 + c) * DV + kh * 32 + g * 8);
#pragma unroll
        for (int mi = 0; mi < 8; ++mi) {
            bf16x8 af = *(const bf16x8*)(kc + (long)(mi * 16 + c) * DV + kh * 32 + g * 8);
            acc[mi] = __builtin_amdgcn_mfma_f32_16x16x32_bf16(af, bq, acc[mi], 0, 0, 0);
        }
    }

    float mx = -INFINITY;
#pragma unroll
    for (int mi = 0; mi < 8; ++mi)
#pragma unroll
        for (int j = 0; j < 4; ++j) {
            acc[mi][j] *= 0.125f;
            mx = fmaxf(mx, acc[mi][j]);
        }
    mx = fmaxf(mx, __shfl_xor(mx, 16));
    mx = fmaxf(mx, __shfl_xor(mx, 32));
    float den = 0.f;
#pragma unroll
    for (int mi = 0; mi < 8; ++mi)
#pragma unroll
        for (int j = 0; j < 4; ++j) {
            acc[mi][j] = __expf(acc[mi][j] - mx);
            den += acc[mi][j];
        }
    den += __shfl_xor(den, 16);
    den += __shfl_xor(den, 32);
    float inv = 1.0f / den;

    int l = wave * 16 + c;
#pragma unroll
    for (int mi = 0; mi < 8; ++mi) {
        short4 sv;
        sv.x = (short)f2bf(acc[mi][0] * inv);
        sv.y = (short)f2bf(acc[mi][1] * inv);
        sv.z = (short)f2bf(acc[mi][2] * inv);
        sv.w = (short)f2bf(acc[mi][3] * inv);
        int byte = l * 256 + ((mi * 32 + g * 8) ^ ((l & 7) << 4));
        *(short4*)((char*)Ps + byte) = sv;
    }
    __syncthreads();

    f32x4 a2[4];
#pragma unroll
    for (int ni = 0; ni < 4; ++ni) a2[ni] = (f32x4){0.f, 0.f, 0.f, 0.f};
#pragma unroll
    for (int kb = 0; kb < 4; ++kb) {
        int kby = kb * 64 + (g << 4);
        bf16x8 pa = *(const bf16x8*)((char*)Ps + l * 256 + (kby ^ ((l & 7) << 4)));
#pragma unroll
        for (int ni = 0; ni < 4; ++ni) {
            bf16x8 vf = *(const bf16x8*)(vg + (long)(ni * 16 + c) * RR + kb * 32 + g * 8);
            a2[ni] = __builtin_amdgcn_mfma_f32_16x16x32_bf16(pa, vf, a2[ni], 0, 0, 0);
        }
    }
#pragma unroll
    for (int ni = 0; ni < 4; ++ni)
#pragma unroll
        for (int j = 0; j < 4; ++j) {
            int lr = wave * 16 + g * 4 + j;
            int dh = ni * 16 + c;
            lngb[((long)(b * LSEQ + l0 + lr)) * DV + h * 64 + dh] = f2bf(a2[ni][j]);
        }
}

// ---------------------------------------------------------------------------
// All weight transposes in one kernel
// ---------------------------------------------------------------------------
struct WTD { const float* src; u16* dst; int K, N, toff; };
struct WTA { WTD d[9]; };

__global__ __launch_bounds__(256) void wtrans_all_k(WTA a)
{
    int bid = blockIdx.x;
    int di = 0;
#pragma unroll
    for (int i = 1; i < 9; ++i) if (bid >= a.d[i].toff) di = i;
    const float* src = a.d[di].src;
    u16* dst = a.d[di].dst;
    int K = a.d[di].K, N = a.d[di].N;
    int tix = bid - a.d[di].toff;
    int nx = N >> 5;
    int tn = tix % nx, tk = tix / nx;
    int n0 = tn * 32, k0 = tk * 32;

    __shared__ float t[32][33];
    int tx = threadIdx.x & 31, ty = threadIdx.x >> 5;
#pragma unroll
    for (int i = 0; i < 32; i += 8)
        t[ty + i][tx] = src[(long)(k0 + ty + i) * N + n0 + tx];
    __syncthreads();
#pragma unroll
    for (int i = 0; i < 32; i += 8)
        dst[(long)(n0 + ty + i) * K + k0 + tx] = f2bf(t[tx][ty + i]);
}

// bf16 [R][C] -> bf16 [C][R] transpose, batched over z
__global__ __launch_bounds__(256) void ttrans_k(const u16* __restrict__ in,
                                                u16* __restrict__ out,
                                                int R, int C, long isb, long osb)
{
    in  += blockIdx.z * isb;
    out += blockIdx.z * osb;
    __shared__ u16 t[32][33];
    int c0 = blockIdx.x * 32, r0 = blockIdx.y * 32;
    int tx = threadIdx.x & 31, ty = threadIdx.x >> 5;
#pragma unroll
    for (int i = 0; i < 32; i += 8)
        t[ty + i][tx] = in[(long)(r0 + ty + i) * C + c0 + tx];
    __syncthreads();
#pragma unroll
    for (int i = 0; i < 32; i += 8)
        out[(long)(c0 + ty + i) * R + r0 + tx] = t[tx][ty + i];
}

// s -> bf16 cast + qkv bias concat, one kernel
__global__ void castcat_k(const float* __restrict__ in, u16* __restrict__ out,
                          const float* qb_, const float* kb_, const float* vb_,
                          float* qkvb)
{
    int bid = blockIdx.x;
    if (bid < 2048) {
        int i = (bid * 256 + threadIdx.x) * 4;
        float4 v = *(const float4*)(in + i);
        out[i]     = f2bf(v.x);
        out[i + 1] = f2bf(v.y);
        out[i + 2] = f2bf(v.z);
        out[i + 3] = f2bf(v.w);
    } else {
        int i = (bid - 2048) * 256 + threadIdx.x;
        if (i < 768)
            qkvb[i] = (i < 256) ? qb_[i] : ((i < 512) ? kb_[i - 256] : vb_[i - 512]);
    }
}

// ---------------------------------------------------------------------------
// GAT attention logits: wave-per-row, shfl reduce
// ---------------------------------------------------------------------------
__global__ __launch_bounds__(256) void gat_att_k(
    const u16* __restrict__ h, const float* __restrict__ att_src,
    const float* __restrict__ att_dst, float* __restrict__ a_src,
    float* __restrict__ a_dst)
{
    int row  = blockIdx.x * 4 + (threadIdx.x >> 6);
    int lane = threadIdx.x & 63;
    int c0   = lane * 16;
    int head = lane >> 4;

    float as[16], ad[16];
#pragma unroll
    for (int i = 0; i < 16; ++i) { as[i] = att_src[c0 + i]; ad[i] = att_dst[c0 + i]; }

    const u16* hr = h + (long)row * (HH * DV) + c0;
    bf16x8 v0 = *(const bf16x8*)(hr);
    bf16x8 v1 = *(const bf16x8*)(hr + 8);
    float ps = 0.f, pd = 0.f;
#pragma unroll
    for (int i = 0; i < 8; ++i) {
        float f0 = bf2f((u16)v0[i]), f1 = bf2f((u16)v1[i]);
        ps += f0 * as[i] + f1 * as[i + 8];
        pd += f0 * ad[i] + f1 * ad[i + 8];
    }
#pragma unroll
    for (int m = 1; m <= 8; m <<= 1) {
        ps += __shfl_xor(ps, m);
        pd += __shfl_xor(pd, m);
    }
    if ((lane & 15) == 0) {
        a_src[(long)row * HH + head] = ps;
        a_dst[(long)row * HH + head] = pd;
    }
}

// ---------------------------------------------------------------------------
// CSR build over dst (batch-shared)
// ---------------------------------------------------------------------------
__global__ void zero_icnt_k(int* __restrict__ cnt)
{
    // 2048 ints = 512 int4
    int t = threadIdx.x;
    ((int4*)cnt)[t]       = (int4){0, 0, 0, 0};
    ((int4*)cnt)[t + 256] = (int4){0, 0, 0, 0};
}

__global__ void csr_count_k(const int* __restrict__ ei, int* __restrict__ cnt)
{
    int i = blockIdx.x * blockDim.x + threadIdx.x;
    if (i >= ETOT) return;
    int dst = (i < EE) ? ei[EE + i] : (i - EE);
    atomicAdd(&cnt[dst], 1);
}

__global__ __launch_bounds__(256) void csr_scan_k(const int* __restrict__ cnt, int* __restrict__ off)
{
    __shared__ int chunk[256];
    int tid = threadIdx.x;
    int base = tid * 8;
    int loc[8];
    int s = 0;
#pragma unroll
    for (int i = 0; i < 8; ++i) { loc[i] = s; s += cnt[base + i]; }
    chunk[tid] = s;
    __syncthreads();
    for (int st = 1; st < 256; st <<= 1) {
        int v = (tid >= st) ? chunk[tid - st] : 0;
        __syncthreads();
        chunk[tid] += v;
        __syncthreads();
    }
    int pre = (tid == 0) ? 0 : chunk[tid - 1];
#pragma unroll
    for (int i = 0; i < 8; ++i) off[base + i] = pre + loc[i];
    if (tid == 255) off[LSEQ] = chunk[255];
}

// fill uses atomicSub on counts (no second zeroing needed)
__global__ void csr_fill_k(const int* __restrict__ ei, const int* __restrict__ off,
                           int* __restrict__ cnt, int* __restrict__ bucket)
{
    int i = blockIdx.x * blockDim.x + threadIdx.x;
    if (i >= ETOT) return;
    int dst = (i < EE) ? ei[EE + i] : (i - EE);
    int p = atomicSub(&cnt[dst], 1) - 1;
    bucket[off[dst] + p] = i;
}

// ---------------------------------------------------------------------------
// GAT scatter-softmax + aggregate: ONE WAVE PER (b,n), no block barriers.
// Each wave owns its LDS slice; intra-wave LDS is program-ordered.
// ---------------------------------------------------------------------------
__global__ __launch_bounds__(256) void gat_gather_k(
    const u16* __restrict__ h, const int* __restrict__ ei,
    const int* __restrict__ off, const int* __restrict__ bucket,
    const float* __restrict__ a_src, const float* __restrict__ a_dst,
    const float* __restrict__ gat_b, u16* __restrict__ out)
{
    int wv = threadIdx.x >> 6, lane = threadIdx.x & 63;
    int n = blockIdx.x * 4 + wv;
    int b = blockIdx.y;
    int beg = off[n], deg = off[n + 1] - beg;

    __shared__ int   src_sh[4][64];
    __shared__ float ex_sh[4][64][4];

    const float* asrc_b = a_src + (long)b * LSEQ * HH;
    const float4 ad4 = *(const float4*)(a_dst + ((long)b * LSEQ + n) * HH);
    float adst[4] = { ad4.x, ad4.y, ad4.z, ad4.w };

    // pass 1: global max per head (wave shfl reduce)
    float mx[4] = { -INFINITY, -INFINITY, -INFINITY, -INFINITY };
    for (int c0 = 0; c0 < deg; c0 += 64) {
        int idx = c0 + lane;
        if (idx < deg) {
            int eid = bucket[beg + idx];
            int src = (eid < EE) ? ei[eid] : (eid - EE);
            float4 as4 = *(const float4*)(asrc_b + (long)src * HH);
            float as[4] = { as4.x, as4.y, as4.z, as4.w };
#pragma unroll
            for (int hh = 0; hh < 4; ++hh) {
                float e = as[hh] + adst[hh];
                e = (e >= 0.f) ? e : 0.2f * e;
                mx[hh] = fmaxf(mx[hh], e);
            }
        }
    }
#pragma unroll
    for (int hh = 0; hh < 4; ++hh)
#pragma unroll
        for (int m = 32; m >= 1; m >>= 1)
            mx[hh] = fmaxf(mx[hh], __shfl_xor(mx[hh], m));

    // pass 2: exp -> wave-private LDS, gather with all 64 lanes
    int hd = lane >> 4;
    const u16* hb = h + (long)b * LSEQ * (HH * DV) + lane * 16;
    float acc[16];
#pragma unroll
    for (int i = 0; i < 16; ++i) acc[i] = 0.f;
    float sm[4] = { 0.f, 0.f, 0.f, 0.f };

    for (int c0 = 0; c0 < deg; c0 += 64) {
        int idx = c0 + lane;
        if (idx < deg) {
            int eid = bucket[beg + idx];
            int src = (eid < EE) ? ei[eid] : (eid - EE);
            src_sh[wv][lane] = src;
            float4 as4 = *(const float4*)(asrc_b + (long)src * HH);
            float as[4] = { as4.x, as4.y, as4.z, as4.w };
#pragma unroll
            for (int hh = 0; hh < 4; ++hh) {
                float e = as[hh] + adst[hh];
                e = (e >= 0.f) ? e : 0.2f * e;
                float ex = __expf(e - mx[hh]);
                ex_sh[wv][lane][hh] = ex;
                sm[hh] += ex;
            }
        }
        int cn = deg - c0; if (cn > 64) cn = 64;
#pragma unroll 2
        for (int j = 0; j < cn; ++j) {
            int src = src_sh[wv][j];
            float al = ex_sh[wv][j][hd];
            const u16* p = hb + (long)src * (HH * DV);
            bf16x8 v0 = *(const bf16x8*)p;
            bf16x8 v1 = *(const bf16x8*)(p + 8);
#pragma unroll
            for (int i = 0; i < 8; ++i) {
                acc[i]     += al * bf2f((u16)v0[i]);
                acc[i + 8] += al * bf2f((u16)v1[i]);
            }
        }
    }

#pragma unroll
    for (int hh = 0; hh < 4; ++hh)
#pragma unroll
        for (int m = 32; m >= 1; m >>= 1)
            sm[hh] += __shfl_xor(sm[hh], m);
    float inv = 1.0f / sm[hd];

    u16 o16[16];
    const float* gb = gat_b + lane * 16;
#pragma unroll
    for (int i = 0; i < 16; ++i) o16[i] = f2bf(acc[i] * inv + gb[i]);
    uint4* op = (uint4*)(out + ((long)b * LSEQ + n) * (HH * DV) + lane * 16);
    op[0] = ((uint4*)o16)[0];
    op[1] = ((uint4*)o16)[1];
}

// ---------------------------------------------------------------------------
// Fused LN of q/k/v segments: grid (ML, 3)
// ---------------------------------------------------------------------------
__global__ __launch_bounds__(256) void ln_cast3_k(
    const float* __restrict__ x,
    const float* g0, const float* b0, const float* g1, const float* b1,
    const float* g2, const float* b2,
    u16* o0, u16* o1, u16* o2)
{
    int seg = blockIdx.y;
    long row = blockIdx.x;
    int tid = threadIdx.x;
    const float* g = (seg == 0) ? g0 : (seg == 1) ? g1 : g2;
    const float* bt = (seg == 0) ? b0 : (seg == 1) ? b1 : b2;
    u16* o = (seg == 0) ? o0 : (seg == 1) ? o1 : o2;

    float v = x[row * 768 + seg * 256 + tid];
    __shared__ float red[256];
    red[tid] = v; __syncthreads();
    for (int s = 128; s > 0; s >>= 1) { if (tid < s) red[tid] += red[tid + s]; __syncthreads(); }
    float mu = red[0] * (1.0f / DV);
    __syncthreads();
    float d = v - mu;
    red[tid] = d * d; __syncthreads();
    for (int s = 128; s > 0; s >>= 1) { if (tid < s) red[tid] += red[tid + s]; __syncthreads(); }
    float r = rsqrtf(red[0] * (1.0f / DV) + 1e-5f);
    o[row * DV + tid] = f2bf(d * r * g[tid] + bt[tid]);
}

// LN of (x0 [+x1] [+x2]) -> fp32 out (+ optional bf16 outb)
__global__ __launch_bounds__(256) void ln3_k(
    const float* __restrict__ x0, const float* __restrict__ x1,
    const float* __restrict__ x2, const float* __restrict__ g,
    const float* __restrict__ bta, float* __restrict__ out,
    u16* __restrict__ outb)
{
    long row = blockIdx.x;
    int tid = threadIdx.x;
    long base = row * DV + tid;
    float v = x0[base];
    if (x1) v += x1[base];
    if (x2) v += x2[base];
    __shared__ float red[256];
    red[tid] = v; __syncthreads();
    for (int s = 128; s > 0; s >>= 1) { if (tid < s) red[tid] += red[tid + s]; __syncthreads(); }
    float mu = red[0] * (1.0f / DV);
    __syncthreads();
    float d = v - mu;
    red[tid] = d * d; __syncthreads();
    for (int s = 128; s > 0; s >>= 1) { if (tid < s) red[tid] += red[tid + s]; __syncthreads(); }
    float r = rsqrtf(red[0] * (1.0f / DV) + 1e-5f);
    float o = d * r * g[tid] + bta[tid];
    out[base] = o;
    if (outb) outb[base] = f2bf(o);
}

// pm softmax over L: single global read pass
__global__ __launch_bounds__(256) void colsoftmax_k(const float* __restrict__ pm,
                                                    u16* __restrict__ pmT)
{
    int r = blockIdx.x;
    int b = blockIdx.y;
    int tid = threadIdx.x, wave = tid >> 6, lane = tid & 63;
    const float* base = pm + (long)b * LSEQ * RR + r;
    u16* obase = pmT + ((long)b * RR + r) * LSEQ;

    float x[8];
#pragma unroll
    for (int i = 0; i < 8; ++i) x[i] = base[(long)(tid + i * 256) * RR];

    __shared__ float red[4];
    __shared__ float m_sh, d_sh;
    float mx = x[0];
#pragma unroll
    for (int i = 1; i < 8; ++i) mx = fmaxf(mx, x[i]);
#pragma unroll
    for (int m = 32; m >= 1; m >>= 1) mx = fmaxf(mx, __shfl_xor(mx, m));
    if (lane == 0) red[wave] = mx;
    __syncthreads();
    if (tid == 0) m_sh = fmaxf(fmaxf(red[0], red[1]), fmaxf(red[2], red[3]));
    __syncthreads();
    float m = m_sh;
    float sm = 0.f;
#pragma unroll
    for (int i = 0; i < 8; ++i) { x[i] = __expf(x[i] - m); sm += x[i]; }
#pragma unroll
    for (int mm = 32; mm >= 1; mm >>= 1) sm += __shfl_xor(sm, mm);
    if (lane == 0) red[wave] = sm;
    __syncthreads();
    if (tid == 0) d_sh = red[0] + red[1] + red[2] + red[3];
    __syncthreads();
    float inv = 1.0f / d_sh;
#pragma unroll
    for (int i = 0; i < 8; ++i) obase[tid + i * 256] = f2bf(x[i] * inv);
}

// sum 16 split-K partials -> bf16 kvcb, and (pair==1) transposed vcT
__global__ __launch_bounds__(256) void reduce_kvc_k(
    const float* __restrict__ part, u16* __restrict__ kvcb, u16* __restrict__ vcT)
{
    int pb = blockIdx.z;
    int pair = pb >> 2, b = pb & 3;
    int r0 = blockIdx.y * 32, d0 = blockIdx.x * 64;
    int tid = threadIdx.x;
    __shared__ float t[32][65];
    const float* pp = part + (long)pb * (16 * 32768);
    int r = tid >> 6;
    int d = tid & 63;
#pragma unroll
    for (int i = 0; i < 8; ++i) {
        int rr = r0 + r + i * 4;
        float s = 0.f;
#pragma unroll
        for (int sp = 0; sp < 16; ++sp)
            s += pp[(long)sp * 32768 + rr * 256 + d0 + d];
        kvcb[(long)pb * 32768 + rr * 256 + d0 + d] = f2bf(s);
        t[r + i * 4][d] = s;
    }
    if (pair == 0) return;
    __syncthreads();
    int dd = tid >> 2, rb = (tid & 3) * 8;
    u16 o8[8];
#pragma unroll
    for (int k = 0; k < 8; ++k) o8[k] = f2bf(t[rb + k][dd]);
    *(uint4*)(vcT + ((long)(b * 256 + d0 + dd)) * 128 + r0 + rb) = *(uint4*)o8;
}

// ---------------------------------------------------------------------------
extern "C" void kernel_launch(void* const* d_in, const int* in_sizes, int n_in,
                              void* d_out, int out_size, void* d_ws, size_t ws_size,
                              hipStream_t stream)
{
    const float* s        = (const float*)d_in[0];
    const float* gat_W    = (const float*)d_in[1];
    const float* att_src  = (const float*)d_in[2];
    const float* att_dst  = (const float*)d_in[3];
    const float* gat_b    = (const float*)d_in[4];
    const float* short_W  = (const float*)d_in[5];
    const float* short_b  = (const float*)d_in[6];
    const float* q_W      = (const float*)d_in[7];
    const float* q_b      = (const float*)d_in[8];
    const float* k_W      = (const float*)d_in[9];
    const float* k_b      = (const float*)d_in[10];
    const float* v_W      = (const float*)d_in[11];
    const float* v_b      = (const float*)d_in[12];
    const float* o_W      = (const float*)d_in[13];
    const float* o_b      = (const float*)d_in[14];
    const float* p_W      = (const float*)d_in[15];
    const float* p_b      = (const float*)d_in[16];
    const float* lnq_g    = (const float*)d_in[17];
    const float* lnq_b    = (const float*)d_in[18];
    const float* lnk_g    = (const float*)d_in[19];
    const float* lnk_b    = (const float*)d_in[20];
    const float* lnv_g    = (const float*)d_in[21];
    const float* lnv_b    = (const float*)d_in[22];
    const float* ln1_g    = (const float*)d_in[23];
    const float* ln1_b    = (const float*)d_in[24];
    const float* ln2_g    = (const float*)d_in[25];
    const float* ln2_b    = (const float*)d_in[26];
    const float* f1_W     = (const float*)d_in[27];
    const float* f1_b     = (const float*)d_in[28];
    const float* f2_W     = (const float*)d_in[29];
    const float* f2_b     = (const float*)d_in[30];
    const int*   ei       = (const int*)d_in[31];
    float* out = (float*)d_out;

    const size_t MB = 1024 * 1024;
    char* W = (char*)d_ws;
    u16*   sb      = (u16*)(W);                         // 4MB
    u16*   gatT    = (u16*)(W + 4*MB);                  // 512KB
    u16*   shortT  = (u16*)(W + 4*MB + 524288);         // 512KB
    u16*   qkvT    = (u16*)(W + 4*MB + 1048576);        // 384KB
    u16*   oT      = (u16*)(W + 4*MB + 1441792);        // 128KB
    u16*   pT      = (u16*)(W + 4*MB + 1572864);        // 64KB
    u16*   f1T     = (u16*)(W + 4*MB + 1638400);        // 512KB
    u16*   f2T     = (u16*)(W + 4*MB + 2162688);        // 512KB
    float* qkvb    = (float*)(W + 4*MB + 2686976);      // 3KB
    int*   ioff    = (int*)(W + 4*MB + 2690048);        // 2049
    int*   icnt    = (int*)(W + 4*MB + 2699264);        // 2048
    int*   ibucket = (int*)(W + 4*MB + 2707456);        // 34816
    u16*   h       = (u16*)(W + 8*MB);                  // 16MB
    u16*   ffh     = (u16*)(W + 8*MB);                  // alias h
    u16*   gat_out = (u16*)(W + 24*MB);                 // 16MB
    float* h1      = (float*)(W + 24*MB);               // alias (8MB)
    u16*   h1b     = (u16*)(W + 32*MB);                 // alias (4MB)
    float* shortb  = (float*)(W + 40*MB);               // 8MB
    float* qkv     = (float*)(W + 48*MB);               // 24MB (dead after ln_cast3)
    float* pmraw   = (float*)(W + 48*MB);               // alias 4MB (dead after colsoftmax)
    float* part    = (float*)(W + 48*MB);               // alias 16MB (kvc partials)
    u16*   lngb    = (u16*)(W + 48*MB);                 // alias 4MB (after part dead)
    float* lng2    = (float*)(W + 64*MB);               // 8MB
    u16*   qb      = (u16*)(W + 72*MB);                 // 4MB
    u16*   kvb     = (u16*)(W + 76*MB);                 // 8MB
    float* ff2     = (float*)(W + 76*MB);               // alias (after kvb dead)
    u16*   kvT     = (u16*)(W + 84*MB);                 // 8MB
    u16*   pmT     = (u16*)(W + 92*MB);                 // 2MB
    u16*   kvcb    = (u16*)(W + 94*MB);                 // 512KB
    u16*   vcT     = (u16*)(W + 94*MB + 524288);        // 256KB
    float* a_src   = (float*)(W + 95*MB);               // 128KB
    float* a_dst   = (float*)(W + 95*MB + 131072);      // 128KB

    const int ML = BB * LSEQ;  // 8192

    // ---- weights -> bf16 transposed; s cast; bias concat ----
    WTA wa;
    wa.d[0] = { gat_W,   gatT,            256, 1024, 0    };
    wa.d[1] = { short_W, shortT,         1024,  256, 256  };
    wa.d[2] = { q_W,     qkvT,            256,  256, 512  };
    wa.d[3] = { k_W,     qkvT + 65536,    256,  256, 576  };
    wa.d[4] = { v_W,     qkvT + 131072,   256,  256, 640  };
    wa.d[5] = { o_W,     oT,              256,  256, 704  };
    wa.d[6] = { p_W,     pT,              256,  128, 768  };
    wa.d[7] = { f1_W,    f1T,             256, 1024, 800  };
    wa.d[8] = { f2_W,    f2T,            1024,  256, 1056 };
    wtrans_all_k<<<1312, 256, 0, stream>>>(wa);
    castcat_k<<<2051, 256, 0, stream>>>(s, sb, q_b, k_b, v_b, qkvb);

    // ---- CSR (custom zero kernel — rocclr fillBuffer was 42 µs/call) ----
    zero_icnt_k<<<1, 256, 0, stream>>>(icnt);
    csr_count_k<<<(ETOT + 255) / 256, 256, 0, stream>>>(ei, icnt);
    csr_scan_k<<<1, 256, 0, stream>>>(icnt, ioff);
    csr_fill_k<<<(ETOT + 255) / 256, 256, 0, stream>>>(ei, ioff, icnt, ibucket);

    // ---- GAT ----
    mfma_gemm_k<128, 128, 1, 0><<<dim3(8, 64, 1), 256, 0, stream>>>(
        sb, gatT, nullptr, h, ML, 1024, 256, 256, 256, 1024,
        0, 0, 0, 0, 0, 0, 1, 0, 0, 0, 0, 1.f);
    gat_att_k<<<ML / 4, 256, 0, stream>>>(h, att_src, att_dst, a_src, a_dst);
    gat_gather_k<<<dim3(LSEQ / 4, BB), 256, 0, stream>>>(h, ei, ioff, ibucket,
                                                         a_src, a_dst, gat_b, gat_out);
    mfma_gemm_k<64, 128, 0, 0><<<dim3(2, 128, 1), 256, 0, stream>>>(
        gat_out, shortT, short_b, shortb, ML, 256, 1024, 1024, 1024, 256,
        0, 0, 0, 0, 0, 0, 1, 0, 0, 0, 0, 1.f);

    // ---- qkv projections + LN ----
    mfma_gemm_k<64, 128, 0, 0><<<dim3(6, 128, 1), 256, 0, stream>>>(
        sb, qkvT, qkvb, qkv, ML, 768, 256, 256, 256, 768,
        0, 0, 0, 0, 0, 0, 1, 0, 0, 0, 0, 1.f);
    ln_cast3_k<<<dim3(ML, 3), 256, 0, stream>>>(qkv, lnq_g, lnq_b, lnk_g, lnk_b,
                                                lnv_g, lnv_b, qb, kvb, kvb + 2097152);

    // pm = softmax_L(k @ p_W + p_b) -> pmT bf16 [b][r][l]
    mfma_gemm_k<64, 64, 0, 0><<<dim3(2, 128, 1), 256, 0, stream>>>(
        kvb, pT, p_b, pmraw, ML, 128, 256, 256, 256, 128,
        0, 0, 0, 0, 0, 0, 1, 0, 0, 0, 0, 1.f);
    colsoftmax_k<<<dim3(RR, BB), 256, 0, stream>>>(pmraw, pmT);

    // k,v -> L-major kvT [2][4][256][2048]
    ttrans_k<<<dim3(8, 64, 8), 256, 0, stream>>>(kvb, kvT, 2048, 256, 524288, 524288);

    // k_c/v_c via split-K (16 splits): part [pair][b][16][128][256]
    mfma_gemm_k<128, 128, 0, 0><<<dim3(2, 2, 64), 256, 0, stream>>>(
        pmT, kvT, nullptr, part, 128, 256, 2048, 2048, 2048, 256,
        262144, 0, 524288, 0, 524288, 32768, 16, 2097152, 2097152, 128, 1, 1.f);
    reduce_kvc_k<<<dim3(4, 4, 8), 256, 0, stream>>>(part, kvcb, vcT);

    // ---- fused attention ----
    attn_k<<<dim3(LSEQ / 64, BB * HH), 256, 0, stream>>>(qb, kvcb, vcT, lngb);

    // lng2 = lng @ o_W + o_b
    mfma_gemm_k<64, 128, 0, 0><<<dim3(2, 128, 1), 256, 0, stream>>>(
        lngb, oT, o_b, lng2, ML, 256, 256, 256, 256, 256,
        0, 0, 0, 0, 0, 0, 1, 0, 0, 0, 0, 1.f);

    // h1 = LN(s + short + lng2)
    ln3_k<<<ML, 256, 0, stream>>>(s, shortb, lng2, ln1_g, ln1_b, h1, h1b);

    // FFN
    mfma_gemm_k<128, 128, 1, 1><<<dim3(8, 64, 1), 256, 0, stream>>>(
        h1b, f1T, f1_b, ffh, ML, 1024, 256, 256, 256, 1024,
        0, 0, 0, 0, 0, 0, 1, 0, 0, 0, 0, 1.f);
    mfma_gemm_k<64, 128, 0, 0><<<dim3(2, 128, 1), 256, 0, stream>>>(
        ffh, f2T, f2_b, ff2, ML, 256, 1024, 1024, 1024, 256,
        0, 0, 0, 0, 0, 0, 1, 0, 0, 0, 0, 1.f);

    // out = LN(h1 + ff2)
    ln3_k<<<ML, 256, 0, stream>>>(h1, ff2, nullptr, ln2_g, ln2_b, out, nullptr);
}